// Round 4
// baseline (3469.698 us; speedup 1.0000x reference)
//
#include <hip/hip_runtime.h>

#define H64 64
#define SEQL 4096
#define NB 64

// ---------------------------------------------------------------------------
// proj16: 16 output channels of a 64->64 projection for one token held in
// registers. Weight reads are wave-uniform -> scalar loads (SMEM pipe),
// activations are VGPRs. 4 accumulators break the FMA dependency chain.
// ---------------------------------------------------------------------------
__device__ __forceinline__ void proj16(const float* __restrict__ W, int j0,
                                       const float* __restrict__ h, float* __restrict__ out)
{
#pragma unroll
    for (int j = 0; j < 16; ++j) {
        const float* wr = W + (size_t)(j0 + j) * 64;
        float a0 = 0.f, a1 = 0.f, a2 = 0.f, a3 = 0.f;
#pragma unroll
        for (int i = 0; i < 64; i += 4) {
            a0 = fmaf(wr[i],     h[i],     a0);
            a1 = fmaf(wr[i + 1], h[i + 1], a1);
            a2 = fmaf(wr[i + 2], h[i + 2], a2);
            a3 = fmaf(wr[i + 3], h[i + 3], a3);
        }
        out[j] = (a0 + a1) + (a2 + a3);
    }
}

// ---------------------------------------------------------------------------
// Encoder v2: one thread = one token. h/z/f in registers (compile-time
// indexed), weights via wave-uniform scalar loads. No LDS in hot loops, no
// barriers, no cross-lane ops. Only k parks its 64 outputs in a conflict-free
// LDS column so the l2-norm can run after a rolled chunk loop.
// ---------------------------------------------------------------------------
__global__ __launch_bounds__(256) void encoder_kernel(
    const int* __restrict__ x, const float* __restrict__ embed,
    const float* __restrict__ W1, const float* __restrict__ b1,
    const float* __restrict__ W2, const float* __restrict__ b2,
    const float* __restrict__ ln_g, const float* __restrict__ ln_b,
    const float* __restrict__ Wk, const float* __restrict__ Wv,
    const float* __restrict__ Wq, const float* __restrict__ Wattn,
    float* __restrict__ ks, float* __restrict__ vs,
    float* __restrict__ qbuf, float* __restrict__ qlast)
{
    __shared__ float sK[64 * 256];   // 64 KB: per-thread k column, stride 256 (conflict-free)

    const int tid = threadIdx.x;
    const size_t gt = (size_t)blockIdx.x * 256 + tid;   // global token id
    const int b = (int)(gt >> 12);
    const int l = (int)(gt & (SEQL - 1));

    // ---- embed gather (L2-resident 32KB table) ----
    float h[64], z[64];
    {
        const float4* er = reinterpret_cast<const float4*>(embed + (size_t)x[gt] * 64);
#pragma unroll
        for (int i = 0; i < 16; ++i) {
            float4 e = er[i];
            h[4 * i] = e.x; h[4 * i + 1] = e.y; h[4 * i + 2] = e.z; h[4 * i + 3] = e.w;
        }
    }
#pragma unroll
    for (int i = 0; i < 64; ++i) z[i] = h[i] + b2[i];

    // ---- FF: z += W2 @ relu(W1 @ h + b1), 8 chunks of 16 intermediate ch ----
    for (int pc = 0; pc < 8; ++pc) {
        float f[16];
#pragma unroll
        for (int p = 0; p < 16; ++p) {
            const float* wr = W1 + (size_t)(pc * 16 + p) * 64;
            float a0 = 0.f, a1 = 0.f, a2 = 0.f, a3 = 0.f;
#pragma unroll
            for (int i = 0; i < 64; i += 4) {
                a0 = fmaf(wr[i],     h[i],     a0);
                a1 = fmaf(wr[i + 1], h[i + 1], a1);
                a2 = fmaf(wr[i + 2], h[i + 2], a2);
                a3 = fmaf(wr[i + 3], h[i + 3], a3);
            }
            f[p] = fmaxf((a0 + a1) + (a2 + a3) + b1[pc * 16 + p], 0.f);
        }
#pragma unroll
        for (int i = 0; i < 64; ++i) {
            const float* w2r = W2 + (size_t)i * 128 + pc * 16;
#pragma unroll
            for (int p = 0; p < 16; ++p)
                z[i] = fmaf(w2r[p], f[p], z[i]);
        }
    }

    // ---- LayerNorm (per-thread, tree-reduced) ----
    {
        float s0 = 0.f, s1 = 0.f, s2 = 0.f, s3 = 0.f;
        float q0 = 0.f, q1 = 0.f, q2 = 0.f, q3 = 0.f;
#pragma unroll
        for (int i = 0; i < 64; i += 4) {
            s0 += z[i];     q0 = fmaf(z[i],     z[i],     q0);
            s1 += z[i + 1]; q1 = fmaf(z[i + 1], z[i + 1], q1);
            s2 += z[i + 2]; q2 = fmaf(z[i + 2], z[i + 2], q2);
            s3 += z[i + 3]; q3 = fmaf(z[i + 3], z[i + 3], q3);
        }
        float mu = ((s0 + s1) + (s2 + s3)) * 0.015625f;
        float var = ((q0 + q1) + (q2 + q3)) * 0.015625f - mu * mu;
        float inv = rsqrtf(var + 1e-5f);
#pragma unroll
        for (int i = 0; i < 64; ++i)
            h[i] = (z[i] - mu) * inv * ln_g[i] + ln_b[i];   // h := hidden
    }

    // ---- k projection + l2norm (outputs parked in LDS column) ----
    {
        float ss0 = 0.f, ss1 = 0.f, ss2 = 0.f, ss3 = 0.f;
        for (int jc = 0; jc < 4; ++jc) {
            float f[16];
            proj16(Wk, jc * 16, h, f);
#pragma unroll
            for (int j = 0; j < 16; ++j) sK[(jc * 16 + j) * 256 + tid] = f[j];
#pragma unroll
            for (int j = 0; j < 16; j += 4) {
                ss0 = fmaf(f[j],     f[j],     ss0);
                ss1 = fmaf(f[j + 1], f[j + 1], ss1);
                ss2 = fmaf(f[j + 2], f[j + 2], ss2);
                ss3 = fmaf(f[j + 3], f[j + 3], ss3);
            }
        }
        float n = sqrtf((ss0 + ss1) + (ss2 + ss3));
        float sc = 1.f / fmaxf(n, 1e-12f);
        float4* ko = reinterpret_cast<float4*>(ks + gt * 64);
#pragma unroll
        for (int jq = 0; jq < 16; ++jq) {
            float4 o;
            o.x = sK[(jq * 4 + 0) * 256 + tid] * sc;
            o.y = sK[(jq * 4 + 1) * 256 + tid] * sc;
            o.z = sK[(jq * 4 + 2) * 256 + tid] * sc;
            o.w = sK[(jq * 4 + 3) * 256 + tid] * sc;
            ko[jq] = o;
        }
    }

    // ---- v projection (streaming) ----
    {
        float4* vo = reinterpret_cast<float4*>(vs + gt * 64);
        for (int jc = 0; jc < 4; ++jc) {
            float f[16];
            proj16(Wv, jc * 16, h, f);
#pragma unroll
            for (int jq = 0; jq < 4; ++jq)
                vo[jc * 4 + jq] = make_float4(f[4 * jq], f[4 * jq + 1], f[4 * jq + 2], f[4 * jq + 3]);
        }
    }

    // ---- q projection, first half only (streaming) ----
    if (l < 2048) {
        float4* qo = reinterpret_cast<float4*>(qbuf + ((size_t)b * 2048 + l) * 64);
        for (int jc = 0; jc < 4; ++jc) {
            float f[16];
            proj16(Wattn, jc * 16, h, f);
#pragma unroll
            for (int jq = 0; jq < 4; ++jq)
                qo[jc * 4 + jq] = make_float4(f[4 * jq], f[4 * jq + 1], f[4 * jq + 2], f[4 * jq + 3]);
        }
    }

    // ---- q_last (one thread per batch) ----
    if (l == SEQL - 1) {
        float4* qo = reinterpret_cast<float4*>(qlast + (size_t)b * 64);
        for (int jc = 0; jc < 4; ++jc) {
            float f[16];
            proj16(Wq, jc * 16, h, f);
#pragma unroll
            for (int jq = 0; jq < 4; ++jq)
                qo[jc * 4 + jq] = make_float4(f[4 * jq], f[4 * jq + 1], f[4 * jq + 2], f[4 * jq + 3]);
        }
    }
}

// ---------------------------------------------------------------------------
// Chunked delta scan, phase A (unchanged).
// ---------------------------------------------------------------------------
#define STEP2(K0, K1, K2, K3, V)                                                \
    do {                                                                        \
        float dp0 = fmaf(p[0], K0.x, fmaf(p[1], K0.y, fmaf(p[2], K0.z, p[3] * K0.w))); \
        float dp1 = fmaf(p[4], K1.x, fmaf(p[5], K1.y, fmaf(p[6], K1.z, p[7] * K1.w))); \
        float dp2 = fmaf(p[8], K2.x, fmaf(p[9], K2.y, fmaf(p[10], K2.z, p[11] * K2.w))); \
        float dp3 = fmaf(p[12], K3.x, fmaf(p[13], K3.y, fmaf(p[14], K3.z, p[15] * K3.w))); \
        float dq0 = fmaf(q[0], K0.x, fmaf(q[1], K0.y, fmaf(q[2], K0.z, q[3] * K0.w))); \
        float dq1 = fmaf(q[4], K1.x, fmaf(q[5], K1.y, fmaf(q[6], K1.z, q[7] * K1.w))); \
        float dq2 = fmaf(q[8], K2.x, fmaf(q[9], K2.y, fmaf(q[10], K2.z, q[11] * K2.w))); \
        float dq3 = fmaf(q[12], K3.x, fmaf(q[13], K3.y, fmaf(q[14], K3.z, q[15] * K3.w))); \
        float ddp = (dp0 + dp1) + (dp2 + dp3);                                  \
        float ddq = (dq0 + dq1) + (dq2 + dq3);                                  \
        ddp += __shfl_xor(ddp, 1);  ddq += __shfl_xor(ddq, 1);                  \
        ddp += __shfl_xor(ddp, 2);  ddq += __shfl_xor(ddq, 2);                  \
        float up = -ddp;                                                        \
        float uq = V - ddq;                                                     \
        p[0] = fmaf(up, K0.x, p[0]);   q[0] = fmaf(uq, K0.x, q[0]);             \
        p[1] = fmaf(up, K0.y, p[1]);   q[1] = fmaf(uq, K0.y, q[1]);             \
        p[2] = fmaf(up, K0.z, p[2]);   q[2] = fmaf(uq, K0.z, q[2]);             \
        p[3] = fmaf(up, K0.w, p[3]);   q[3] = fmaf(uq, K0.w, q[3]);             \
        p[4] = fmaf(up, K1.x, p[4]);   q[4] = fmaf(uq, K1.x, q[4]);             \
        p[5] = fmaf(up, K1.y, p[5]);   q[5] = fmaf(uq, K1.y, q[5]);             \
        p[6] = fmaf(up, K1.z, p[6]);   q[6] = fmaf(uq, K1.z, q[6]);             \
        p[7] = fmaf(up, K1.w, p[7]);   q[7] = fmaf(uq, K1.w, q[7]);             \
        p[8] = fmaf(up, K2.x, p[8]);   q[8] = fmaf(uq, K2.x, q[8]);             \
        p[9] = fmaf(up, K2.y, p[9]);   q[9] = fmaf(uq, K2.y, q[9]);             \
        p[10] = fmaf(up, K2.z, p[10]); q[10] = fmaf(uq, K2.z, q[10]);           \
        p[11] = fmaf(up, K2.w, p[11]); q[11] = fmaf(uq, K2.w, q[11]);           \
        p[12] = fmaf(up, K3.x, p[12]); q[12] = fmaf(uq, K3.x, q[12]);           \
        p[13] = fmaf(up, K3.y, p[13]); q[13] = fmaf(uq, K3.y, q[13]);           \
        p[14] = fmaf(up, K3.z, p[14]); q[14] = fmaf(uq, K3.z, q[14]);           \
        p[15] = fmaf(up, K3.w, p[15]); q[15] = fmaf(uq, K3.w, q[15]);           \
    } while (0)

__global__ __launch_bounds__(256) void chunk_kernel(
    float* __restrict__ ksb, float* __restrict__ vsb, int C)
{
    const int job = blockIdx.x;
    const int tid = threadIdx.x;
    const int r = tid >> 2;
    const int c0 = (tid & 3) * 16;
    float* kc = ksb + (size_t)job * C * 64;
    float* vc = vsb + (size_t)job * C * 64;

    float p[16], q[16];
#pragma unroll
    for (int j = 0; j < 16; ++j) { p[j] = (c0 + j == r) ? 1.f : 0.f; q[j] = 0.f; }

    const float* kb = kc + c0;
    const float* vp = vc + r;

    float4 a0, a1, a2, a3, e0, e1, e2, e3;
    float va, ve;
    {
        const float4* kp = reinterpret_cast<const float4*>(kb);
        a0 = kp[0]; a1 = kp[1]; a2 = kp[2]; a3 = kp[3];
        va = vp[0];
    }
    for (int t = 0; t < C; t += 2) {
        {
            const float4* kp = reinterpret_cast<const float4*>(kb + (size_t)(t + 1) * 64);
            e0 = kp[0]; e1 = kp[1]; e2 = kp[2]; e3 = kp[3];
            ve = vp[(size_t)(t + 1) * 64];
        }
        STEP2(a0, a1, a2, a3, va);
        if (t + 2 < C) {
            const float4* kp = reinterpret_cast<const float4*>(kb + (size_t)(t + 2) * 64);
            a0 = kp[0]; a1 = kp[1]; a2 = kp[2]; a3 = kp[3];
            va = vp[(size_t)(t + 2) * 64];
        }
        STEP2(e0, e1, e2, e3, ve);
    }

    float4* po = reinterpret_cast<float4*>(kc + r * 64 + c0);
    po[0] = make_float4(p[0], p[1], p[2], p[3]);
    po[1] = make_float4(p[4], p[5], p[6], p[7]);
    po[2] = make_float4(p[8], p[9], p[10], p[11]);
    po[3] = make_float4(p[12], p[13], p[14], p[15]);
    float4* qo = reinterpret_cast<float4*>(vc + r * 64 + c0);
    qo[0] = make_float4(q[0], q[1], q[2], q[3]);
    qo[1] = make_float4(q[4], q[5], q[6], q[7]);
    qo[2] = make_float4(q[8], q[9], q[10], q[11]);
    qo[3] = make_float4(q[12], q[13], q[14], q[15]);
}

// ---------------------------------------------------------------------------
// Chunked delta scan, phase B (unchanged).
// ---------------------------------------------------------------------------
__global__ __launch_bounds__(256) void combine_kernel(
    const float* __restrict__ Pb, const float* __restrict__ Qb,
    const float* __restrict__ Min, float* __restrict__ Mout,
    int nc, int chunk_stride)
{
    __shared__ __align__(16) float sM[2][64 * 68];
    __shared__ __align__(16) float sP[2][64 * 64];
    const int b = blockIdx.x;
    const int tid = threadIdx.x;
    const int r = tid >> 2;
    const int j0 = (tid & 3) * 16;

    if (Min) {
        const float4* mi = reinterpret_cast<const float4*>(Min + ((size_t)b * 64 + r) * 64 + j0);
        float4* mo = reinterpret_cast<float4*>(&sM[0][r * 68 + j0]);
#pragma unroll
        for (int u = 0; u < 4; ++u) mo[u] = mi[u];
    } else {
#pragma unroll
        for (int u = 0; u < 16; ++u) sM[0][r * 68 + j0 + u] = 0.f;
    }
    {
        const float4* g = reinterpret_cast<const float4*>(Pb + (size_t)b * nc * chunk_stride);
        float4* s = reinterpret_cast<float4*>(sP[0]);
        for (int i = tid; i < 1024; i += 256) s[i] = g[i];
    }
    __syncthreads();

    int cur = 0;
    for (int c = 0; c < nc; ++c) {
        const size_t cbase = (size_t)(b * nc + c) * chunk_stride;
        float4 rp0, rp1, rp2, rp3;
        if (c + 1 < nc) {
            const float4* g = reinterpret_cast<const float4*>(Pb + cbase + chunk_stride);
            rp0 = g[tid]; rp1 = g[tid + 256]; rp2 = g[tid + 512]; rp3 = g[tid + 768];
        }
        float4 rq0, rq1, rq2, rq3;
        {
            const float4* gq = reinterpret_cast<const float4*>(Qb + cbase + r * 64 + j0);
            rq0 = gq[0]; rq1 = gq[1]; rq2 = gq[2]; rq3 = gq[3];
        }
        float acc[16];
#pragma unroll
        for (int u = 0; u < 16; ++u) acc[u] = 0.f;
        const float* Mrow = &sM[cur][r * 68];
        const float* Pl = sP[c & 1];
#pragma unroll
        for (int mg = 0; mg < 16; ++mg) {
            float4 a = *reinterpret_cast<const float4*>(Mrow + mg * 4);
#pragma unroll
            for (int e2 = 0; e2 < 4; ++e2) {
                float am = (e2 == 0) ? a.x : (e2 == 1) ? a.y : (e2 == 2) ? a.z : a.w;
                const float4* pr = reinterpret_cast<const float4*>(Pl + (mg * 4 + e2) * 64 + j0);
                float4 p0 = pr[0], p1 = pr[1], p2 = pr[2], p3 = pr[3];
                acc[0] = fmaf(am, p0.x, acc[0]);  acc[1] = fmaf(am, p0.y, acc[1]);
                acc[2] = fmaf(am, p0.z, acc[2]);  acc[3] = fmaf(am, p0.w, acc[3]);
                acc[4] = fmaf(am, p1.x, acc[4]);  acc[5] = fmaf(am, p1.y, acc[5]);
                acc[6] = fmaf(am, p1.z, acc[6]);  acc[7] = fmaf(am, p1.w, acc[7]);
                acc[8] = fmaf(am, p2.x, acc[8]);  acc[9] = fmaf(am, p2.y, acc[9]);
                acc[10] = fmaf(am, p2.z, acc[10]); acc[11] = fmaf(am, p2.w, acc[11]);
                acc[12] = fmaf(am, p3.x, acc[12]); acc[13] = fmaf(am, p3.y, acc[13]);
                acc[14] = fmaf(am, p3.z, acc[14]); acc[15] = fmaf(am, p3.w, acc[15]);
            }
        }
        const int nxt = cur ^ 1;
        float* om = &sM[nxt][r * 68 + j0];
        om[0] = acc[0] + rq0.x;  om[1] = acc[1] + rq0.y;
        om[2] = acc[2] + rq0.z;  om[3] = acc[3] + rq0.w;
        om[4] = acc[4] + rq1.x;  om[5] = acc[5] + rq1.y;
        om[6] = acc[6] + rq1.z;  om[7] = acc[7] + rq1.w;
        om[8] = acc[8] + rq2.x;  om[9] = acc[9] + rq2.y;
        om[10] = acc[10] + rq2.z; om[11] = acc[11] + rq2.w;
        om[12] = acc[12] + rq3.x; om[13] = acc[13] + rq3.y;
        om[14] = acc[14] + rq3.z; om[15] = acc[15] + rq3.w;
        if (c + 1 < nc) {
            float4* s = reinterpret_cast<float4*>(sP[(c + 1) & 1]);
            s[tid] = rp0; s[tid + 256] = rp1; s[tid + 512] = rp2; s[tid + 768] = rp3;
        }
        __syncthreads();
        cur = nxt;
    }

    float4* mo = reinterpret_cast<float4*>(Mout + ((size_t)b * 64 + r) * 64 + j0);
    const float* fm = &sM[cur][r * 68 + j0];
    mo[0] = make_float4(fm[0], fm[1], fm[2], fm[3]);
    mo[1] = make_float4(fm[4], fm[5], fm[6], fm[7]);
    mo[2] = make_float4(fm[8], fm[9], fm[10], fm[11]);
    mo[3] = make_float4(fm[12], fm[13], fm[14], fm[15]);
}

// ---------------------------------------------------------------------------
// Attention read + second k/v projection (unchanged from round 3).
// ---------------------------------------------------------------------------
__global__ __launch_bounds__(256) void attn_kernel(
    const float* __restrict__ qg, const float* __restrict__ Mbuf,
    const float* __restrict__ Wk, const float* __restrict__ Wv,
    float* __restrict__ ks2, float* __restrict__ vs2)
{
    __shared__ __align__(16) float sM[64 * 65];
    __shared__ __align__(16) float sWkT[64 * 65];
    __shared__ __align__(16) float sWvT[64 * 65];
    __shared__ __align__(16) float sA[64 * 36];   // qT -> ctxT  [h][t]
    __shared__ __align__(16) float sB[64 * 36];   // pT          [k][t]

    const int b = blockIdx.y;
    const int tile0 = blockIdx.x * 32;
    const int tid = threadIdx.x;
    const int lane = tid & 63;
    const int t0 = (tid >> 6) * 8;
    const size_t qbase = (size_t)b * 2048 + tile0;

    for (int idx = tid; idx < 4096; idx += 256) {
        int rr = idx >> 6, cc = idx & 63;
        sM[rr * 65 + cc] = Mbuf[(size_t)b * 4096 + idx];
        sWkT[cc * 65 + rr] = Wk[idx];
        sWvT[cc * 65 + rr] = Wv[idx];
    }
    for (int it = tid; it < 512; it += 256) {
        int hg = it & 15, t = it >> 4;
        float4 qv = *reinterpret_cast<const float4*>(&qg[(qbase + t) * 64 + hg * 4]);
        sA[(hg * 4 + 0) * 36 + t] = qv.x;
        sA[(hg * 4 + 1) * 36 + t] = qv.y;
        sA[(hg * 4 + 2) * 36 + t] = qv.z;
        sA[(hg * 4 + 3) * 36 + t] = qv.w;
    }
    __syncthreads();

    float acc[8];
#pragma unroll
    for (int u = 0; u < 8; ++u) acc[u] = 0.f;
    for (int h = 0; h < 64; ++h) {
        float w = sM[h * 65 + lane];
        const float4* qp = reinterpret_cast<const float4*>(&sA[h * 36 + t0]);
        float4 q0 = qp[0], q1 = qp[1];
        acc[0] = fmaf(w, q0.x, acc[0]); acc[1] = fmaf(w, q0.y, acc[1]);
        acc[2] = fmaf(w, q0.z, acc[2]); acc[3] = fmaf(w, q0.w, acc[3]);
        acc[4] = fmaf(w, q1.x, acc[4]); acc[5] = fmaf(w, q1.y, acc[5]);
        acc[6] = fmaf(w, q1.z, acc[6]); acc[7] = fmaf(w, q1.w, acc[7]);
    }

#pragma unroll
    for (int u = 0; u < 8; ++u) {
        float sv = acc[u] * 0.125f;
        float mx = sv;
        for (int off = 32; off; off >>= 1) mx = fmaxf(mx, __shfl_xor(mx, off));
        float e = __expf(sv - mx);
        float sm = e;
        for (int off = 32; off; off >>= 1) sm += __shfl_xor(sm, off);
        acc[u] = e / sm;
    }
#pragma unroll
    for (int u = 0; u < 8; ++u) sB[lane * 36 + t0 + u] = acc[u];
    __syncthreads();

#pragma unroll
    for (int u = 0; u < 8; ++u) acc[u] = 0.f;
    for (int k = 0; k < 64; ++k) {
        float m = sM[lane * 65 + k];
        const float4* pp = reinterpret_cast<const float4*>(&sB[k * 36 + t0]);
        float4 p0 = pp[0], p1 = pp[1];
        acc[0] = fmaf(m, p0.x, acc[0]); acc[1] = fmaf(m, p0.y, acc[1]);
        acc[2] = fmaf(m, p0.z, acc[2]); acc[3] = fmaf(m, p0.w, acc[3]);
        acc[4] = fmaf(m, p1.x, acc[4]); acc[5] = fmaf(m, p1.y, acc[5]);
        acc[6] = fmaf(m, p1.z, acc[6]); acc[7] = fmaf(m, p1.w, acc[7]);
    }
#pragma unroll
    for (int u = 0; u < 8; ++u) sA[lane * 36 + t0 + u] = acc[u];
    __syncthreads();

    float ak[8], av[8];
#pragma unroll
    for (int u = 0; u < 8; ++u) { ak[u] = 0.f; av[u] = 0.f; }
    for (int h = 0; h < 64; ++h) {
        float wk = sWkT[h * 65 + lane];
        float wv = sWvT[h * 65 + lane];
        const float4* cp = reinterpret_cast<const float4*>(&sA[h * 36 + t0]);
        float4 c0 = cp[0], c1 = cp[1];
        ak[0] = fmaf(wk, c0.x, ak[0]); av[0] = fmaf(wv, c0.x, av[0]);
        ak[1] = fmaf(wk, c0.y, ak[1]); av[1] = fmaf(wv, c0.y, av[1]);
        ak[2] = fmaf(wk, c0.z, ak[2]); av[2] = fmaf(wv, c0.z, av[2]);
        ak[3] = fmaf(wk, c0.w, ak[3]); av[3] = fmaf(wv, c0.w, av[3]);
        ak[4] = fmaf(wk, c1.x, ak[4]); av[4] = fmaf(wv, c1.x, av[4]);
        ak[5] = fmaf(wk, c1.y, ak[5]); av[5] = fmaf(wv, c1.y, av[5]);
        ak[6] = fmaf(wk, c1.z, ak[6]); av[6] = fmaf(wv, c1.z, av[6]);
        ak[7] = fmaf(wk, c1.w, ak[7]); av[7] = fmaf(wv, c1.w, av[7]);
    }
#pragma unroll
    for (int u = 0; u < 8; ++u) {
        float ssq = ak[u] * ak[u];
        for (int off = 32; off; off >>= 1) ssq += __shfl_xor(ssq, off);
        float n = sqrtf(ssq);
        float sc = 1.f / fmaxf(n, 1e-12f);
        const size_t o = (qbase + t0 + u) * 64 + lane;
        ks2[o] = ak[u] * sc;
        vs2[o] = av[u];
    }
}

// ---------------------------------------------------------------------------
// Output: read = M2 @ q_last; out = read @ Wout^T + bout
// ---------------------------------------------------------------------------
__global__ __launch_bounds__(128) void out_kernel(
    const float* __restrict__ M2, const float* __restrict__ qlast,
    const float* __restrict__ Wout, const float* __restrict__ bout,
    float* __restrict__ out)
{
    const int b = blockIdx.x;
    const int tid = threadIdx.x;
    __shared__ float sq[64], sread[64];
    if (tid < 64) sq[tid] = qlast[b * 64 + tid];
    __syncthreads();
    if (tid < 64) {
        const float* Mr = M2 + ((size_t)b * 64 + tid) * 64;
        float acc = 0.f;
        for (int j = 0; j < 64; ++j) acc = fmaf(Mr[j], sq[j], acc);
        sread[tid] = acc;
    }
    __syncthreads();
    float acc = bout[tid];
    for (int h = 0; h < 64; ++h) acc = fmaf(Wout[tid * 64 + h], sread[h], acc);
    out[b * 128 + tid] = acc;
}

// ---------------------------------------------------------------------------
extern "C" void kernel_launch(void* const* d_in, const int* in_sizes, int n_in,
                              void* d_out, int out_size, void* d_ws, size_t ws_size,
                              hipStream_t stream)
{
    const int* x        = (const int*)d_in[0];
    const float* embed  = (const float*)d_in[1];
    const float* W1     = (const float*)d_in[2];
    const float* b1     = (const float*)d_in[3];
    const float* W2     = (const float*)d_in[4];
    const float* b2     = (const float*)d_in[5];
    const float* ln_g   = (const float*)d_in[6];
    const float* ln_b   = (const float*)d_in[7];
    const float* Wk     = (const float*)d_in[8];
    const float* Wv     = (const float*)d_in[9];
    const float* Wq     = (const float*)d_in[10];
    const float* Wattn  = (const float*)d_in[11];
    const float* Wout   = (const float*)d_in[12];
    const float* bout   = (const float*)d_in[13];

    // workspace layout (floats): ks | vs | q | qlast | M | M2
    float* ws = (float*)d_ws;
    float* ks = ws;
    float* vs = ks + (size_t)NB * SEQL * 64;
    float* qb = vs + (size_t)NB * SEQL * 64;
    float* ql = qb + (size_t)NB * 2048 * 64;
    float* M  = ql + (size_t)NB * 64;
    float* M2 = M + (size_t)NB * 64 * 64;
    if (ws_size < (size_t)(M2 + (size_t)NB * 64 * 64 - ws) * sizeof(float)) return;

    hipLaunchKernelGGL(encoder_kernel, dim3((NB * SEQL) / 256), dim3(256), 0, stream,
                       x, embed, W1, b1, W2, b2, ln_g, ln_b, Wk, Wv, Wq, Wattn,
                       ks, vs, qb, ql);

    // scan 1: L=4096, C=256 -> 16 chunks/batch, 1024 parallel chunk jobs
    const int C1 = 256, nc1 = SEQL / C1;
    hipLaunchKernelGGL(chunk_kernel, dim3(NB * nc1), dim3(256), 0, stream, ks, vs, C1);
    hipLaunchKernelGGL(combine_kernel, dim3(NB), dim3(256), 0, stream,
                       ks, vs, (const float*)nullptr, M, nc1, C1 * 64);

    // attention + second k/v projection (ks2/vs2 reuse ks/vs)
    hipLaunchKernelGGL(attn_kernel, dim3(64, NB), dim3(256), 0, stream,
                       qb, M, Wk, Wv, ks, vs);

    // scan 2: L=2048, C=128 -> 16 chunks/batch, 1024 parallel chunk jobs
    const int C2 = 128, nc2 = 2048 / C2;
    hipLaunchKernelGGL(chunk_kernel, dim3(NB * nc2), dim3(256), 0, stream, ks, vs, C2);
    hipLaunchKernelGGL(combine_kernel, dim3(NB), dim3(256), 0, stream,
                       ks, vs, M, M2, nc2, C2 * 64);

    hipLaunchKernelGGL(out_kernel, dim3(NB), dim3(128), 0, stream,
                       M2, ql, Wout, bout, (float*)d_out);
}

// Round 5
// 914.713 us; speedup vs baseline: 3.7932x; 3.7932x over previous
//
#include <hip/hip_runtime.h>

#define SEQL 4096
#define NB 64

// ---------------------------------------------------------------------------
// Encoder v3: block = 64 tokens, 256 threads. Each thread owns a 4x4 tile
// (4 output channels j = jq..jq+3, 4 tokens t = tq..tq+3). Every GEMM K-step
// is 2 x ds_read_b128 (per-lane weight float4 + broadcast activation float4)
// feeding 16 FMAs -> 0.125 LDS insts/FMA (round-3 was 0.31-0.375).
// Weights staged into a 64x68 LDS buffer in K- or J-halves.
// LDS total = (64 + 128 + 64) * 68 * 4 = 69632 B -> 2 blocks/CU.
// ---------------------------------------------------------------------------
#define FMA16(A, W, H)                                      \
    A[0]  = fmaf(W.x, H.x, A[0]);  A[1]  = fmaf(W.x, H.y, A[1]);   \
    A[2]  = fmaf(W.x, H.z, A[2]);  A[3]  = fmaf(W.x, H.w, A[3]);   \
    A[4]  = fmaf(W.y, H.x, A[4]);  A[5]  = fmaf(W.y, H.y, A[5]);   \
    A[6]  = fmaf(W.y, H.z, A[6]);  A[7]  = fmaf(W.y, H.w, A[7]);   \
    A[8]  = fmaf(W.z, H.x, A[8]);  A[9]  = fmaf(W.z, H.y, A[9]);   \
    A[10] = fmaf(W.z, H.z, A[10]); A[11] = fmaf(W.z, H.w, A[11]);  \
    A[12] = fmaf(W.w, H.x, A[12]); A[13] = fmaf(W.w, H.y, A[13]);  \
    A[14] = fmaf(W.w, H.z, A[14]); A[15] = fmaf(W.w, H.w, A[15])

__device__ __forceinline__ void proj_tile64(const float* __restrict__ sW,
                                            const float* __restrict__ sA,
                                            int jq, int tq, float* __restrict__ a)
{
#pragma unroll
    for (int u = 0; u < 16; ++u) a[u] = 0.f;
#pragma unroll 2
    for (int i = 0; i < 64; ++i) {
        float4 w  = *reinterpret_cast<const float4*>(&sW[i * 68 + jq]);
        float4 h4 = *reinterpret_cast<const float4*>(&sA[i * 68 + tq]);
        FMA16(a, w, h4);
    }
}

__global__ __launch_bounds__(256) void encoder_kernel(
    const int* __restrict__ x, const float* __restrict__ embed,
    const float* __restrict__ W1, const float* __restrict__ b1,
    const float* __restrict__ W2, const float* __restrict__ b2,
    const float* __restrict__ ln_g, const float* __restrict__ ln_b,
    const float* __restrict__ Wk, const float* __restrict__ Wv,
    const float* __restrict__ Wq, const float* __restrict__ Wattn,
    float* __restrict__ ks, float* __restrict__ vs,
    float* __restrict__ qbuf, float* __restrict__ qlast)
{
    __shared__ __align__(16) float sZ[64 * 68];    // embed h -> hidden, [i][t]
    __shared__ __align__(16) float sF[128 * 68];   // ff1 relu out, [p][t]
    __shared__ __align__(16) float sW[64 * 68];    // staged weight half, [k][j]

    const int tid = threadIdx.x;
    const size_t g0 = (size_t)blockIdx.x * 64;
    const int b = (int)(g0 >> 12);
    const int l0 = (int)(g0 & (SEQL - 1));
    const int jq = (tid & 15) * 4;       // output channels jq..jq+3
    const int tq = (tid >> 4) * 4;       // tokens tq..tq+3

    // ---- embed gather -> sZ[i][t] (coalesced row reads) ----
    for (int idx = tid; idx < 4096; idx += 256) {
        int t = idx >> 6, i = idx & 63;
        sZ[i * 68 + t] = embed[(size_t)x[g0 + t] * 64 + i];
    }

    // ---- ff1: relu(W1 @ h + b1) -> sF, two j-halves ----
    for (int jh = 0; jh < 2; ++jh) {
        if (jh) __syncthreads();                       // prev-half sW consumers done
        for (int idx = tid; idx < 4096; idx += 256) {
            int i = idx & 63, jj = idx >> 6;
            sW[i * 68 + jj] = W1[(size_t)(jh * 64 + jj) * 64 + i];
        }
        __syncthreads();                               // also covers embed gather (jh==0)
        float a[16];
        proj_tile64(sW, sZ, jq, tq, a);
        float4 bb = *reinterpret_cast<const float4*>(&b1[jh * 64 + jq]);
        float bv[4] = {bb.x, bb.y, bb.z, bb.w};
#pragma unroll
        for (int u = 0; u < 4; ++u) {
            float4 o;
            o.x = fmaxf(a[u * 4 + 0] + bv[u], 0.f);
            o.y = fmaxf(a[u * 4 + 1] + bv[u], 0.f);
            o.z = fmaxf(a[u * 4 + 2] + bv[u], 0.f);
            o.w = fmaxf(a[u * 4 + 3] + bv[u], 0.f);
            *reinterpret_cast<float4*>(&sF[(jh * 64 + jq + u) * 68 + tq]) = o;
        }
    }

    // ---- ff2: W2 @ f, K=128 in two p-halves, accumulate in regs ----
    float zacc[16];
#pragma unroll
    for (int u = 0; u < 16; ++u) zacc[u] = 0.f;
    for (int ph = 0; ph < 2; ++ph) {
        __syncthreads();                               // sW consumers + sF writes visible
        for (int idx = tid; idx < 4096; idx += 256) {
            int p = idx & 63, j = idx >> 6;
            sW[p * 68 + j] = W2[(size_t)j * 128 + ph * 64 + p];
        }
        __syncthreads();
#pragma unroll 2
        for (int p = 0; p < 64; ++p) {
            float4 w  = *reinterpret_cast<const float4*>(&sW[p * 68 + jq]);
            float4 f4 = *reinterpret_cast<const float4*>(&sF[(ph * 64 + p) * 68 + tq]);
            FMA16(zacc, w, f4);
        }
    }

    // ---- residual + LayerNorm (reduce over j across the 16-lane jq group) ----
    {
        float z[16];
        float4 b2v = *reinterpret_cast<const float4*>(&b2[jq]);
        float bv[4] = {b2v.x, b2v.y, b2v.z, b2v.w};
#pragma unroll
        for (int u = 0; u < 4; ++u) {
            float4 h4 = *reinterpret_cast<const float4*>(&sZ[(jq + u) * 68 + tq]);
            z[u * 4 + 0] = h4.x + bv[u] + zacc[u * 4 + 0];
            z[u * 4 + 1] = h4.y + bv[u] + zacc[u * 4 + 1];
            z[u * 4 + 2] = h4.z + bv[u] + zacc[u * 4 + 2];
            z[u * 4 + 3] = h4.w + bv[u] + zacc[u * 4 + 3];
        }
        float s[4], ss[4];
#pragma unroll
        for (int v = 0; v < 4; ++v) {
            s[v]  = z[v] + z[4 + v] + z[8 + v] + z[12 + v];
            ss[v] = z[v] * z[v] + z[4 + v] * z[4 + v]
                  + z[8 + v] * z[8 + v] + z[12 + v] * z[12 + v];
        }
#pragma unroll
        for (int m = 1; m <= 8; m <<= 1) {
#pragma unroll
            for (int v = 0; v < 4; ++v) {
                s[v]  += __shfl_xor(s[v], m);
                ss[v] += __shfl_xor(ss[v], m);
            }
        }
        float mu[4], inv[4];
#pragma unroll
        for (int v = 0; v < 4; ++v) {
            mu[v] = s[v] * 0.015625f;
            float var = ss[v] * 0.015625f - mu[v] * mu[v];
            inv[v] = rsqrtf(var + 1e-5f);
        }
        float4 g4  = *reinterpret_cast<const float4*>(&ln_g[jq]);
        float4 be4 = *reinterpret_cast<const float4*>(&ln_b[jq]);
        float gv[4] = {g4.x, g4.y, g4.z, g4.w};
        float bev[4] = {be4.x, be4.y, be4.z, be4.w};
#pragma unroll
        for (int u = 0; u < 4; ++u) {
            float4 o;
            o.x = (z[u * 4 + 0] - mu[0]) * inv[0] * gv[u] + bev[u];
            o.y = (z[u * 4 + 1] - mu[1]) * inv[1] * gv[u] + bev[u];
            o.z = (z[u * 4 + 2] - mu[2]) * inv[2] * gv[u] + bev[u];
            o.w = (z[u * 4 + 3] - mu[3]) * inv[3] * gv[u] + bev[u];
            *reinterpret_cast<float4*>(&sZ[(jq + u) * 68 + tq]) = o;  // own cells only
        }
    }

    // ---- k projection + l2norm ----
    {
        __syncthreads();                               // LN writes visible, sW free
        for (int idx = tid; idx < 4096; idx += 256) {
            int i = idx & 63, j = idx >> 6;
            sW[i * 68 + j] = Wk[(size_t)j * 64 + i];
        }
        __syncthreads();
        float a[16];
        proj_tile64(sW, sZ, jq, tq, a);
        float ssq[4];
#pragma unroll
        for (int v = 0; v < 4; ++v)
            ssq[v] = a[v] * a[v] + a[4 + v] * a[4 + v]
                   + a[8 + v] * a[8 + v] + a[12 + v] * a[12 + v];
#pragma unroll
        for (int m = 1; m <= 8; m <<= 1) {
#pragma unroll
            for (int v = 0; v < 4; ++v) ssq[v] += __shfl_xor(ssq[v], m);
        }
#pragma unroll
        for (int v = 0; v < 4; ++v) {
            float sc = 1.f / fmaxf(sqrtf(ssq[v]), 1e-12f);
            float4 o = make_float4(a[v] * sc, a[4 + v] * sc, a[8 + v] * sc, a[12 + v] * sc);
            *reinterpret_cast<float4*>(&ks[(g0 + tq + v) * 64 + jq]) = o;
        }
    }

    // ---- v projection ----
    {
        __syncthreads();
        for (int idx = tid; idx < 4096; idx += 256) {
            int i = idx & 63, j = idx >> 6;
            sW[i * 68 + j] = Wv[(size_t)j * 64 + i];
        }
        __syncthreads();
        float a[16];
        proj_tile64(sW, sZ, jq, tq, a);
#pragma unroll
        for (int v = 0; v < 4; ++v) {
            float4 o = make_float4(a[v], a[4 + v], a[8 + v], a[12 + v]);
            *reinterpret_cast<float4*>(&vs[(g0 + tq + v) * 64 + jq]) = o;
        }
    }

    // ---- q projection (first-half blocks only; block never straddles halves) ----
    if (l0 < 2048) {
        __syncthreads();
        for (int idx = tid; idx < 4096; idx += 256) {
            int i = idx & 63, j = idx >> 6;
            sW[i * 68 + j] = Wattn[(size_t)j * 64 + i];
        }
        __syncthreads();
        float a[16];
        proj_tile64(sW, sZ, jq, tq, a);
#pragma unroll
        for (int v = 0; v < 4; ++v) {
            float4 o = make_float4(a[v], a[4 + v], a[8 + v], a[12 + v]);
            *reinterpret_cast<float4*>(&qbuf[((size_t)b * 2048 + l0 + tq + v) * 64 + jq]) = o;
        }
    }

    // ---- q_last (last block of each batch; token 4095 = local t 63) ----
    if (l0 == SEQL - 64) {
        __syncthreads();
        for (int idx = tid; idx < 4096; idx += 256) {
            int i = idx & 63, j = idx >> 6;
            sW[i * 68 + j] = Wq[(size_t)j * 64 + i];
        }
        __syncthreads();
        float a[16];
        proj_tile64(sW, sZ, jq, tq, a);
        if ((tid >> 4) == 15) {   // owns tokens 60..63 -> v=3 is token 63
            float4 o = make_float4(a[3], a[7], a[11], a[15]);
            *reinterpret_cast<float4*>(&qlast[(size_t)b * 64 + jq]) = o;
        }
    }
}

// ---------------------------------------------------------------------------
// Chunked delta scan, phase A (unchanged).
// ---------------------------------------------------------------------------
#define STEP2(K0, K1, K2, K3, V)                                                \
    do {                                                                        \
        float dp0 = fmaf(p[0], K0.x, fmaf(p[1], K0.y, fmaf(p[2], K0.z, p[3] * K0.w))); \
        float dp1 = fmaf(p[4], K1.x, fmaf(p[5], K1.y, fmaf(p[6], K1.z, p[7] * K1.w))); \
        float dp2 = fmaf(p[8], K2.x, fmaf(p[9], K2.y, fmaf(p[10], K2.z, p[11] * K2.w))); \
        float dp3 = fmaf(p[12], K3.x, fmaf(p[13], K3.y, fmaf(p[14], K3.z, p[15] * K3.w))); \
        float dq0 = fmaf(q[0], K0.x, fmaf(q[1], K0.y, fmaf(q[2], K0.z, q[3] * K0.w))); \
        float dq1 = fmaf(q[4], K1.x, fmaf(q[5], K1.y, fmaf(q[6], K1.z, q[7] * K1.w))); \
        float dq2 = fmaf(q[8], K2.x, fmaf(q[9], K2.y, fmaf(q[10], K2.z, q[11] * K2.w))); \
        float dq3 = fmaf(q[12], K3.x, fmaf(q[13], K3.y, fmaf(q[14], K3.z, q[15] * K3.w))); \
        float ddp = (dp0 + dp1) + (dp2 + dp3);                                  \
        float ddq = (dq0 + dq1) + (dq2 + dq3);                                  \
        ddp += __shfl_xor(ddp, 1);  ddq += __shfl_xor(ddq, 1);                  \
        ddp += __shfl_xor(ddp, 2);  ddq += __shfl_xor(ddq, 2);                  \
        float up = -ddp;                                                        \
        float uq = V - ddq;                                                     \
        p[0] = fmaf(up, K0.x, p[0]);   q[0] = fmaf(uq, K0.x, q[0]);             \
        p[1] = fmaf(up, K0.y, p[1]);   q[1] = fmaf(uq, K0.y, q[1]);             \
        p[2] = fmaf(up, K0.z, p[2]);   q[2] = fmaf(uq, K0.z, q[2]);             \
        p[3] = fmaf(up, K0.w, p[3]);   q[3] = fmaf(uq, K0.w, q[3]);             \
        p[4] = fmaf(up, K1.x, p[4]);   q[4] = fmaf(uq, K1.x, q[4]);             \
        p[5] = fmaf(up, K1.y, p[5]);   q[5] = fmaf(uq, K1.y, q[5]);             \
        p[6] = fmaf(up, K1.z, p[6]);   q[6] = fmaf(uq, K1.z, q[6]);             \
        p[7] = fmaf(up, K1.w, p[7]);   q[7] = fmaf(uq, K1.w, q[7]);             \
        p[8] = fmaf(up, K2.x, p[8]);   q[8] = fmaf(uq, K2.x, q[8]);             \
        p[9] = fmaf(up, K2.y, p[9]);   q[9] = fmaf(uq, K2.y, q[9]);             \
        p[10] = fmaf(up, K2.z, p[10]); q[10] = fmaf(uq, K2.z, q[10]);           \
        p[11] = fmaf(up, K2.w, p[11]); q[11] = fmaf(uq, K2.w, q[11]);           \
        p[12] = fmaf(up, K3.x, p[12]); q[12] = fmaf(uq, K3.x, q[12]);           \
        p[13] = fmaf(up, K3.y, p[13]); q[13] = fmaf(uq, K3.y, q[13]);           \
        p[14] = fmaf(up, K3.z, p[14]); q[14] = fmaf(uq, K3.z, q[14]);           \
        p[15] = fmaf(up, K3.w, p[15]); q[15] = fmaf(uq, K3.w, q[15]);           \
    } while (0)

__global__ __launch_bounds__(256) void chunk_kernel(
    float* __restrict__ ksb, float* __restrict__ vsb, int C)
{
    const int job = blockIdx.x;
    const int tid = threadIdx.x;
    const int r = tid >> 2;
    const int c0 = (tid & 3) * 16;
    float* kc = ksb + (size_t)job * C * 64;
    float* vc = vsb + (size_t)job * C * 64;

    float p[16], q[16];
#pragma unroll
    for (int j = 0; j < 16; ++j) { p[j] = (c0 + j == r) ? 1.f : 0.f; q[j] = 0.f; }

    const float* kb = kc + c0;
    const float* vp = vc + r;

    float4 a0, a1, a2, a3, e0, e1, e2, e3;
    float va, ve;
    {
        const float4* kp = reinterpret_cast<const float4*>(kb);
        a0 = kp[0]; a1 = kp[1]; a2 = kp[2]; a3 = kp[3];
        va = vp[0];
    }
    for (int t = 0; t < C; t += 2) {
        {
            const float4* kp = reinterpret_cast<const float4*>(kb + (size_t)(t + 1) * 64);
            e0 = kp[0]; e1 = kp[1]; e2 = kp[2]; e3 = kp[3];
            ve = vp[(size_t)(t + 1) * 64];
        }
        STEP2(a0, a1, a2, a3, va);
        if (t + 2 < C) {
            const float4* kp = reinterpret_cast<const float4*>(kb + (size_t)(t + 2) * 64);
            a0 = kp[0]; a1 = kp[1]; a2 = kp[2]; a3 = kp[3];
            va = vp[(size_t)(t + 2) * 64];
        }
        STEP2(e0, e1, e2, e3, ve);
    }

    float4* po = reinterpret_cast<float4*>(kc + r * 64 + c0);
    po[0] = make_float4(p[0], p[1], p[2], p[3]);
    po[1] = make_float4(p[4], p[5], p[6], p[7]);
    po[2] = make_float4(p[8], p[9], p[10], p[11]);
    po[3] = make_float4(p[12], p[13], p[14], p[15]);
    float4* qo = reinterpret_cast<float4*>(vc + r * 64 + c0);
    qo[0] = make_float4(q[0], q[1], q[2], q[3]);
    qo[1] = make_float4(q[4], q[5], q[6], q[7]);
    qo[2] = make_float4(q[8], q[9], q[10], q[11]);
    qo[3] = make_float4(q[12], q[13], q[14], q[15]);
}

// ---------------------------------------------------------------------------
// Chunked delta scan, phase B (unchanged).
// ---------------------------------------------------------------------------
__global__ __launch_bounds__(256) void combine_kernel(
    const float* __restrict__ Pb, const float* __restrict__ Qb,
    const float* __restrict__ Min, float* __restrict__ Mout,
    int nc, int chunk_stride)
{
    __shared__ __align__(16) float sM[2][64 * 68];
    __shared__ __align__(16) float sP[2][64 * 64];
    const int b = blockIdx.x;
    const int tid = threadIdx.x;
    const int r = tid >> 2;
    const int j0 = (tid & 3) * 16;

    if (Min) {
        const float4* mi = reinterpret_cast<const float4*>(Min + ((size_t)b * 64 + r) * 64 + j0);
        float4* mo = reinterpret_cast<float4*>(&sM[0][r * 68 + j0]);
#pragma unroll
        for (int u = 0; u < 4; ++u) mo[u] = mi[u];
    } else {
#pragma unroll
        for (int u = 0; u < 16; ++u) sM[0][r * 68 + j0 + u] = 0.f;
    }
    {
        const float4* g = reinterpret_cast<const float4*>(Pb + (size_t)b * nc * chunk_stride);
        float4* s = reinterpret_cast<float4*>(sP[0]);
        for (int i = tid; i < 1024; i += 256) s[i] = g[i];
    }
    __syncthreads();

    int cur = 0;
    for (int c = 0; c < nc; ++c) {
        const size_t cbase = (size_t)(b * nc + c) * chunk_stride;
        float4 rp0, rp1, rp2, rp3;
        if (c + 1 < nc) {
            const float4* g = reinterpret_cast<const float4*>(Pb + cbase + chunk_stride);
            rp0 = g[tid]; rp1 = g[tid + 256]; rp2 = g[tid + 512]; rp3 = g[tid + 768];
        }
        float4 rq0, rq1, rq2, rq3;
        {
            const float4* gq = reinterpret_cast<const float4*>(Qb + cbase + r * 64 + j0);
            rq0 = gq[0]; rq1 = gq[1]; rq2 = gq[2]; rq3 = gq[3];
        }
        float acc[16];
#pragma unroll
        for (int u = 0; u < 16; ++u) acc[u] = 0.f;
        const float* Mrow = &sM[cur][r * 68];
        const float* Pl = sP[c & 1];
#pragma unroll
        for (int mg = 0; mg < 16; ++mg) {
            float4 a = *reinterpret_cast<const float4*>(Mrow + mg * 4);
#pragma unroll
            for (int e2 = 0; e2 < 4; ++e2) {
                float am = (e2 == 0) ? a.x : (e2 == 1) ? a.y : (e2 == 2) ? a.z : a.w;
                const float4* pr = reinterpret_cast<const float4*>(Pl + (mg * 4 + e2) * 64 + j0);
                float4 p0 = pr[0], p1 = pr[1], p2 = pr[2], p3 = pr[3];
                acc[0] = fmaf(am, p0.x, acc[0]);  acc[1] = fmaf(am, p0.y, acc[1]);
                acc[2] = fmaf(am, p0.z, acc[2]);  acc[3] = fmaf(am, p0.w, acc[3]);
                acc[4] = fmaf(am, p1.x, acc[4]);  acc[5] = fmaf(am, p1.y, acc[5]);
                acc[6] = fmaf(am, p1.z, acc[6]);  acc[7] = fmaf(am, p1.w, acc[7]);
                acc[8] = fmaf(am, p2.x, acc[8]);  acc[9] = fmaf(am, p2.y, acc[9]);
                acc[10] = fmaf(am, p2.z, acc[10]); acc[11] = fmaf(am, p2.w, acc[11]);
                acc[12] = fmaf(am, p3.x, acc[12]); acc[13] = fmaf(am, p3.y, acc[13]);
                acc[14] = fmaf(am, p3.z, acc[14]); acc[15] = fmaf(am, p3.w, acc[15]);
            }
        }
        const int nxt = cur ^ 1;
        float* om = &sM[nxt][r * 68 + j0];
        om[0] = acc[0] + rq0.x;  om[1] = acc[1] + rq0.y;
        om[2] = acc[2] + rq0.z;  om[3] = acc[3] + rq0.w;
        om[4] = acc[4] + rq1.x;  om[5] = acc[5] + rq1.y;
        om[6] = acc[6] + rq1.z;  om[7] = acc[7] + rq1.w;
        om[8] = acc[8] + rq2.x;  om[9] = acc[9] + rq2.y;
        om[10] = acc[10] + rq2.z; om[11] = acc[11] + rq2.w;
        om[12] = acc[12] + rq3.x; om[13] = acc[13] + rq3.y;
        om[14] = acc[14] + rq3.z; om[15] = acc[15] + rq3.w;
        if (c + 1 < nc) {
            float4* s = reinterpret_cast<float4*>(sP[(c + 1) & 1]);
            s[tid] = rp0; s[tid + 256] = rp1; s[tid + 512] = rp2; s[tid + 768] = rp3;
        }
        __syncthreads();
        cur = nxt;
    }

    float4* mo = reinterpret_cast<float4*>(Mout + ((size_t)b * 64 + r) * 64 + j0);
    const float* fm = &sM[cur][r * 68 + j0];
    mo[0] = make_float4(fm[0], fm[1], fm[2], fm[3]);
    mo[1] = make_float4(fm[4], fm[5], fm[6], fm[7]);
    mo[2] = make_float4(fm[8], fm[9], fm[10], fm[11]);
    mo[3] = make_float4(fm[12], fm[13], fm[14], fm[15]);
}

// ---------------------------------------------------------------------------
// Attention read + second k/v projection (unchanged from round 3).
// ---------------------------------------------------------------------------
__global__ __launch_bounds__(256) void attn_kernel(
    const float* __restrict__ qg, const float* __restrict__ Mbuf,
    const float* __restrict__ Wk, const float* __restrict__ Wv,
    float* __restrict__ ks2, float* __restrict__ vs2)
{
    __shared__ __align__(16) float sM[64 * 65];
    __shared__ __align__(16) float sWkT[64 * 65];
    __shared__ __align__(16) float sWvT[64 * 65];
    __shared__ __align__(16) float sA[64 * 36];
    __shared__ __align__(16) float sB[64 * 36];

    const int b = blockIdx.y;
    const int tile0 = blockIdx.x * 32;
    const int tid = threadIdx.x;
    const int lane = tid & 63;
    const int t0 = (tid >> 6) * 8;
    const size_t qbase = (size_t)b * 2048 + tile0;

    for (int idx = tid; idx < 4096; idx += 256) {
        int rr = idx >> 6, cc = idx & 63;
        sM[rr * 65 + cc] = Mbuf[(size_t)b * 4096 + idx];
        sWkT[cc * 65 + rr] = Wk[idx];
        sWvT[cc * 65 + rr] = Wv[idx];
    }
    for (int it = tid; it < 512; it += 256) {
        int hg = it & 15, t = it >> 4;
        float4 qv = *reinterpret_cast<const float4*>(&qg[(qbase + t) * 64 + hg * 4]);
        sA[(hg * 4 + 0) * 36 + t] = qv.x;
        sA[(hg * 4 + 1) * 36 + t] = qv.y;
        sA[(hg * 4 + 2) * 36 + t] = qv.z;
        sA[(hg * 4 + 3) * 36 + t] = qv.w;
    }
    __syncthreads();

    float acc[8];
#pragma unroll
    for (int u = 0; u < 8; ++u) acc[u] = 0.f;
    for (int h = 0; h < 64; ++h) {
        float w = sM[h * 65 + lane];
        const float4* qp = reinterpret_cast<const float4*>(&sA[h * 36 + t0]);
        float4 q0 = qp[0], q1 = qp[1];
        acc[0] = fmaf(w, q0.x, acc[0]); acc[1] = fmaf(w, q0.y, acc[1]);
        acc[2] = fmaf(w, q0.z, acc[2]); acc[3] = fmaf(w, q0.w, acc[3]);
        acc[4] = fmaf(w, q1.x, acc[4]); acc[5] = fmaf(w, q1.y, acc[5]);
        acc[6] = fmaf(w, q1.z, acc[6]); acc[7] = fmaf(w, q1.w, acc[7]);
    }

#pragma unroll
    for (int u = 0; u < 8; ++u) {
        float sv = acc[u] * 0.125f;
        float mx = sv;
        for (int off = 32; off; off >>= 1) mx = fmaxf(mx, __shfl_xor(mx, off));
        float e = __expf(sv - mx);
        float sm = e;
        for (int off = 32; off; off >>= 1) sm += __shfl_xor(sm, off);
        acc[u] = e / sm;
    }
#pragma unroll
    for (int u = 0; u < 8; ++u) sB[lane * 36 + t0 + u] = acc[u];
    __syncthreads();

#pragma unroll
    for (int u = 0; u < 8; ++u) acc[u] = 0.f;
    for (int k = 0; k < 64; ++k) {
        float m = sM[lane * 65 + k];
        const float4* pp = reinterpret_cast<const float4*>(&sB[k * 36 + t0]);
        float4 p0 = pp[0], p1 = pp[1];
        acc[0] = fmaf(m, p0.x, acc[0]); acc[1] = fmaf(m, p0.y, acc[1]);
        acc[2] = fmaf(m, p0.z, acc[2]); acc[3] = fmaf(m, p0.w, acc[3]);
        acc[4] = fmaf(m, p1.x, acc[4]); acc[5] = fmaf(m, p1.y, acc[5]);
        acc[6] = fmaf(m, p1.z, acc[6]); acc[7] = fmaf(m, p1.w, acc[7]);
    }
#pragma unroll
    for (int u = 0; u < 8; ++u) sA[lane * 36 + t0 + u] = acc[u];
    __syncthreads();

    float ak[8], av[8];
#pragma unroll
    for (int u = 0; u < 8; ++u) { ak[u] = 0.f; av[u] = 0.f; }
    for (int h = 0; h < 64; ++h) {
        float wk = sWkT[h * 65 + lane];
        float wv = sWvT[h * 65 + lane];
        const float4* cp = reinterpret_cast<const float4*>(&sA[h * 36 + t0]);
        float4 c0 = cp[0], c1 = cp[1];
        ak[0] = fmaf(wk, c0.x, ak[0]); av[0] = fmaf(wv, c0.x, av[0]);
        ak[1] = fmaf(wk, c0.y, ak[1]); av[1] = fmaf(wv, c0.y, av[1]);
        ak[2] = fmaf(wk, c0.z, ak[2]); av[2] = fmaf(wv, c0.z, av[2]);
        ak[3] = fmaf(wk, c0.w, ak[3]); av[3] = fmaf(wv, c0.w, av[3]);
        ak[4] = fmaf(wk, c1.x, ak[4]); av[4] = fmaf(wv, c1.x, av[4]);
        ak[5] = fmaf(wk, c1.y, ak[5]); av[5] = fmaf(wv, c1.y, av[5]);
        ak[6] = fmaf(wk, c1.z, ak[6]); av[6] = fmaf(wv, c1.z, av[6]);
        ak[7] = fmaf(wk, c1.w, ak[7]); av[7] = fmaf(wv, c1.w, av[7]);
    }
#pragma unroll
    for (int u = 0; u < 8; ++u) {
        float ssq = ak[u] * ak[u];
        for (int off = 32; off; off >>= 1) ssq += __shfl_xor(ssq, off);
        float n = sqrtf(ssq);
        float sc = 1.f / fmaxf(n, 1e-12f);
        const size_t o = (qbase + t0 + u) * 64 + lane;
        ks2[o] = ak[u] * sc;
        vs2[o] = av[u];
    }
}

// ---------------------------------------------------------------------------
// Output: read = M2 @ q_last; out = read @ Wout^T + bout
// ---------------------------------------------------------------------------
__global__ __launch_bounds__(128) void out_kernel(
    const float* __restrict__ M2, const float* __restrict__ qlast,
    const float* __restrict__ Wout, const float* __restrict__ bout,
    float* __restrict__ out)
{
    const int b = blockIdx.x;
    const int tid = threadIdx.x;
    __shared__ float sq[64], sread[64];
    if (tid < 64) sq[tid] = qlast[b * 64 + tid];
    __syncthreads();
    if (tid < 64) {
        const float* Mr = M2 + ((size_t)b * 64 + tid) * 64;
        float acc = 0.f;
        for (int j = 0; j < 64; ++j) acc = fmaf(Mr[j], sq[j], acc);
        sread[tid] = acc;
    }
    __syncthreads();
    float acc = bout[tid];
    for (int h = 0; h < 64; ++h) acc = fmaf(Wout[tid * 64 + h], sread[h], acc);
    out[b * 128 + tid] = acc;
}

// ---------------------------------------------------------------------------
extern "C" void kernel_launch(void* const* d_in, const int* in_sizes, int n_in,
                              void* d_out, int out_size, void* d_ws, size_t ws_size,
                              hipStream_t stream)
{
    const int* x        = (const int*)d_in[0];
    const float* embed  = (const float*)d_in[1];
    const float* W1     = (const float*)d_in[2];
    const float* b1     = (const float*)d_in[3];
    const float* W2     = (const float*)d_in[4];
    const float* b2     = (const float*)d_in[5];
    const float* ln_g   = (const float*)d_in[6];
    const float* ln_b   = (const float*)d_in[7];
    const float* Wk     = (const float*)d_in[8];
    const float* Wv     = (const float*)d_in[9];
    const float* Wq     = (const float*)d_in[10];
    const float* Wattn  = (const float*)d_in[11];
    const float* Wout   = (const float*)d_in[12];
    const float* bout   = (const float*)d_in[13];

    // workspace layout (floats): ks | vs | q | qlast | M | M2
    float* ws = (float*)d_ws;
    float* ks = ws;
    float* vs = ks + (size_t)NB * SEQL * 64;
    float* qb = vs + (size_t)NB * SEQL * 64;
    float* ql = qb + (size_t)NB * 2048 * 64;
    float* M  = ql + (size_t)NB * 64;
    float* M2 = M + (size_t)NB * 64 * 64;
    if (ws_size < (size_t)(M2 + (size_t)NB * 64 * 64 - ws) * sizeof(float)) return;

    hipLaunchKernelGGL(encoder_kernel, dim3((NB * SEQL) / 64), dim3(256), 0, stream,
                       x, embed, W1, b1, W2, b2, ln_g, ln_b, Wk, Wv, Wq, Wattn,
                       ks, vs, qb, ql);

    // scan 1: L=4096, C=256 -> 16 chunks/batch, 1024 parallel chunk jobs
    const int C1 = 256, nc1 = SEQL / C1;
    hipLaunchKernelGGL(chunk_kernel, dim3(NB * nc1), dim3(256), 0, stream, ks, vs, C1);
    hipLaunchKernelGGL(combine_kernel, dim3(NB), dim3(256), 0, stream,
                       ks, vs, (const float*)nullptr, M, nc1, C1 * 64);

    // attention + second k/v projection (ks2/vs2 reuse ks/vs)
    hipLaunchKernelGGL(attn_kernel, dim3(64, NB), dim3(256), 0, stream,
                       qb, M, Wk, Wv, ks, vs);

    // scan 2: L=2048, C=128 -> 16 chunks/batch, 1024 parallel chunk jobs
    const int C2 = 128, nc2 = 2048 / C2;
    hipLaunchKernelGGL(chunk_kernel, dim3(NB * nc2), dim3(256), 0, stream, ks, vs, C2);
    hipLaunchKernelGGL(combine_kernel, dim3(NB), dim3(256), 0, stream,
                       ks, vs, M, M2, nc2, C2 * 64);

    hipLaunchKernelGGL(out_kernel, dim3(NB), dim3(128), 0, stream,
                       M2, ql, Wout, bout, (float*)d_out);
}

// Round 6
// 894.590 us; speedup vs baseline: 3.8785x; 1.0225x over previous
//
#include <hip/hip_runtime.h>

#define SEQL 4096
#define NB 64

// ---------------------------------------------------------------------------
// DPP quad-reductions: cross-lane xor-1 / xor-2 within lane quads on the VALU
// pipe (no ds_swizzle -> frees the LDS pipe in the scan hot loop).
// quad_perm[1,0,3,2] = 0xB1, quad_perm[2,3,0,1] = 0x4E.
// ---------------------------------------------------------------------------
__device__ __forceinline__ float dpp_xor1_add(float x) {
    int v = __builtin_amdgcn_mov_dpp(__float_as_int(x), 0xB1, 0xF, 0xF, true);
    return x + __int_as_float(v);
}
__device__ __forceinline__ float dpp_xor2_add(float x) {
    int v = __builtin_amdgcn_mov_dpp(__float_as_int(x), 0x4E, 0xF, 0xF, true);
    return x + __int_as_float(v);
}

// ---------------------------------------------------------------------------
// Encoder v3 (unchanged from round 5).
// ---------------------------------------------------------------------------
#define FMA16(A, W, H)                                      \
    A[0]  = fmaf(W.x, H.x, A[0]);  A[1]  = fmaf(W.x, H.y, A[1]);   \
    A[2]  = fmaf(W.x, H.z, A[2]);  A[3]  = fmaf(W.x, H.w, A[3]);   \
    A[4]  = fmaf(W.y, H.x, A[4]);  A[5]  = fmaf(W.y, H.y, A[5]);   \
    A[6]  = fmaf(W.y, H.z, A[6]);  A[7]  = fmaf(W.y, H.w, A[7]);   \
    A[8]  = fmaf(W.z, H.x, A[8]);  A[9]  = fmaf(W.z, H.y, A[9]);   \
    A[10] = fmaf(W.z, H.z, A[10]); A[11] = fmaf(W.z, H.w, A[11]);  \
    A[12] = fmaf(W.w, H.x, A[12]); A[13] = fmaf(W.w, H.y, A[13]);  \
    A[14] = fmaf(W.w, H.z, A[14]); A[15] = fmaf(W.w, H.w, A[15])

__device__ __forceinline__ void proj_tile64(const float* __restrict__ sW,
                                            const float* __restrict__ sA,
                                            int jq, int tq, float* __restrict__ a)
{
#pragma unroll
    for (int u = 0; u < 16; ++u) a[u] = 0.f;
#pragma unroll 2
    for (int i = 0; i < 64; ++i) {
        float4 w  = *reinterpret_cast<const float4*>(&sW[i * 68 + jq]);
        float4 h4 = *reinterpret_cast<const float4*>(&sA[i * 68 + tq]);
        FMA16(a, w, h4);
    }
}

__global__ __launch_bounds__(256) void encoder_kernel(
    const int* __restrict__ x, const float* __restrict__ embed,
    const float* __restrict__ W1, const float* __restrict__ b1,
    const float* __restrict__ W2, const float* __restrict__ b2,
    const float* __restrict__ ln_g, const float* __restrict__ ln_b,
    const float* __restrict__ Wk, const float* __restrict__ Wv,
    const float* __restrict__ Wq, const float* __restrict__ Wattn,
    float* __restrict__ ks, float* __restrict__ vs,
    float* __restrict__ qbuf, float* __restrict__ qlast)
{
    __shared__ __align__(16) float sZ[64 * 68];    // embed h -> hidden, [i][t]
    __shared__ __align__(16) float sF[128 * 68];   // ff1 relu out, [p][t]
    __shared__ __align__(16) float sW[64 * 68];    // staged weight half, [k][j]

    const int tid = threadIdx.x;
    const size_t g0 = (size_t)blockIdx.x * 64;
    const int b = (int)(g0 >> 12);
    const int l0 = (int)(g0 & (SEQL - 1));
    const int jq = (tid & 15) * 4;       // output channels jq..jq+3
    const int tq = (tid >> 4) * 4;       // tokens tq..tq+3

    // ---- embed gather -> sZ[i][t] (coalesced row reads) ----
    for (int idx = tid; idx < 4096; idx += 256) {
        int t = idx >> 6, i = idx & 63;
        sZ[i * 68 + t] = embed[(size_t)x[g0 + t] * 64 + i];
    }

    // ---- ff1: relu(W1 @ h + b1) -> sF, two j-halves ----
    for (int jh = 0; jh < 2; ++jh) {
        if (jh) __syncthreads();
        for (int idx = tid; idx < 4096; idx += 256) {
            int i = idx & 63, jj = idx >> 6;
            sW[i * 68 + jj] = W1[(size_t)(jh * 64 + jj) * 64 + i];
        }
        __syncthreads();
        float a[16];
        proj_tile64(sW, sZ, jq, tq, a);
        float4 bb = *reinterpret_cast<const float4*>(&b1[jh * 64 + jq]);
        float bv[4] = {bb.x, bb.y, bb.z, bb.w};
#pragma unroll
        for (int u = 0; u < 4; ++u) {
            float4 o;
            o.x = fmaxf(a[u * 4 + 0] + bv[u], 0.f);
            o.y = fmaxf(a[u * 4 + 1] + bv[u], 0.f);
            o.z = fmaxf(a[u * 4 + 2] + bv[u], 0.f);
            o.w = fmaxf(a[u * 4 + 3] + bv[u], 0.f);
            *reinterpret_cast<float4*>(&sF[(jh * 64 + jq + u) * 68 + tq]) = o;
        }
    }

    // ---- ff2: W2 @ f, K=128 in two p-halves, accumulate in regs ----
    float zacc[16];
#pragma unroll
    for (int u = 0; u < 16; ++u) zacc[u] = 0.f;
    for (int ph = 0; ph < 2; ++ph) {
        __syncthreads();
        for (int idx = tid; idx < 4096; idx += 256) {
            int p = idx & 63, j = idx >> 6;
            sW[p * 68 + j] = W2[(size_t)j * 128 + ph * 64 + p];
        }
        __syncthreads();
#pragma unroll 2
        for (int p = 0; p < 64; ++p) {
            float4 w  = *reinterpret_cast<const float4*>(&sW[p * 68 + jq]);
            float4 f4 = *reinterpret_cast<const float4*>(&sF[(ph * 64 + p) * 68 + tq]);
            FMA16(zacc, w, f4);
        }
    }

    // ---- residual + LayerNorm ----
    {
        float z[16];
        float4 b2v = *reinterpret_cast<const float4*>(&b2[jq]);
        float bv[4] = {b2v.x, b2v.y, b2v.z, b2v.w};
#pragma unroll
        for (int u = 0; u < 4; ++u) {
            float4 h4 = *reinterpret_cast<const float4*>(&sZ[(jq + u) * 68 + tq]);
            z[u * 4 + 0] = h4.x + bv[u] + zacc[u * 4 + 0];
            z[u * 4 + 1] = h4.y + bv[u] + zacc[u * 4 + 1];
            z[u * 4 + 2] = h4.z + bv[u] + zacc[u * 4 + 2];
            z[u * 4 + 3] = h4.w + bv[u] + zacc[u * 4 + 3];
        }
        float s[4], ss[4];
#pragma unroll
        for (int v = 0; v < 4; ++v) {
            s[v]  = z[v] + z[4 + v] + z[8 + v] + z[12 + v];
            ss[v] = z[v] * z[v] + z[4 + v] * z[4 + v]
                  + z[8 + v] * z[8 + v] + z[12 + v] * z[12 + v];
        }
#pragma unroll
        for (int m = 1; m <= 8; m <<= 1) {
#pragma unroll
            for (int v = 0; v < 4; ++v) {
                s[v]  += __shfl_xor(s[v], m);
                ss[v] += __shfl_xor(ss[v], m);
            }
        }
        float mu[4], inv[4];
#pragma unroll
        for (int v = 0; v < 4; ++v) {
            mu[v] = s[v] * 0.015625f;
            float var = ss[v] * 0.015625f - mu[v] * mu[v];
            inv[v] = rsqrtf(var + 1e-5f);
        }
        float4 g4  = *reinterpret_cast<const float4*>(&ln_g[jq]);
        float4 be4 = *reinterpret_cast<const float4*>(&ln_b[jq]);
        float gv[4] = {g4.x, g4.y, g4.z, g4.w};
        float bev[4] = {be4.x, be4.y, be4.z, be4.w};
#pragma unroll
        for (int u = 0; u < 4; ++u) {
            float4 o;
            o.x = (z[u * 4 + 0] - mu[0]) * inv[0] * gv[u] + bev[u];
            o.y = (z[u * 4 + 1] - mu[1]) * inv[1] * gv[u] + bev[u];
            o.z = (z[u * 4 + 2] - mu[2]) * inv[2] * gv[u] + bev[u];
            o.w = (z[u * 4 + 3] - mu[3]) * inv[3] * gv[u] + bev[u];
            *reinterpret_cast<float4*>(&sZ[(jq + u) * 68 + tq]) = o;
        }
    }

    // ---- k projection + l2norm ----
    {
        __syncthreads();
        for (int idx = tid; idx < 4096; idx += 256) {
            int i = idx & 63, j = idx >> 6;
            sW[i * 68 + j] = Wk[(size_t)j * 64 + i];
        }
        __syncthreads();
        float a[16];
        proj_tile64(sW, sZ, jq, tq, a);
        float ssq[4];
#pragma unroll
        for (int v = 0; v < 4; ++v)
            ssq[v] = a[v] * a[v] + a[4 + v] * a[4 + v]
                   + a[8 + v] * a[8 + v] + a[12 + v] * a[12 + v];
#pragma unroll
        for (int m = 1; m <= 8; m <<= 1) {
#pragma unroll
            for (int v = 0; v < 4; ++v) ssq[v] += __shfl_xor(ssq[v], m);
        }
#pragma unroll
        for (int v = 0; v < 4; ++v) {
            float sc = 1.f / fmaxf(sqrtf(ssq[v]), 1e-12f);
            float4 o = make_float4(a[v] * sc, a[4 + v] * sc, a[8 + v] * sc, a[12 + v] * sc);
            *reinterpret_cast<float4*>(&ks[(g0 + tq + v) * 64 + jq]) = o;
        }
    }

    // ---- v projection ----
    {
        __syncthreads();
        for (int idx = tid; idx < 4096; idx += 256) {
            int i = idx & 63, j = idx >> 6;
            sW[i * 68 + j] = Wv[(size_t)j * 64 + i];
        }
        __syncthreads();
        float a[16];
        proj_tile64(sW, sZ, jq, tq, a);
#pragma unroll
        for (int v = 0; v < 4; ++v) {
            float4 o = make_float4(a[v], a[4 + v], a[8 + v], a[12 + v]);
            *reinterpret_cast<float4*>(&vs[(g0 + tq + v) * 64 + jq]) = o;
        }
    }

    // ---- q projection (first-half blocks only) ----
    if (l0 < 2048) {
        __syncthreads();
        for (int idx = tid; idx < 4096; idx += 256) {
            int i = idx & 63, j = idx >> 6;
            sW[i * 68 + j] = Wattn[(size_t)j * 64 + i];
        }
        __syncthreads();
        float a[16];
        proj_tile64(sW, sZ, jq, tq, a);
#pragma unroll
        for (int v = 0; v < 4; ++v) {
            float4 o = make_float4(a[v], a[4 + v], a[8 + v], a[12 + v]);
            *reinterpret_cast<float4*>(&qbuf[((size_t)b * 2048 + l0 + tq + v) * 64 + jq]) = o;
        }
    }

    // ---- q_last ----
    if (l0 == SEQL - 64) {
        __syncthreads();
        for (int idx = tid; idx < 4096; idx += 256) {
            int i = idx & 63, j = idx >> 6;
            sW[i * 68 + j] = Wq[(size_t)j * 64 + i];
        }
        __syncthreads();
        float a[16];
        proj_tile64(sW, sZ, jq, tq, a);
        if ((tid >> 4) == 15) {
            float4 o = make_float4(a[3], a[7], a[11], a[15]);
            *reinterpret_cast<float4*>(&qlast[(size_t)b * 64 + jq]) = o;
        }
    }
}

// ---------------------------------------------------------------------------
// Chunked delta scan, phase A. Quad reduction now via DPP (VALU pipe) instead
// of ds_swizzle shuffles (LDS pipe) -> hot loop issues zero DS ops.
// ---------------------------------------------------------------------------
#define STEP2(K0, K1, K2, K3, V)                                                \
    do {                                                                        \
        float dp0 = fmaf(p[0], K0.x, fmaf(p[1], K0.y, fmaf(p[2], K0.z, p[3] * K0.w))); \
        float dp1 = fmaf(p[4], K1.x, fmaf(p[5], K1.y, fmaf(p[6], K1.z, p[7] * K1.w))); \
        float dp2 = fmaf(p[8], K2.x, fmaf(p[9], K2.y, fmaf(p[10], K2.z, p[11] * K2.w))); \
        float dp3 = fmaf(p[12], K3.x, fmaf(p[13], K3.y, fmaf(p[14], K3.z, p[15] * K3.w))); \
        float dq0 = fmaf(q[0], K0.x, fmaf(q[1], K0.y, fmaf(q[2], K0.z, q[3] * K0.w))); \
        float dq1 = fmaf(q[4], K1.x, fmaf(q[5], K1.y, fmaf(q[6], K1.z, q[7] * K1.w))); \
        float dq2 = fmaf(q[8], K2.x, fmaf(q[9], K2.y, fmaf(q[10], K2.z, q[11] * K2.w))); \
        float dq3 = fmaf(q[12], K3.x, fmaf(q[13], K3.y, fmaf(q[14], K3.z, q[15] * K3.w))); \
        float ddp = (dp0 + dp1) + (dp2 + dp3);                                  \
        float ddq = (dq0 + dq1) + (dq2 + dq3);                                  \
        ddp = dpp_xor1_add(ddp);  ddq = dpp_xor1_add(ddq);                      \
        ddp = dpp_xor2_add(ddp);  ddq = dpp_xor2_add(ddq);                      \
        float up = -ddp;                                                        \
        float uq = V - ddq;                                                     \
        p[0] = fmaf(up, K0.x, p[0]);   q[0] = fmaf(uq, K0.x, q[0]);             \
        p[1] = fmaf(up, K0.y, p[1]);   q[1] = fmaf(uq, K0.y, q[1]);             \
        p[2] = fmaf(up, K0.z, p[2]);   q[2] = fmaf(uq, K0.z, q[2]);             \
        p[3] = fmaf(up, K0.w, p[3]);   q[3] = fmaf(uq, K0.w, q[3]);             \
        p[4] = fmaf(up, K1.x, p[4]);   q[4] = fmaf(uq, K1.x, q[4]);             \
        p[5] = fmaf(up, K1.y, p[5]);   q[5] = fmaf(uq, K1.y, q[5]);             \
        p[6] = fmaf(up, K1.z, p[6]);   q[6] = fmaf(uq, K1.z, q[6]);             \
        p[7] = fmaf(up, K1.w, p[7]);   q[7] = fmaf(uq, K1.w, q[7]);             \
        p[8] = fmaf(up, K2.x, p[8]);   q[8] = fmaf(uq, K2.x, q[8]);             \
        p[9] = fmaf(up, K2.y, p[9]);   q[9] = fmaf(uq, K2.y, q[9]);             \
        p[10] = fmaf(up, K2.z, p[10]); q[10] = fmaf(uq, K2.z, q[10]);           \
        p[11] = fmaf(up, K2.w, p[11]); q[11] = fmaf(uq, K2.w, q[11]);           \
        p[12] = fmaf(up, K3.x, p[12]); q[12] = fmaf(uq, K3.x, q[12]);           \
        p[13] = fmaf(up, K3.y, p[13]); q[13] = fmaf(uq, K3.y, q[13]);           \
        p[14] = fmaf(up, K3.z, p[14]); q[14] = fmaf(uq, K3.z, q[14]);           \
        p[15] = fmaf(up, K3.w, p[15]); q[15] = fmaf(uq, K3.w, q[15]);           \
    } while (0)

__global__ __launch_bounds__(256) void chunk_kernel(
    float* __restrict__ ksb, float* __restrict__ vsb, int C)
{
    const int job = blockIdx.x;
    const int tid = threadIdx.x;
    const int r = tid >> 2;
    const int c0 = (tid & 3) * 16;
    float* kc = ksb + (size_t)job * C * 64;
    float* vc = vsb + (size_t)job * C * 64;

    float p[16], q[16];
#pragma unroll
    for (int j = 0; j < 16; ++j) { p[j] = (c0 + j == r) ? 1.f : 0.f; q[j] = 0.f; }

    const float* kb = kc + c0;
    const float* vp = vc + r;

    float4 a0, a1, a2, a3, e0, e1, e2, e3;
    float va, ve;
    {
        const float4* kp = reinterpret_cast<const float4*>(kb);
        a0 = kp[0]; a1 = kp[1]; a2 = kp[2]; a3 = kp[3];
        va = vp[0];
    }
    for (int t = 0; t < C; t += 2) {
        {
            const float4* kp = reinterpret_cast<const float4*>(kb + (size_t)(t + 1) * 64);
            e0 = kp[0]; e1 = kp[1]; e2 = kp[2]; e3 = kp[3];
            ve = vp[(size_t)(t + 1) * 64];
        }
        STEP2(a0, a1, a2, a3, va);
        if (t + 2 < C) {
            const float4* kp = reinterpret_cast<const float4*>(kb + (size_t)(t + 2) * 64);
            a0 = kp[0]; a1 = kp[1]; a2 = kp[2]; a3 = kp[3];
            va = vp[(size_t)(t + 2) * 64];
        }
        STEP2(e0, e1, e2, e3, ve);
    }

    float4* po = reinterpret_cast<float4*>(kc + r * 64 + c0);
    po[0] = make_float4(p[0], p[1], p[2], p[3]);
    po[1] = make_float4(p[4], p[5], p[6], p[7]);
    po[2] = make_float4(p[8], p[9], p[10], p[11]);
    po[3] = make_float4(p[12], p[13], p[14], p[15]);
    float4* qo = reinterpret_cast<float4*>(vc + r * 64 + c0);
    qo[0] = make_float4(q[0], q[1], q[2], q[3]);
    qo[1] = make_float4(q[4], q[5], q[6], q[7]);
    qo[2] = make_float4(q[8], q[9], q[10], q[11]);
    qo[3] = make_float4(q[12], q[13], q[14], q[15]);
}

// ---------------------------------------------------------------------------
// Chunked delta scan, phase B (unchanged).
// ---------------------------------------------------------------------------
__global__ __launch_bounds__(256) void combine_kernel(
    const float* __restrict__ Pb, const float* __restrict__ Qb,
    const float* __restrict__ Min, float* __restrict__ Mout,
    int nc, int chunk_stride)
{
    __shared__ __align__(16) float sM[2][64 * 68];
    __shared__ __align__(16) float sP[2][64 * 64];
    const int b = blockIdx.x;
    const int tid = threadIdx.x;
    const int r = tid >> 2;
    const int j0 = (tid & 3) * 16;

    if (Min) {
        const float4* mi = reinterpret_cast<const float4*>(Min + ((size_t)b * 64 + r) * 64 + j0);
        float4* mo = reinterpret_cast<float4*>(&sM[0][r * 68 + j0]);
#pragma unroll
        for (int u = 0; u < 4; ++u) mo[u] = mi[u];
    } else {
#pragma unroll
        for (int u = 0; u < 16; ++u) sM[0][r * 68 + j0 + u] = 0.f;
    }
    {
        const float4* g = reinterpret_cast<const float4*>(Pb + (size_t)b * nc * chunk_stride);
        float4* s = reinterpret_cast<float4*>(sP[0]);
        for (int i = tid; i < 1024; i += 256) s[i] = g[i];
    }
    __syncthreads();

    int cur = 0;
    for (int c = 0; c < nc; ++c) {
        const size_t cbase = (size_t)(b * nc + c) * chunk_stride;
        float4 rp0, rp1, rp2, rp3;
        if (c + 1 < nc) {
            const float4* g = reinterpret_cast<const float4*>(Pb + cbase + chunk_stride);
            rp0 = g[tid]; rp1 = g[tid + 256]; rp2 = g[tid + 512]; rp3 = g[tid + 768];
        }
        float4 rq0, rq1, rq2, rq3;
        {
            const float4* gq = reinterpret_cast<const float4*>(Qb + cbase + r * 64 + j0);
            rq0 = gq[0]; rq1 = gq[1]; rq2 = gq[2]; rq3 = gq[3];
        }
        float acc[16];
#pragma unroll
        for (int u = 0; u < 16; ++u) acc[u] = 0.f;
        const float* Mrow = &sM[cur][r * 68];
        const float* Pl = sP[c & 1];
#pragma unroll
        for (int mg = 0; mg < 16; ++mg) {
            float4 a = *reinterpret_cast<const float4*>(Mrow + mg * 4);
#pragma unroll
            for (int e2 = 0; e2 < 4; ++e2) {
                float am = (e2 == 0) ? a.x : (e2 == 1) ? a.y : (e2 == 2) ? a.z : a.w;
                const float4* pr = reinterpret_cast<const float4*>(Pl + (mg * 4 + e2) * 64 + j0);
                float4 p0 = pr[0], p1 = pr[1], p2 = pr[2], p3 = pr[3];
                acc[0] = fmaf(am, p0.x, acc[0]);  acc[1] = fmaf(am, p0.y, acc[1]);
                acc[2] = fmaf(am, p0.z, acc[2]);  acc[3] = fmaf(am, p0.w, acc[3]);
                acc[4] = fmaf(am, p1.x, acc[4]);  acc[5] = fmaf(am, p1.y, acc[5]);
                acc[6] = fmaf(am, p1.z, acc[6]);  acc[7] = fmaf(am, p1.w, acc[7]);
                acc[8] = fmaf(am, p2.x, acc[8]);  acc[9] = fmaf(am, p2.y, acc[9]);
                acc[10] = fmaf(am, p2.z, acc[10]); acc[11] = fmaf(am, p2.w, acc[11]);
                acc[12] = fmaf(am, p3.x, acc[12]); acc[13] = fmaf(am, p3.y, acc[13]);
                acc[14] = fmaf(am, p3.z, acc[14]); acc[15] = fmaf(am, p3.w, acc[15]);
            }
        }
        const int nxt = cur ^ 1;
        float* om = &sM[nxt][r * 68 + j0];
        om[0] = acc[0] + rq0.x;  om[1] = acc[1] + rq0.y;
        om[2] = acc[2] + rq0.z;  om[3] = acc[3] + rq0.w;
        om[4] = acc[4] + rq1.x;  om[5] = acc[5] + rq1.y;
        om[6] = acc[6] + rq1.z;  om[7] = acc[7] + rq1.w;
        om[8] = acc[8] + rq2.x;  om[9] = acc[9] + rq2.y;
        om[10] = acc[10] + rq2.z; om[11] = acc[11] + rq2.w;
        om[12] = acc[12] + rq3.x; om[13] = acc[13] + rq3.y;
        om[14] = acc[14] + rq3.z; om[15] = acc[15] + rq3.w;
        if (c + 1 < nc) {
            float4* s = reinterpret_cast<float4*>(sP[(c + 1) & 1]);
            s[tid] = rp0; s[tid + 256] = rp1; s[tid + 512] = rp2; s[tid + 768] = rp3;
        }
        __syncthreads();
        cur = nxt;
    }

    float4* mo = reinterpret_cast<float4*>(Mout + ((size_t)b * 64 + r) * 64 + j0);
    const float* fm = &sM[cur][r * 68 + j0];
    mo[0] = make_float4(fm[0], fm[1], fm[2], fm[3]);
    mo[1] = make_float4(fm[4], fm[5], fm[6], fm[7]);
    mo[2] = make_float4(fm[8], fm[9], fm[10], fm[11]);
    mo[3] = make_float4(fm[12], fm[13], fm[14], fm[15]);
}

// ---------------------------------------------------------------------------
// Attention read + second k/v projection (unchanged from round 3).
// ---------------------------------------------------------------------------
__global__ __launch_bounds__(256) void attn_kernel(
    const float* __restrict__ qg, const float* __restrict__ Mbuf,
    const float* __restrict__ Wk, const float* __restrict__ Wv,
    float* __restrict__ ks2, float* __restrict__ vs2)
{
    __shared__ __align__(16) float sM[64 * 65];
    __shared__ __align__(16) float sWkT[64 * 65];
    __shared__ __align__(16) float sWvT[64 * 65];
    __shared__ __align__(16) float sA[64 * 36];
    __shared__ __align__(16) float sB[64 * 36];

    const int b = blockIdx.y;
    const int tile0 = blockIdx.x * 32;
    const int tid = threadIdx.x;
    const int lane = tid & 63;
    const int t0 = (tid >> 6) * 8;
    const size_t qbase = (size_t)b * 2048 + tile0;

    for (int idx = tid; idx < 4096; idx += 256) {
        int rr = idx >> 6, cc = idx & 63;
        sM[rr * 65 + cc] = Mbuf[(size_t)b * 4096 + idx];
        sWkT[cc * 65 + rr] = Wk[idx];
        sWvT[cc * 65 + rr] = Wv[idx];
    }
    for (int it = tid; it < 512; it += 256) {
        int hg = it & 15, t = it >> 4;
        float4 qv = *reinterpret_cast<const float4*>(&qg[(qbase + t) * 64 + hg * 4]);
        sA[(hg * 4 + 0) * 36 + t] = qv.x;
        sA[(hg * 4 + 1) * 36 + t] = qv.y;
        sA[(hg * 4 + 2) * 36 + t] = qv.z;
        sA[(hg * 4 + 3) * 36 + t] = qv.w;
    }
    __syncthreads();

    float acc[8];
#pragma unroll
    for (int u = 0; u < 8; ++u) acc[u] = 0.f;
    for (int h = 0; h < 64; ++h) {
        float w = sM[h * 65 + lane];
        const float4* qp = reinterpret_cast<const float4*>(&sA[h * 36 + t0]);
        float4 q0 = qp[0], q1 = qp[1];
        acc[0] = fmaf(w, q0.x, acc[0]); acc[1] = fmaf(w, q0.y, acc[1]);
        acc[2] = fmaf(w, q0.z, acc[2]); acc[3] = fmaf(w, q0.w, acc[3]);
        acc[4] = fmaf(w, q1.x, acc[4]); acc[5] = fmaf(w, q1.y, acc[5]);
        acc[6] = fmaf(w, q1.z, acc[6]); acc[7] = fmaf(w, q1.w, acc[7]);
    }

#pragma unroll
    for (int u = 0; u < 8; ++u) {
        float sv = acc[u] * 0.125f;
        float mx = sv;
        for (int off = 32; off; off >>= 1) mx = fmaxf(mx, __shfl_xor(mx, off));
        float e = __expf(sv - mx);
        float sm = e;
        for (int off = 32; off; off >>= 1) sm += __shfl_xor(sm, off);
        acc[u] = e / sm;
    }
#pragma unroll
    for (int u = 0; u < 8; ++u) sB[lane * 36 + t0 + u] = acc[u];
    __syncthreads();

#pragma unroll
    for (int u = 0; u < 8; ++u) acc[u] = 0.f;
    for (int k = 0; k < 64; ++k) {
        float m = sM[lane * 65 + k];
        const float4* pp = reinterpret_cast<const float4*>(&sB[k * 36 + t0]);
        float4 p0 = pp[0], p1 = pp[1];
        acc[0] = fmaf(m, p0.x, acc[0]); acc[1] = fmaf(m, p0.y, acc[1]);
        acc[2] = fmaf(m, p0.z, acc[2]); acc[3] = fmaf(m, p0.w, acc[3]);
        acc[4] = fmaf(m, p1.x, acc[4]); acc[5] = fmaf(m, p1.y, acc[5]);
        acc[6] = fmaf(m, p1.z, acc[6]); acc[7] = fmaf(m, p1.w, acc[7]);
    }
#pragma unroll
    for (int u = 0; u < 8; ++u) sA[lane * 36 + t0 + u] = acc[u];
    __syncthreads();

    float ak[8], av[8];
#pragma unroll
    for (int u = 0; u < 8; ++u) { ak[u] = 0.f; av[u] = 0.f; }
    for (int h = 0; h < 64; ++h) {
        float wk = sWkT[h * 65 + lane];
        float wv = sWvT[h * 65 + lane];
        const float4* cp = reinterpret_cast<const float4*>(&sA[h * 36 + t0]);
        float4 c0 = cp[0], c1 = cp[1];
        ak[0] = fmaf(wk, c0.x, ak[0]); av[0] = fmaf(wv, c0.x, av[0]);
        ak[1] = fmaf(wk, c0.y, ak[1]); av[1] = fmaf(wv, c0.y, av[1]);
        ak[2] = fmaf(wk, c0.z, ak[2]); av[2] = fmaf(wv, c0.z, av[2]);
        ak[3] = fmaf(wk, c0.w, ak[3]); av[3] = fmaf(wv, c0.w, av[3]);
        ak[4] = fmaf(wk, c1.x, ak[4]); av[4] = fmaf(wv, c1.x, av[4]);
        ak[5] = fmaf(wk, c1.y, ak[5]); av[5] = fmaf(wv, c1.y, av[5]);
        ak[6] = fmaf(wk, c1.z, ak[6]); av[6] = fmaf(wv, c1.z, av[6]);
        ak[7] = fmaf(wk, c1.w, ak[7]); av[7] = fmaf(wv, c1.w, av[7]);
    }
#pragma unroll
    for (int u = 0; u < 8; ++u) {
        float ssq = ak[u] * ak[u];
        for (int off = 32; off; off >>= 1) ssq += __shfl_xor(ssq, off);
        float n = sqrtf(ssq);
        float sc = 1.f / fmaxf(n, 1e-12f);
        const size_t o = (qbase + t0 + u) * 64 + lane;
        ks2[o] = ak[u] * sc;
        vs2[o] = av[u];
    }
}

// ---------------------------------------------------------------------------
// Output: read = M2 @ q_last; out = read @ Wout^T + bout
// ---------------------------------------------------------------------------
__global__ __launch_bounds__(128) void out_kernel(
    const float* __restrict__ M2, const float* __restrict__ qlast,
    const float* __restrict__ Wout, const float* __restrict__ bout,
    float* __restrict__ out)
{
    const int b = blockIdx.x;
    const int tid = threadIdx.x;
    __shared__ float sq[64], sread[64];
    if (tid < 64) sq[tid] = qlast[b * 64 + tid];
    __syncthreads();
    if (tid < 64) {
        const float* Mr = M2 + ((size_t)b * 64 + tid) * 64;
        float acc = 0.f;
        for (int j = 0; j < 64; ++j) acc = fmaf(Mr[j], sq[j], acc);
        sread[tid] = acc;
    }
    __syncthreads();
    float acc = bout[tid];
    for (int h = 0; h < 64; ++h) acc = fmaf(Wout[tid * 64 + h], sread[h], acc);
    out[b * 128 + tid] = acc;
}

// ---------------------------------------------------------------------------
extern "C" void kernel_launch(void* const* d_in, const int* in_sizes, int n_in,
                              void* d_out, int out_size, void* d_ws, size_t ws_size,
                              hipStream_t stream)
{
    const int* x        = (const int*)d_in[0];
    const float* embed  = (const float*)d_in[1];
    const float* W1     = (const float*)d_in[2];
    const float* b1     = (const float*)d_in[3];
    const float* W2     = (const float*)d_in[4];
    const float* b2     = (const float*)d_in[5];
    const float* ln_g   = (const float*)d_in[6];
    const float* ln_b   = (const float*)d_in[7];
    const float* Wk     = (const float*)d_in[8];
    const float* Wv     = (const float*)d_in[9];
    const float* Wq     = (const float*)d_in[10];
    const float* Wattn  = (const float*)d_in[11];
    const float* Wout   = (const float*)d_in[12];
    const float* bout   = (const float*)d_in[13];

    // workspace layout (floats): ks | vs | q | qlast | M | M2
    float* ws = (float*)d_ws;
    float* ks = ws;
    float* vs = ks + (size_t)NB * SEQL * 64;
    float* qb = vs + (size_t)NB * SEQL * 64;
    float* ql = qb + (size_t)NB * 2048 * 64;
    float* M  = ql + (size_t)NB * 64;
    float* M2 = M + (size_t)NB * 64 * 64;
    if (ws_size < (size_t)(M2 + (size_t)NB * 64 * 64 - ws) * sizeof(float)) return;

    hipLaunchKernelGGL(encoder_kernel, dim3((NB * SEQL) / 64), dim3(256), 0, stream,
                       x, embed, W1, b1, W2, b2, ln_g, ln_b, Wk, Wv, Wq, Wattn,
                       ks, vs, qb, ql);

    // scan 1: L=4096, C=256 -> 16 chunks/batch, 1024 parallel chunk jobs
    const int C1 = 256, nc1 = SEQL / C1;
    hipLaunchKernelGGL(chunk_kernel, dim3(NB * nc1), dim3(256), 0, stream, ks, vs, C1);
    hipLaunchKernelGGL(combine_kernel, dim3(NB), dim3(256), 0, stream,
                       ks, vs, (const float*)nullptr, M, nc1, C1 * 64);

    // attention + second k/v projection (ks2/vs2 reuse ks/vs)
    hipLaunchKernelGGL(attn_kernel, dim3(64, NB), dim3(256), 0, stream,
                       qb, M, Wk, Wv, ks, vs);

    // scan 2: L=2048, C=128 -> 16 chunks/batch, 1024 parallel chunk jobs
    const int C2 = 128, nc2 = 2048 / C2;
    hipLaunchKernelGGL(chunk_kernel, dim3(NB * nc2), dim3(256), 0, stream, ks, vs, C2);
    hipLaunchKernelGGL(combine_kernel, dim3(NB), dim3(256), 0, stream,
                       ks, vs, M, M2, nc2, C2 * 64);

    hipLaunchKernelGGL(out_kernel, dim3(NB), dim3(128), 0, stream,
                       M2, ql, Wout, bout, (float*)d_out);
}

// Round 7
// 875.481 us; speedup vs baseline: 3.9632x; 1.0218x over previous
//
#include <hip/hip_runtime.h>

#define SEQL 4096
#define NB 64

// ---------------------------------------------------------------------------
// DPP quad-reductions (VALU pipe, no DS ops).
// ---------------------------------------------------------------------------
__device__ __forceinline__ float dpp_xor1_add(float x) {
    int v = __builtin_amdgcn_mov_dpp(__float_as_int(x), 0xB1, 0xF, 0xF, true);
    return x + __int_as_float(v);
}
__device__ __forceinline__ float dpp_xor2_add(float x) {
    int v = __builtin_amdgcn_mov_dpp(__float_as_int(x), 0x4E, 0xF, 0xF, true);
    return x + __int_as_float(v);
}

// ---------------------------------------------------------------------------
// Encoder v3 (unchanged from round 5).
// ---------------------------------------------------------------------------
#define FMA16(A, W, H)                                      \
    A[0]  = fmaf(W.x, H.x, A[0]);  A[1]  = fmaf(W.x, H.y, A[1]);   \
    A[2]  = fmaf(W.x, H.z, A[2]);  A[3]  = fmaf(W.x, H.w, A[3]);   \
    A[4]  = fmaf(W.y, H.x, A[4]);  A[5]  = fmaf(W.y, H.y, A[5]);   \
    A[6]  = fmaf(W.y, H.z, A[6]);  A[7]  = fmaf(W.y, H.w, A[7]);   \
    A[8]  = fmaf(W.z, H.x, A[8]);  A[9]  = fmaf(W.z, H.y, A[9]);   \
    A[10] = fmaf(W.z, H.z, A[10]); A[11] = fmaf(W.z, H.w, A[11]);  \
    A[12] = fmaf(W.w, H.x, A[12]); A[13] = fmaf(W.w, H.y, A[13]);  \
    A[14] = fmaf(W.w, H.z, A[14]); A[15] = fmaf(W.w, H.w, A[15])

__device__ __forceinline__ void proj_tile64(const float* __restrict__ sW,
                                            const float* __restrict__ sA,
                                            int jq, int tq, float* __restrict__ a)
{
#pragma unroll
    for (int u = 0; u < 16; ++u) a[u] = 0.f;
#pragma unroll 2
    for (int i = 0; i < 64; ++i) {
        float4 w  = *reinterpret_cast<const float4*>(&sW[i * 68 + jq]);
        float4 h4 = *reinterpret_cast<const float4*>(&sA[i * 68 + tq]);
        FMA16(a, w, h4);
    }
}

__global__ __launch_bounds__(256) void encoder_kernel(
    const int* __restrict__ x, const float* __restrict__ embed,
    const float* __restrict__ W1, const float* __restrict__ b1,
    const float* __restrict__ W2, const float* __restrict__ b2,
    const float* __restrict__ ln_g, const float* __restrict__ ln_b,
    const float* __restrict__ Wk, const float* __restrict__ Wv,
    const float* __restrict__ Wq, const float* __restrict__ Wattn,
    float* __restrict__ ks, float* __restrict__ vs,
    float* __restrict__ qbuf, float* __restrict__ qlast)
{
    __shared__ __align__(16) float sZ[64 * 68];
    __shared__ __align__(16) float sF[128 * 68];
    __shared__ __align__(16) float sW[64 * 68];

    const int tid = threadIdx.x;
    const size_t g0 = (size_t)blockIdx.x * 64;
    const int b = (int)(g0 >> 12);
    const int l0 = (int)(g0 & (SEQL - 1));
    const int jq = (tid & 15) * 4;
    const int tq = (tid >> 4) * 4;

    for (int idx = tid; idx < 4096; idx += 256) {
        int t = idx >> 6, i = idx & 63;
        sZ[i * 68 + t] = embed[(size_t)x[g0 + t] * 64 + i];
    }

    for (int jh = 0; jh < 2; ++jh) {
        if (jh) __syncthreads();
        for (int idx = tid; idx < 4096; idx += 256) {
            int i = idx & 63, jj = idx >> 6;
            sW[i * 68 + jj] = W1[(size_t)(jh * 64 + jj) * 64 + i];
        }
        __syncthreads();
        float a[16];
        proj_tile64(sW, sZ, jq, tq, a);
        float4 bb = *reinterpret_cast<const float4*>(&b1[jh * 64 + jq]);
        float bv[4] = {bb.x, bb.y, bb.z, bb.w};
#pragma unroll
        for (int u = 0; u < 4; ++u) {
            float4 o;
            o.x = fmaxf(a[u * 4 + 0] + bv[u], 0.f);
            o.y = fmaxf(a[u * 4 + 1] + bv[u], 0.f);
            o.z = fmaxf(a[u * 4 + 2] + bv[u], 0.f);
            o.w = fmaxf(a[u * 4 + 3] + bv[u], 0.f);
            *reinterpret_cast<float4*>(&sF[(jh * 64 + jq + u) * 68 + tq]) = o;
        }
    }

    float zacc[16];
#pragma unroll
    for (int u = 0; u < 16; ++u) zacc[u] = 0.f;
    for (int ph = 0; ph < 2; ++ph) {
        __syncthreads();
        for (int idx = tid; idx < 4096; idx += 256) {
            int p = idx & 63, j = idx >> 6;
            sW[p * 68 + j] = W2[(size_t)j * 128 + ph * 64 + p];
        }
        __syncthreads();
#pragma unroll 2
        for (int p = 0; p < 64; ++p) {
            float4 w  = *reinterpret_cast<const float4*>(&sW[p * 68 + jq]);
            float4 f4 = *reinterpret_cast<const float4*>(&sF[(ph * 64 + p) * 68 + tq]);
            FMA16(zacc, w, f4);
        }
    }

    {
        float z[16];
        float4 b2v = *reinterpret_cast<const float4*>(&b2[jq]);
        float bv[4] = {b2v.x, b2v.y, b2v.z, b2v.w};
#pragma unroll
        for (int u = 0; u < 4; ++u) {
            float4 h4 = *reinterpret_cast<const float4*>(&sZ[(jq + u) * 68 + tq]);
            z[u * 4 + 0] = h4.x + bv[u] + zacc[u * 4 + 0];
            z[u * 4 + 1] = h4.y + bv[u] + zacc[u * 4 + 1];
            z[u * 4 + 2] = h4.z + bv[u] + zacc[u * 4 + 2];
            z[u * 4 + 3] = h4.w + bv[u] + zacc[u * 4 + 3];
        }
        float s[4], ss[4];
#pragma unroll
        for (int v = 0; v < 4; ++v) {
            s[v]  = z[v] + z[4 + v] + z[8 + v] + z[12 + v];
            ss[v] = z[v] * z[v] + z[4 + v] * z[4 + v]
                  + z[8 + v] * z[8 + v] + z[12 + v] * z[12 + v];
        }
#pragma unroll
        for (int m = 1; m <= 8; m <<= 1) {
#pragma unroll
            for (int v = 0; v < 4; ++v) {
                s[v]  += __shfl_xor(s[v], m);
                ss[v] += __shfl_xor(ss[v], m);
            }
        }
        float mu[4], inv[4];
#pragma unroll
        for (int v = 0; v < 4; ++v) {
            mu[v] = s[v] * 0.015625f;
            float var = ss[v] * 0.015625f - mu[v] * mu[v];
            inv[v] = rsqrtf(var + 1e-5f);
        }
        float4 g4  = *reinterpret_cast<const float4*>(&ln_g[jq]);
        float4 be4 = *reinterpret_cast<const float4*>(&ln_b[jq]);
        float gv[4] = {g4.x, g4.y, g4.z, g4.w};
        float bev[4] = {be4.x, be4.y, be4.z, be4.w};
#pragma unroll
        for (int u = 0; u < 4; ++u) {
            float4 o;
            o.x = (z[u * 4 + 0] - mu[0]) * inv[0] * gv[u] + bev[u];
            o.y = (z[u * 4 + 1] - mu[1]) * inv[1] * gv[u] + bev[u];
            o.z = (z[u * 4 + 2] - mu[2]) * inv[2] * gv[u] + bev[u];
            o.w = (z[u * 4 + 3] - mu[3]) * inv[3] * gv[u] + bev[u];
            *reinterpret_cast<float4*>(&sZ[(jq + u) * 68 + tq]) = o;
        }
    }

    {
        __syncthreads();
        for (int idx = tid; idx < 4096; idx += 256) {
            int i = idx & 63, j = idx >> 6;
            sW[i * 68 + j] = Wk[(size_t)j * 64 + i];
        }
        __syncthreads();
        float a[16];
        proj_tile64(sW, sZ, jq, tq, a);
        float ssq[4];
#pragma unroll
        for (int v = 0; v < 4; ++v)
            ssq[v] = a[v] * a[v] + a[4 + v] * a[4 + v]
                   + a[8 + v] * a[8 + v] + a[12 + v] * a[12 + v];
#pragma unroll
        for (int m = 1; m <= 8; m <<= 1) {
#pragma unroll
            for (int v = 0; v < 4; ++v) ssq[v] += __shfl_xor(ssq[v], m);
        }
#pragma unroll
        for (int v = 0; v < 4; ++v) {
            float sc = 1.f / fmaxf(sqrtf(ssq[v]), 1e-12f);
            float4 o = make_float4(a[v] * sc, a[4 + v] * sc, a[8 + v] * sc, a[12 + v] * sc);
            *reinterpret_cast<float4*>(&ks[(g0 + tq + v) * 64 + jq]) = o;
        }
    }

    {
        __syncthreads();
        for (int idx = tid; idx < 4096; idx += 256) {
            int i = idx & 63, j = idx >> 6;
            sW[i * 68 + j] = Wv[(size_t)j * 64 + i];
        }
        __syncthreads();
        float a[16];
        proj_tile64(sW, sZ, jq, tq, a);
#pragma unroll
        for (int v = 0; v < 4; ++v) {
            float4 o = make_float4(a[v], a[4 + v], a[8 + v], a[12 + v]);
            *reinterpret_cast<float4*>(&vs[(g0 + tq + v) * 64 + jq]) = o;
        }
    }

    if (l0 < 2048) {
        __syncthreads();
        for (int idx = tid; idx < 4096; idx += 256) {
            int i = idx & 63, j = idx >> 6;
            sW[i * 68 + j] = Wattn[(size_t)j * 64 + i];
        }
        __syncthreads();
        float a[16];
        proj_tile64(sW, sZ, jq, tq, a);
#pragma unroll
        for (int v = 0; v < 4; ++v) {
            float4 o = make_float4(a[v], a[4 + v], a[8 + v], a[12 + v]);
            *reinterpret_cast<float4*>(&qbuf[((size_t)b * 2048 + l0 + tq + v) * 64 + jq]) = o;
        }
    }

    if (l0 == SEQL - 64) {
        __syncthreads();
        for (int idx = tid; idx < 4096; idx += 256) {
            int i = idx & 63, j = idx >> 6;
            sW[i * 68 + j] = Wq[(size_t)j * 64 + i];
        }
        __syncthreads();
        float a[16];
        proj_tile64(sW, sZ, jq, tq, a);
        if ((tid >> 4) == 15) {
            float4 o = make_float4(a[3], a[7], a[11], a[15]);
            *reinterpret_cast<float4*>(&qlast[(size_t)b * 64 + jq]) = o;
        }
    }
}

// ---------------------------------------------------------------------------
// Chunked delta scan, phase A. 4-deep register prefetch pipeline (named slots,
// fully unrolled -> compile-time indexing, no scratch). Prefetch address is
// clamped to C-1 for the tail (loads in-bounds, values unused).
// ---------------------------------------------------------------------------
#define STEP2(K0, K1, K2, K3, V)                                                \
    do {                                                                        \
        float dp0 = fmaf(p[0], K0.x, fmaf(p[1], K0.y, fmaf(p[2], K0.z, p[3] * K0.w))); \
        float dp1 = fmaf(p[4], K1.x, fmaf(p[5], K1.y, fmaf(p[6], K1.z, p[7] * K1.w))); \
        float dp2 = fmaf(p[8], K2.x, fmaf(p[9], K2.y, fmaf(p[10], K2.z, p[11] * K2.w))); \
        float dp3 = fmaf(p[12], K3.x, fmaf(p[13], K3.y, fmaf(p[14], K3.z, p[15] * K3.w))); \
        float dq0 = fmaf(q[0], K0.x, fmaf(q[1], K0.y, fmaf(q[2], K0.z, q[3] * K0.w))); \
        float dq1 = fmaf(q[4], K1.x, fmaf(q[5], K1.y, fmaf(q[6], K1.z, q[7] * K1.w))); \
        float dq2 = fmaf(q[8], K2.x, fmaf(q[9], K2.y, fmaf(q[10], K2.z, q[11] * K2.w))); \
        float dq3 = fmaf(q[12], K3.x, fmaf(q[13], K3.y, fmaf(q[14], K3.z, q[15] * K3.w))); \
        float ddp = (dp0 + dp1) + (dp2 + dp3);                                  \
        float ddq = (dq0 + dq1) + (dq2 + dq3);                                  \
        ddp = dpp_xor1_add(ddp);  ddq = dpp_xor1_add(ddq);                      \
        ddp = dpp_xor2_add(ddp);  ddq = dpp_xor2_add(ddq);                      \
        float up = -ddp;                                                        \
        float uq = V - ddq;                                                     \
        p[0] = fmaf(up, K0.x, p[0]);   q[0] = fmaf(uq, K0.x, q[0]);             \
        p[1] = fmaf(up, K0.y, p[1]);   q[1] = fmaf(uq, K0.y, q[1]);             \
        p[2] = fmaf(up, K0.z, p[2]);   q[2] = fmaf(uq, K0.z, q[2]);             \
        p[3] = fmaf(up, K0.w, p[3]);   q[3] = fmaf(uq, K0.w, q[3]);             \
        p[4] = fmaf(up, K1.x, p[4]);   q[4] = fmaf(uq, K1.x, q[4]);             \
        p[5] = fmaf(up, K1.y, p[5]);   q[5] = fmaf(uq, K1.y, q[5]);             \
        p[6] = fmaf(up, K1.z, p[6]);   q[6] = fmaf(uq, K1.z, q[6]);             \
        p[7] = fmaf(up, K1.w, p[7]);   q[7] = fmaf(uq, K1.w, q[7]);             \
        p[8] = fmaf(up, K2.x, p[8]);   q[8] = fmaf(uq, K2.x, q[8]);             \
        p[9] = fmaf(up, K2.y, p[9]);   q[9] = fmaf(uq, K2.y, q[9]);             \
        p[10] = fmaf(up, K2.z, p[10]); q[10] = fmaf(uq, K2.z, q[10]);           \
        p[11] = fmaf(up, K2.w, p[11]); q[11] = fmaf(uq, K2.w, q[11]);           \
        p[12] = fmaf(up, K3.x, p[12]); q[12] = fmaf(uq, K3.x, q[12]);           \
        p[13] = fmaf(up, K3.y, p[13]); q[13] = fmaf(uq, K3.y, q[13]);           \
        p[14] = fmaf(up, K3.z, p[14]); q[14] = fmaf(uq, K3.z, q[14]);           \
        p[15] = fmaf(up, K3.w, p[15]); q[15] = fmaf(uq, K3.w, q[15]);           \
    } while (0)

#define KLOAD(S, T)                                                             \
    do {                                                                        \
        int tt = (T) < C ? (T) : (C - 1);                                       \
        const float4* kp = reinterpret_cast<const float4*>(kb + (size_t)tt * 64); \
        k##S##0 = kp[0]; k##S##1 = kp[1]; k##S##2 = kp[2]; k##S##3 = kp[3];     \
        v##S = vp[(size_t)tt * 64];                                             \
    } while (0)

__global__ __launch_bounds__(256) void chunk_kernel(
    float* __restrict__ ksb, float* __restrict__ vsb, int C)
{
    const int job = blockIdx.x;
    const int tid = threadIdx.x;
    const int r = tid >> 2;
    const int c0 = (tid & 3) * 16;
    float* kc = ksb + (size_t)job * C * 64;
    float* vc = vsb + (size_t)job * C * 64;

    float p[16], q[16];
#pragma unroll
    for (int j = 0; j < 16; ++j) { p[j] = (c0 + j == r) ? 1.f : 0.f; q[j] = 0.f; }

    const float* kb = kc + c0;
    const float* vp = vc + r;

    float4 k00, k01, k02, k03, k10, k11, k12, k13;
    float4 k20, k21, k22, k23, k30, k31, k32, k33;
    float v0, v1, v2, v3;

    KLOAD(0, 0); KLOAD(1, 1); KLOAD(2, 2); KLOAD(3, 3);

    for (int t = 0; t < C; t += 4) {
        STEP2(k00, k01, k02, k03, v0);  KLOAD(0, t + 4);
        STEP2(k10, k11, k12, k13, v1);  KLOAD(1, t + 5);
        STEP2(k20, k21, k22, k23, v2);  KLOAD(2, t + 6);
        STEP2(k30, k31, k32, k33, v3);  KLOAD(3, t + 7);
    }

    float4* po = reinterpret_cast<float4*>(kc + r * 64 + c0);
    po[0] = make_float4(p[0], p[1], p[2], p[3]);
    po[1] = make_float4(p[4], p[5], p[6], p[7]);
    po[2] = make_float4(p[8], p[9], p[10], p[11]);
    po[3] = make_float4(p[12], p[13], p[14], p[15]);
    float4* qo = reinterpret_cast<float4*>(vc + r * 64 + c0);
    qo[0] = make_float4(q[0], q[1], q[2], q[3]);
    qo[1] = make_float4(q[4], q[5], q[6], q[7]);
    qo[2] = make_float4(q[8], q[9], q[10], q[11]);
    qo[3] = make_float4(q[12], q[13], q[14], q[15]);
}

// ---------------------------------------------------------------------------
// Chunked delta scan, phase B (unchanged).
// ---------------------------------------------------------------------------
__global__ __launch_bounds__(256) void combine_kernel(
    const float* __restrict__ Pb, const float* __restrict__ Qb,
    const float* __restrict__ Min, float* __restrict__ Mout,
    int nc, int chunk_stride)
{
    __shared__ __align__(16) float sM[2][64 * 68];
    __shared__ __align__(16) float sP[2][64 * 64];
    const int b = blockIdx.x;
    const int tid = threadIdx.x;
    const int r = tid >> 2;
    const int j0 = (tid & 3) * 16;

    if (Min) {
        const float4* mi = reinterpret_cast<const float4*>(Min + ((size_t)b * 64 + r) * 64 + j0);
        float4* mo = reinterpret_cast<float4*>(&sM[0][r * 68 + j0]);
#pragma unroll
        for (int u = 0; u < 4; ++u) mo[u] = mi[u];
    } else {
#pragma unroll
        for (int u = 0; u < 16; ++u) sM[0][r * 68 + j0 + u] = 0.f;
    }
    {
        const float4* g = reinterpret_cast<const float4*>(Pb + (size_t)b * nc * chunk_stride);
        float4* s = reinterpret_cast<float4*>(sP[0]);
        for (int i = tid; i < 1024; i += 256) s[i] = g[i];
    }
    __syncthreads();

    int cur = 0;
    for (int c = 0; c < nc; ++c) {
        const size_t cbase = (size_t)(b * nc + c) * chunk_stride;
        float4 rp0, rp1, rp2, rp3;
        if (c + 1 < nc) {
            const float4* g = reinterpret_cast<const float4*>(Pb + cbase + chunk_stride);
            rp0 = g[tid]; rp1 = g[tid + 256]; rp2 = g[tid + 512]; rp3 = g[tid + 768];
        }
        float4 rq0, rq1, rq2, rq3;
        {
            const float4* gq = reinterpret_cast<const float4*>(Qb + cbase + r * 64 + j0);
            rq0 = gq[0]; rq1 = gq[1]; rq2 = gq[2]; rq3 = gq[3];
        }
        float acc[16];
#pragma unroll
        for (int u = 0; u < 16; ++u) acc[u] = 0.f;
        const float* Mrow = &sM[cur][r * 68];
        const float* Pl = sP[c & 1];
#pragma unroll
        for (int mg = 0; mg < 16; ++mg) {
            float4 a = *reinterpret_cast<const float4*>(Mrow + mg * 4);
#pragma unroll
            for (int e2 = 0; e2 < 4; ++e2) {
                float am = (e2 == 0) ? a.x : (e2 == 1) ? a.y : (e2 == 2) ? a.z : a.w;
                const float4* pr = reinterpret_cast<const float4*>(Pl + (mg * 4 + e2) * 64 + j0);
                float4 p0 = pr[0], p1 = pr[1], p2 = pr[2], p3 = pr[3];
                acc[0] = fmaf(am, p0.x, acc[0]);  acc[1] = fmaf(am, p0.y, acc[1]);
                acc[2] = fmaf(am, p0.z, acc[2]);  acc[3] = fmaf(am, p0.w, acc[3]);
                acc[4] = fmaf(am, p1.x, acc[4]);  acc[5] = fmaf(am, p1.y, acc[5]);
                acc[6] = fmaf(am, p1.z, acc[6]);  acc[7] = fmaf(am, p1.w, acc[7]);
                acc[8] = fmaf(am, p2.x, acc[8]);  acc[9] = fmaf(am, p2.y, acc[9]);
                acc[10] = fmaf(am, p2.z, acc[10]); acc[11] = fmaf(am, p2.w, acc[11]);
                acc[12] = fmaf(am, p3.x, acc[12]); acc[13] = fmaf(am, p3.y, acc[13]);
                acc[14] = fmaf(am, p3.z, acc[14]); acc[15] = fmaf(am, p3.w, acc[15]);
            }
        }
        const int nxt = cur ^ 1;
        float* om = &sM[nxt][r * 68 + j0];
        om[0] = acc[0] + rq0.x;  om[1] = acc[1] + rq0.y;
        om[2] = acc[2] + rq0.z;  om[3] = acc[3] + rq0.w;
        om[4] = acc[4] + rq1.x;  om[5] = acc[5] + rq1.y;
        om[6] = acc[6] + rq1.z;  om[7] = acc[7] + rq1.w;
        om[8] = acc[8] + rq2.x;  om[9] = acc[9] + rq2.y;
        om[10] = acc[10] + rq2.z; om[11] = acc[11] + rq2.w;
        om[12] = acc[12] + rq3.x; om[13] = acc[13] + rq3.y;
        om[14] = acc[14] + rq3.z; om[15] = acc[15] + rq3.w;
        if (c + 1 < nc) {
            float4* s = reinterpret_cast<float4*>(sP[(c + 1) & 1]);
            s[tid] = rp0; s[tid + 256] = rp1; s[tid + 512] = rp2; s[tid + 768] = rp3;
        }
        __syncthreads();
        cur = nxt;
    }

    float4* mo = reinterpret_cast<float4*>(Mout + ((size_t)b * 64 + r) * 64 + j0);
    const float* fm = &sM[cur][r * 68 + j0];
    mo[0] = make_float4(fm[0], fm[1], fm[2], fm[3]);
    mo[1] = make_float4(fm[4], fm[5], fm[6], fm[7]);
    mo[2] = make_float4(fm[8], fm[9], fm[10], fm[11]);
    mo[3] = make_float4(fm[12], fm[13], fm[14], fm[15]);
}

// ---------------------------------------------------------------------------
// Attention read + second k/v projection (unchanged from round 3).
// ---------------------------------------------------------------------------
__global__ __launch_bounds__(256) void attn_kernel(
    const float* __restrict__ qg, const float* __restrict__ Mbuf,
    const float* __restrict__ Wk, const float* __restrict__ Wv,
    float* __restrict__ ks2, float* __restrict__ vs2)
{
    __shared__ __align__(16) float sM[64 * 65];
    __shared__ __align__(16) float sWkT[64 * 65];
    __shared__ __align__(16) float sWvT[64 * 65];
    __shared__ __align__(16) float sA[64 * 36];
    __shared__ __align__(16) float sB[64 * 36];

    const int b = blockIdx.y;
    const int tile0 = blockIdx.x * 32;
    const int tid = threadIdx.x;
    const int lane = tid & 63;
    const int t0 = (tid >> 6) * 8;
    const size_t qbase = (size_t)b * 2048 + tile0;

    for (int idx = tid; idx < 4096; idx += 256) {
        int rr = idx >> 6, cc = idx & 63;
        sM[rr * 65 + cc] = Mbuf[(size_t)b * 4096 + idx];
        sWkT[cc * 65 + rr] = Wk[idx];
        sWvT[cc * 65 + rr] = Wv[idx];
    }
    for (int it = tid; it < 512; it += 256) {
        int hg = it & 15, t = it >> 4;
        float4 qv = *reinterpret_cast<const float4*>(&qg[(qbase + t) * 64 + hg * 4]);
        sA[(hg * 4 + 0) * 36 + t] = qv.x;
        sA[(hg * 4 + 1) * 36 + t] = qv.y;
        sA[(hg * 4 + 2) * 36 + t] = qv.z;
        sA[(hg * 4 + 3) * 36 + t] = qv.w;
    }
    __syncthreads();

    float acc[8];
#pragma unroll
    for (int u = 0; u < 8; ++u) acc[u] = 0.f;
    for (int h = 0; h < 64; ++h) {
        float w = sM[h * 65 + lane];
        const float4* qp = reinterpret_cast<const float4*>(&sA[h * 36 + t0]);
        float4 q0 = qp[0], q1 = qp[1];
        acc[0] = fmaf(w, q0.x, acc[0]); acc[1] = fmaf(w, q0.y, acc[1]);
        acc[2] = fmaf(w, q0.z, acc[2]); acc[3] = fmaf(w, q0.w, acc[3]);
        acc[4] = fmaf(w, q1.x, acc[4]); acc[5] = fmaf(w, q1.y, acc[5]);
        acc[6] = fmaf(w, q1.z, acc[6]); acc[7] = fmaf(w, q1.w, acc[7]);
    }

#pragma unroll
    for (int u = 0; u < 8; ++u) {
        float sv = acc[u] * 0.125f;
        float mx = sv;
        for (int off = 32; off; off >>= 1) mx = fmaxf(mx, __shfl_xor(mx, off));
        float e = __expf(sv - mx);
        float sm = e;
        for (int off = 32; off; off >>= 1) sm += __shfl_xor(sm, off);
        acc[u] = e / sm;
    }
#pragma unroll
    for (int u = 0; u < 8; ++u) sB[lane * 36 + t0 + u] = acc[u];
    __syncthreads();

#pragma unroll
    for (int u = 0; u < 8; ++u) acc[u] = 0.f;
    for (int k = 0; k < 64; ++k) {
        float m = sM[lane * 65 + k];
        const float4* pp = reinterpret_cast<const float4*>(&sB[k * 36 + t0]);
        float4 p0 = pp[0], p1 = pp[1];
        acc[0] = fmaf(m, p0.x, acc[0]); acc[1] = fmaf(m, p0.y, acc[1]);
        acc[2] = fmaf(m, p0.z, acc[2]); acc[3] = fmaf(m, p0.w, acc[3]);
        acc[4] = fmaf(m, p1.x, acc[4]); acc[5] = fmaf(m, p1.y, acc[5]);
        acc[6] = fmaf(m, p1.z, acc[6]); acc[7] = fmaf(m, p1.w, acc[7]);
    }
#pragma unroll
    for (int u = 0; u < 8; ++u) sA[lane * 36 + t0 + u] = acc[u];
    __syncthreads();

    float ak[8], av[8];
#pragma unroll
    for (int u = 0; u < 8; ++u) { ak[u] = 0.f; av[u] = 0.f; }
    for (int h = 0; h < 64; ++h) {
        float wk = sWkT[h * 65 + lane];
        float wv = sWvT[h * 65 + lane];
        const float4* cp = reinterpret_cast<const float4*>(&sA[h * 36 + t0]);
        float4 c0 = cp[0], c1 = cp[1];
        ak[0] = fmaf(wk, c0.x, ak[0]); av[0] = fmaf(wv, c0.x, av[0]);
        ak[1] = fmaf(wk, c0.y, ak[1]); av[1] = fmaf(wv, c0.y, av[1]);
        ak[2] = fmaf(wk, c0.z, ak[2]); av[2] = fmaf(wv, c0.z, av[2]);
        ak[3] = fmaf(wk, c0.w, ak[3]); av[3] = fmaf(wv, c0.w, av[3]);
        ak[4] = fmaf(wk, c1.x, ak[4]); av[4] = fmaf(wv, c1.x, av[4]);
        ak[5] = fmaf(wk, c1.y, ak[5]); av[5] = fmaf(wv, c1.y, av[5]);
        ak[6] = fmaf(wk, c1.z, ak[6]); av[6] = fmaf(wv, c1.z, av[6]);
        ak[7] = fmaf(wk, c1.w, ak[7]); av[7] = fmaf(wv, c1.w, av[7]);
    }
#pragma unroll
    for (int u = 0; u < 8; ++u) {
        float ssq = ak[u] * ak[u];
        for (int off = 32; off; off >>= 1) ssq += __shfl_xor(ssq, off);
        float n = sqrtf(ssq);
        float sc = 1.f / fmaxf(n, 1e-12f);
        const size_t o = (qbase + t0 + u) * 64 + lane;
        ks2[o] = ak[u] * sc;
        vs2[o] = av[u];
    }
}

// ---------------------------------------------------------------------------
// Output: read = M2 @ q_last; out = read @ Wout^T + bout
// ---------------------------------------------------------------------------
__global__ __launch_bounds__(128) void out_kernel(
    const float* __restrict__ M2, const float* __restrict__ qlast,
    const float* __restrict__ Wout, const float* __restrict__ bout,
    float* __restrict__ out)
{
    const int b = blockIdx.x;
    const int tid = threadIdx.x;
    __shared__ float sq[64], sread[64];
    if (tid < 64) sq[tid] = qlast[b * 64 + tid];
    __syncthreads();
    if (tid < 64) {
        const float* Mr = M2 + ((size_t)b * 64 + tid) * 64;
        float acc = 0.f;
        for (int j = 0; j < 64; ++j) acc = fmaf(Mr[j], sq[j], acc);
        sread[tid] = acc;
    }
    __syncthreads();
    float acc = bout[tid];
    for (int h = 0; h < 64; ++h) acc = fmaf(Wout[tid * 64 + h], sread[h], acc);
    out[b * 128 + tid] = acc;
}

// ---------------------------------------------------------------------------
extern "C" void kernel_launch(void* const* d_in, const int* in_sizes, int n_in,
                              void* d_out, int out_size, void* d_ws, size_t ws_size,
                              hipStream_t stream)
{
    const int* x        = (const int*)d_in[0];
    const float* embed  = (const float*)d_in[1];
    const float* W1     = (const float*)d_in[2];
    const float* b1     = (const float*)d_in[3];
    const float* W2     = (const float*)d_in[4];
    const float* b2     = (const float*)d_in[5];
    const float* ln_g   = (const float*)d_in[6];
    const float* ln_b   = (const float*)d_in[7];
    const float* Wk     = (const float*)d_in[8];
    const float* Wv     = (const float*)d_in[9];
    const float* Wq     = (const float*)d_in[10];
    const float* Wattn  = (const float*)d_in[11];
    const float* Wout   = (const float*)d_in[12];
    const float* bout   = (const float*)d_in[13];

    // workspace layout (floats): ks | vs | q | qlast | M | M2
    float* ws = (float*)d_ws;
    float* ks = ws;
    float* vs = ks + (size_t)NB * SEQL * 64;
    float* qb = vs + (size_t)NB * SEQL * 64;
    float* ql = qb + (size_t)NB * 2048 * 64;
    float* M  = ql + (size_t)NB * 64;
    float* M2 = M + (size_t)NB * 64 * 64;
    if (ws_size < (size_t)(M2 + (size_t)NB * 64 * 64 - ws) * sizeof(float)) return;

    hipLaunchKernelGGL(encoder_kernel, dim3((NB * SEQL) / 64), dim3(256), 0, stream,
                       x, embed, W1, b1, W2, b2, ln_g, ln_b, Wk, Wv, Wq, Wattn,
                       ks, vs, qb, ql);

    // scan 1: L=4096, C=256 -> 16 chunks/batch, 1024 parallel chunk jobs
    const int C1 = 256, nc1 = SEQL / C1;
    hipLaunchKernelGGL(chunk_kernel, dim3(NB * nc1), dim3(256), 0, stream, ks, vs, C1);
    hipLaunchKernelGGL(combine_kernel, dim3(NB), dim3(256), 0, stream,
                       ks, vs, (const float*)nullptr, M, nc1, C1 * 64);

    // attention + second k/v projection (ks2/vs2 reuse ks/vs)
    hipLaunchKernelGGL(attn_kernel, dim3(64, NB), dim3(256), 0, stream,
                       qb, M, Wk, Wv, ks, vs);

    // scan 2: L=2048, C=128 -> 16 chunks/batch, 1024 parallel chunk jobs
    const int C2 = 128, nc2 = 2048 / C2;
    hipLaunchKernelGGL(chunk_kernel, dim3(NB * nc2), dim3(256), 0, stream, ks, vs, C2);
    hipLaunchKernelGGL(combine_kernel, dim3(NB), dim3(256), 0, stream,
                       ks, vs, M, M2, nc2, C2 * 64);

    hipLaunchKernelGGL(out_kernel, dim3(NB), dim3(128), 0, stream,
                       M2, ql, Wout, bout, (float*)d_out);
}

// Round 8
// 682.139 us; speedup vs baseline: 5.0865x; 1.2834x over previous
//
#include <hip/hip_runtime.h>

#define SEQL 4096
#define NB 64

// ---------------------------------------------------------------------------
// DPP quad-reductions (VALU pipe, no DS ops).
// ---------------------------------------------------------------------------
__device__ __forceinline__ float dpp_xor1_add(float x) {
    int v = __builtin_amdgcn_mov_dpp(__float_as_int(x), 0xB1, 0xF, 0xF, true);
    return x + __int_as_float(v);
}
__device__ __forceinline__ float dpp_xor2_add(float x) {
    int v = __builtin_amdgcn_mov_dpp(__float_as_int(x), 0x4E, 0xF, 0xF, true);
    return x + __int_as_float(v);
}

// ---------------------------------------------------------------------------
// Encoder v3 (unchanged).
// ---------------------------------------------------------------------------
#define FMA16(A, W, H)                                      \
    A[0]  = fmaf(W.x, H.x, A[0]);  A[1]  = fmaf(W.x, H.y, A[1]);   \
    A[2]  = fmaf(W.x, H.z, A[2]);  A[3]  = fmaf(W.x, H.w, A[3]);   \
    A[4]  = fmaf(W.y, H.x, A[4]);  A[5]  = fmaf(W.y, H.y, A[5]);   \
    A[6]  = fmaf(W.y, H.z, A[6]);  A[7]  = fmaf(W.y, H.w, A[7]);   \
    A[8]  = fmaf(W.z, H.x, A[8]);  A[9]  = fmaf(W.z, H.y, A[9]);   \
    A[10] = fmaf(W.z, H.z, A[10]); A[11] = fmaf(W.z, H.w, A[11]);  \
    A[12] = fmaf(W.w, H.x, A[12]); A[13] = fmaf(W.w, H.y, A[13]);  \
    A[14] = fmaf(W.w, H.z, A[14]); A[15] = fmaf(W.w, H.w, A[15])

__device__ __forceinline__ void proj_tile64(const float* __restrict__ sW,
                                            const float* __restrict__ sA,
                                            int jq, int tq, float* __restrict__ a)
{
#pragma unroll
    for (int u = 0; u < 16; ++u) a[u] = 0.f;
#pragma unroll 2
    for (int i = 0; i < 64; ++i) {
        float4 w  = *reinterpret_cast<const float4*>(&sW[i * 68 + jq]);
        float4 h4 = *reinterpret_cast<const float4*>(&sA[i * 68 + tq]);
        FMA16(a, w, h4);
    }
}

__global__ __launch_bounds__(256) void encoder_kernel(
    const int* __restrict__ x, const float* __restrict__ embed,
    const float* __restrict__ W1, const float* __restrict__ b1,
    const float* __restrict__ W2, const float* __restrict__ b2,
    const float* __restrict__ ln_g, const float* __restrict__ ln_b,
    const float* __restrict__ Wk, const float* __restrict__ Wv,
    const float* __restrict__ Wq, const float* __restrict__ Wattn,
    float* __restrict__ ks, float* __restrict__ vs,
    float* __restrict__ qbuf, float* __restrict__ qlast)
{
    __shared__ __align__(16) float sZ[64 * 68];
    __shared__ __align__(16) float sF[128 * 68];
    __shared__ __align__(16) float sW[64 * 68];

    const int tid = threadIdx.x;
    const size_t g0 = (size_t)blockIdx.x * 64;
    const int b = (int)(g0 >> 12);
    const int l0 = (int)(g0 & (SEQL - 1));
    const int jq = (tid & 15) * 4;
    const int tq = (tid >> 4) * 4;

    for (int idx = tid; idx < 4096; idx += 256) {
        int t = idx >> 6, i = idx & 63;
        sZ[i * 68 + t] = embed[(size_t)x[g0 + t] * 64 + i];
    }

    for (int jh = 0; jh < 2; ++jh) {
        if (jh) __syncthreads();
        for (int idx = tid; idx < 4096; idx += 256) {
            int i = idx & 63, jj = idx >> 6;
            sW[i * 68 + jj] = W1[(size_t)(jh * 64 + jj) * 64 + i];
        }
        __syncthreads();
        float a[16];
        proj_tile64(sW, sZ, jq, tq, a);
        float4 bb = *reinterpret_cast<const float4*>(&b1[jh * 64 + jq]);
        float bv[4] = {bb.x, bb.y, bb.z, bb.w};
#pragma unroll
        for (int u = 0; u < 4; ++u) {
            float4 o;
            o.x = fmaxf(a[u * 4 + 0] + bv[u], 0.f);
            o.y = fmaxf(a[u * 4 + 1] + bv[u], 0.f);
            o.z = fmaxf(a[u * 4 + 2] + bv[u], 0.f);
            o.w = fmaxf(a[u * 4 + 3] + bv[u], 0.f);
            *reinterpret_cast<float4*>(&sF[(jh * 64 + jq + u) * 68 + tq]) = o;
        }
    }

    float zacc[16];
#pragma unroll
    for (int u = 0; u < 16; ++u) zacc[u] = 0.f;
    for (int ph = 0; ph < 2; ++ph) {
        __syncthreads();
        for (int idx = tid; idx < 4096; idx += 256) {
            int p = idx & 63, j = idx >> 6;
            sW[p * 68 + j] = W2[(size_t)j * 128 + ph * 64 + p];
        }
        __syncthreads();
#pragma unroll 2
        for (int p = 0; p < 64; ++p) {
            float4 w  = *reinterpret_cast<const float4*>(&sW[p * 68 + jq]);
            float4 f4 = *reinterpret_cast<const float4*>(&sF[(ph * 64 + p) * 68 + tq]);
            FMA16(zacc, w, f4);
        }
    }

    {
        float z[16];
        float4 b2v = *reinterpret_cast<const float4*>(&b2[jq]);
        float bv[4] = {b2v.x, b2v.y, b2v.z, b2v.w};
#pragma unroll
        for (int u = 0; u < 4; ++u) {
            float4 h4 = *reinterpret_cast<const float4*>(&sZ[(jq + u) * 68 + tq]);
            z[u * 4 + 0] = h4.x + bv[u] + zacc[u * 4 + 0];
            z[u * 4 + 1] = h4.y + bv[u] + zacc[u * 4 + 1];
            z[u * 4 + 2] = h4.z + bv[u] + zacc[u * 4 + 2];
            z[u * 4 + 3] = h4.w + bv[u] + zacc[u * 4 + 3];
        }
        float s[4], ss[4];
#pragma unroll
        for (int v = 0; v < 4; ++v) {
            s[v]  = z[v] + z[4 + v] + z[8 + v] + z[12 + v];
            ss[v] = z[v] * z[v] + z[4 + v] * z[4 + v]
                  + z[8 + v] * z[8 + v] + z[12 + v] * z[12 + v];
        }
#pragma unroll
        for (int m = 1; m <= 8; m <<= 1) {
#pragma unroll
            for (int v = 0; v < 4; ++v) {
                s[v]  += __shfl_xor(s[v], m);
                ss[v] += __shfl_xor(ss[v], m);
            }
        }
        float mu[4], inv[4];
#pragma unroll
        for (int v = 0; v < 4; ++v) {
            mu[v] = s[v] * 0.015625f;
            float var = ss[v] * 0.015625f - mu[v] * mu[v];
            inv[v] = rsqrtf(var + 1e-5f);
        }
        float4 g4  = *reinterpret_cast<const float4*>(&ln_g[jq]);
        float4 be4 = *reinterpret_cast<const float4*>(&ln_b[jq]);
        float gv[4] = {g4.x, g4.y, g4.z, g4.w};
        float bev[4] = {be4.x, be4.y, be4.z, be4.w};
#pragma unroll
        for (int u = 0; u < 4; ++u) {
            float4 o;
            o.x = (z[u * 4 + 0] - mu[0]) * inv[0] * gv[u] + bev[u];
            o.y = (z[u * 4 + 1] - mu[1]) * inv[1] * gv[u] + bev[u];
            o.z = (z[u * 4 + 2] - mu[2]) * inv[2] * gv[u] + bev[u];
            o.w = (z[u * 4 + 3] - mu[3]) * inv[3] * gv[u] + bev[u];
            *reinterpret_cast<float4*>(&sZ[(jq + u) * 68 + tq]) = o;
        }
    }

    {
        __syncthreads();
        for (int idx = tid; idx < 4096; idx += 256) {
            int i = idx & 63, j = idx >> 6;
            sW[i * 68 + j] = Wk[(size_t)j * 64 + i];
        }
        __syncthreads();
        float a[16];
        proj_tile64(sW, sZ, jq, tq, a);
        float ssq[4];
#pragma unroll
        for (int v = 0; v < 4; ++v)
            ssq[v] = a[v] * a[v] + a[4 + v] * a[4 + v]
                   + a[8 + v] * a[8 + v] + a[12 + v] * a[12 + v];
#pragma unroll
        for (int m = 1; m <= 8; m <<= 1) {
#pragma unroll
            for (int v = 0; v < 4; ++v) ssq[v] += __shfl_xor(ssq[v], m);
        }
#pragma unroll
        for (int v = 0; v < 4; ++v) {
            float sc = 1.f / fmaxf(sqrtf(ssq[v]), 1e-12f);
            float4 o = make_float4(a[v] * sc, a[4 + v] * sc, a[8 + v] * sc, a[12 + v] * sc);
            *reinterpret_cast<float4*>(&ks[(g0 + tq + v) * 64 + jq]) = o;
        }
    }

    {
        __syncthreads();
        for (int idx = tid; idx < 4096; idx += 256) {
            int i = idx & 63, j = idx >> 6;
            sW[i * 68 + j] = Wv[(size_t)j * 64 + i];
        }
        __syncthreads();
        float a[16];
        proj_tile64(sW, sZ, jq, tq, a);
#pragma unroll
        for (int v = 0; v < 4; ++v) {
            float4 o = make_float4(a[v], a[4 + v], a[8 + v], a[12 + v]);
            *reinterpret_cast<float4*>(&vs[(g0 + tq + v) * 64 + jq]) = o;
        }
    }

    if (l0 < 2048) {
        __syncthreads();
        for (int idx = tid; idx < 4096; idx += 256) {
            int i = idx & 63, j = idx >> 6;
            sW[i * 68 + j] = Wattn[(size_t)j * 64 + i];
        }
        __syncthreads();
        float a[16];
        proj_tile64(sW, sZ, jq, tq, a);
#pragma unroll
        for (int v = 0; v < 4; ++v) {
            float4 o = make_float4(a[v], a[4 + v], a[8 + v], a[12 + v]);
            *reinterpret_cast<float4*>(&qbuf[((size_t)b * 2048 + l0 + tq + v) * 64 + jq]) = o;
        }
    }

    if (l0 == SEQL - 64) {
        __syncthreads();
        for (int idx = tid; idx < 4096; idx += 256) {
            int i = idx & 63, j = idx >> 6;
            sW[i * 68 + j] = Wq[(size_t)j * 64 + i];
        }
        __syncthreads();
        float a[16];
        proj_tile64(sW, sZ, jq, tq, a);
        if ((tid >> 4) == 15) {
            float4 o = make_float4(a[3], a[7], a[11], a[15]);
            *reinterpret_cast<float4*>(&qlast[(size_t)b * 64 + jq]) = o;
        }
    }
}

// ---------------------------------------------------------------------------
// Chunked delta scan, phase A. k/v staged through double-buffered LDS tiles
// of 32 steps (2x(8+8)KB = 32KB): global traffic becomes unique+coalesced
// (TCP relief: was 4.25KB/wave-step redundant, now 512B/block-step), per-step
// operand reads are LDS broadcasts with immediate offsets (inner loop fully
// unrolled). One barrier per tile; reg-staged next-tile prefetch.
// ---------------------------------------------------------------------------
#define STEP2(K0, K1, K2, K3, V)                                                \
    do {                                                                        \
        float dp0 = fmaf(p[0], K0.x, fmaf(p[1], K0.y, fmaf(p[2], K0.z, p[3] * K0.w))); \
        float dp1 = fmaf(p[4], K1.x, fmaf(p[5], K1.y, fmaf(p[6], K1.z, p[7] * K1.w))); \
        float dp2 = fmaf(p[8], K2.x, fmaf(p[9], K2.y, fmaf(p[10], K2.z, p[11] * K2.w))); \
        float dp3 = fmaf(p[12], K3.x, fmaf(p[13], K3.y, fmaf(p[14], K3.z, p[15] * K3.w))); \
        float dq0 = fmaf(q[0], K0.x, fmaf(q[1], K0.y, fmaf(q[2], K0.z, q[3] * K0.w))); \
        float dq1 = fmaf(q[4], K1.x, fmaf(q[5], K1.y, fmaf(q[6], K1.z, q[7] * K1.w))); \
        float dq2 = fmaf(q[8], K2.x, fmaf(q[9], K2.y, fmaf(q[10], K2.z, q[11] * K2.w))); \
        float dq3 = fmaf(q[12], K3.x, fmaf(q[13], K3.y, fmaf(q[14], K3.z, q[15] * K3.w))); \
        float ddp = (dp0 + dp1) + (dp2 + dp3);                                  \
        float ddq = (dq0 + dq1) + (dq2 + dq3);                                  \
        ddp = dpp_xor1_add(ddp);  ddq = dpp_xor1_add(ddq);                      \
        ddp = dpp_xor2_add(ddp);  ddq = dpp_xor2_add(ddq);                      \
        float up = -ddp;                                                        \
        float uq = V - ddq;                                                     \
        p[0] = fmaf(up, K0.x, p[0]);   q[0] = fmaf(uq, K0.x, q[0]);             \
        p[1] = fmaf(up, K0.y, p[1]);   q[1] = fmaf(uq, K0.y, q[1]);             \
        p[2] = fmaf(up, K0.z, p[2]);   q[2] = fmaf(uq, K0.z, q[2]);             \
        p[3] = fmaf(up, K0.w, p[3]);   q[3] = fmaf(uq, K0.w, q[3]);             \
        p[4] = fmaf(up, K1.x, p[4]);   q[4] = fmaf(uq, K1.x, q[4]);             \
        p[5] = fmaf(up, K1.y, p[5]);   q[5] = fmaf(uq, K1.y, q[5]);             \
        p[6] = fmaf(up, K1.z, p[6]);   q[6] = fmaf(uq, K1.z, q[6]);             \
        p[7] = fmaf(up, K1.w, p[7]);   q[7] = fmaf(uq, K1.w, q[7]);             \
        p[8] = fmaf(up, K2.x, p[8]);   q[8] = fmaf(uq, K2.x, q[8]);             \
        p[9] = fmaf(up, K2.y, p[9]);   q[9] = fmaf(uq, K2.y, q[9]);             \
        p[10] = fmaf(up, K2.z, p[10]); q[10] = fmaf(uq, K2.z, q[10]);           \
        p[11] = fmaf(up, K2.w, p[11]); q[11] = fmaf(uq, K2.w, q[11]);           \
        p[12] = fmaf(up, K3.x, p[12]); q[12] = fmaf(uq, K3.x, q[12]);           \
        p[13] = fmaf(up, K3.y, p[13]); q[13] = fmaf(uq, K3.y, q[13]);           \
        p[14] = fmaf(up, K3.z, p[14]); q[14] = fmaf(uq, K3.z, q[14]);           \
        p[15] = fmaf(up, K3.w, p[15]); q[15] = fmaf(uq, K3.w, q[15]);           \
    } while (0)

__global__ __launch_bounds__(256) void chunk_kernel(
    float* __restrict__ ksb, float* __restrict__ vsb, int C)
{
    __shared__ __align__(16) float sk[2][32 * 64];
    __shared__ __align__(16) float sv[2][32 * 64];

    const int job = blockIdx.x;
    const int tid = threadIdx.x;
    const int r = tid >> 2;
    const int c0 = (tid & 3) * 16;
    float* kc = ksb + (size_t)job * C * 64;
    float* vc = vsb + (size_t)job * C * 64;

    float p[16], q[16];
#pragma unroll
    for (int j = 0; j < 16; ++j) { p[j] = (c0 + j == r) ? 1.f : 0.f; q[j] = 0.f; }

    const int nt = C >> 5;   // 32-step tiles
    float4 rk0, rk1, rv0, rv1;

    // tile 0 -> LDS buf 0 (coalesced, unique)
    {
        const float4* gk = reinterpret_cast<const float4*>(kc);
        const float4* gv = reinterpret_cast<const float4*>(vc);
        float4 a0 = gk[tid], a1 = gk[256 + tid];
        float4 b0 = gv[tid], b1 = gv[256 + tid];
        float4* dk = reinterpret_cast<float4*>(sk[0]);
        float4* dv = reinterpret_cast<float4*>(sv[0]);
        dk[tid] = a0; dk[256 + tid] = a1;
        dv[tid] = b0; dv[256 + tid] = b1;
    }
    // tile 1 -> regs
    if (nt > 1) {
        const float4* gk = reinterpret_cast<const float4*>(kc + 2048);
        const float4* gv = reinterpret_cast<const float4*>(vc + 2048);
        rk0 = gk[tid]; rk1 = gk[256 + tid];
        rv0 = gv[tid]; rv1 = gv[256 + tid];
    }
    __syncthreads();

    int cur = 0;
    for (int tile = 0; tile < nt; ++tile) {
        // park tile+1 regs into the idle buffer; issue tile+2 global loads
        if (tile + 1 < nt) {
            float4* dk = reinterpret_cast<float4*>(sk[cur ^ 1]);
            float4* dv = reinterpret_cast<float4*>(sv[cur ^ 1]);
            dk[tid] = rk0; dk[256 + tid] = rk1;
            dv[tid] = rv0; dv[256 + tid] = rv1;
            if (tile + 2 < nt) {
                const float4* gk = reinterpret_cast<const float4*>(kc + (size_t)(tile + 2) * 2048);
                const float4* gv = reinterpret_cast<const float4*>(vc + (size_t)(tile + 2) * 2048);
                rk0 = gk[tid]; rk1 = gk[256 + tid];
                rv0 = gv[tid]; rv1 = gv[256 + tid];
            }
        }

        const float* kl = sk[cur] + c0;
        const float* vl = sv[cur] + r;
        float4 a0, a1, a2, a3, e0, e1, e2, e3;
        float va, ve;
        {
            const float4* kp = reinterpret_cast<const float4*>(kl);
            a0 = kp[0]; a1 = kp[1]; a2 = kp[2]; a3 = kp[3];
            va = vl[0];
        }
#pragma unroll
        for (int t = 0; t < 32; t += 2) {
            {
                const float4* kp = reinterpret_cast<const float4*>(kl + (t + 1) * 64);
                e0 = kp[0]; e1 = kp[1]; e2 = kp[2]; e3 = kp[3];
                ve = vl[(t + 1) * 64];
            }
            STEP2(a0, a1, a2, a3, va);
            if (t + 2 < 32) {
                const float4* kp = reinterpret_cast<const float4*>(kl + (t + 2) * 64);
                a0 = kp[0]; a1 = kp[1]; a2 = kp[2]; a3 = kp[3];
                va = vl[(t + 2) * 64];
            }
            STEP2(e0, e1, e2, e3, ve);
        }
        __syncthreads();   // all reads of cur done; tile+1 writes visible
        cur ^= 1;
    }

    // write P over k-chunk, Q over v-chunk (all global reads completed above)
    float4* po = reinterpret_cast<float4*>(kc + r * 64 + c0);
    po[0] = make_float4(p[0], p[1], p[2], p[3]);
    po[1] = make_float4(p[4], p[5], p[6], p[7]);
    po[2] = make_float4(p[8], p[9], p[10], p[11]);
    po[3] = make_float4(p[12], p[13], p[14], p[15]);
    float4* qo = reinterpret_cast<float4*>(vc + r * 64 + c0);
    qo[0] = make_float4(q[0], q[1], q[2], q[3]);
    qo[1] = make_float4(q[4], q[5], q[6], q[7]);
    qo[2] = make_float4(q[8], q[9], q[10], q[11]);
    qo[3] = make_float4(q[12], q[13], q[14], q[15]);
}

// ---------------------------------------------------------------------------
// Chunked delta scan, phase B (unchanged).
// ---------------------------------------------------------------------------
__global__ __launch_bounds__(256) void combine_kernel(
    const float* __restrict__ Pb, const float* __restrict__ Qb,
    const float* __restrict__ Min, float* __restrict__ Mout,
    int nc, int chunk_stride)
{
    __shared__ __align__(16) float sM[2][64 * 68];
    __shared__ __align__(16) float sP[2][64 * 64];
    const int b = blockIdx.x;
    const int tid = threadIdx.x;
    const int r = tid >> 2;
    const int j0 = (tid & 3) * 16;

    if (Min) {
        const float4* mi = reinterpret_cast<const float4*>(Min + ((size_t)b * 64 + r) * 64 + j0);
        float4* mo = reinterpret_cast<float4*>(&sM[0][r * 68 + j0]);
#pragma unroll
        for (int u = 0; u < 4; ++u) mo[u] = mi[u];
    } else {
#pragma unroll
        for (int u = 0; u < 16; ++u) sM[0][r * 68 + j0 + u] = 0.f;
    }
    {
        const float4* g = reinterpret_cast<const float4*>(Pb + (size_t)b * nc * chunk_stride);
        float4* s = reinterpret_cast<float4*>(sP[0]);
        for (int i = tid; i < 1024; i += 256) s[i] = g[i];
    }
    __syncthreads();

    int cur = 0;
    for (int c = 0; c < nc; ++c) {
        const size_t cbase = (size_t)(b * nc + c) * chunk_stride;
        float4 rp0, rp1, rp2, rp3;
        if (c + 1 < nc) {
            const float4* g = reinterpret_cast<const float4*>(Pb + cbase + chunk_stride);
            rp0 = g[tid]; rp1 = g[tid + 256]; rp2 = g[tid + 512]; rp3 = g[tid + 768];
        }
        float4 rq0, rq1, rq2, rq3;
        {
            const float4* gq = reinterpret_cast<const float4*>(Qb + cbase + r * 64 + j0);
            rq0 = gq[0]; rq1 = gq[1]; rq2 = gq[2]; rq3 = gq[3];
        }
        float acc[16];
#pragma unroll
        for (int u = 0; u < 16; ++u) acc[u] = 0.f;
        const float* Mrow = &sM[cur][r * 68];
        const float* Pl = sP[c & 1];
#pragma unroll
        for (int mg = 0; mg < 16; ++mg) {
            float4 a = *reinterpret_cast<const float4*>(Mrow + mg * 4);
#pragma unroll
            for (int e2 = 0; e2 < 4; ++e2) {
                float am = (e2 == 0) ? a.x : (e2 == 1) ? a.y : (e2 == 2) ? a.z : a.w;
                const float4* pr = reinterpret_cast<const float4*>(Pl + (mg * 4 + e2) * 64 + j0);
                float4 p0 = pr[0], p1 = pr[1], p2 = pr[2], p3 = pr[3];
                acc[0] = fmaf(am, p0.x, acc[0]);  acc[1] = fmaf(am, p0.y, acc[1]);
                acc[2] = fmaf(am, p0.z, acc[2]);  acc[3] = fmaf(am, p0.w, acc[3]);
                acc[4] = fmaf(am, p1.x, acc[4]);  acc[5] = fmaf(am, p1.y, acc[5]);
                acc[6] = fmaf(am, p1.z, acc[6]);  acc[7] = fmaf(am, p1.w, acc[7]);
                acc[8] = fmaf(am, p2.x, acc[8]);  acc[9] = fmaf(am, p2.y, acc[9]);
                acc[10] = fmaf(am, p2.z, acc[10]); acc[11] = fmaf(am, p2.w, acc[11]);
                acc[12] = fmaf(am, p3.x, acc[12]); acc[13] = fmaf(am, p3.y, acc[13]);
                acc[14] = fmaf(am, p3.z, acc[14]); acc[15] = fmaf(am, p3.w, acc[15]);
            }
        }
        const int nxt = cur ^ 1;
        float* om = &sM[nxt][r * 68 + j0];
        om[0] = acc[0] + rq0.x;  om[1] = acc[1] + rq0.y;
        om[2] = acc[2] + rq0.z;  om[3] = acc[3] + rq0.w;
        om[4] = acc[4] + rq1.x;  om[5] = acc[5] + rq1.y;
        om[6] = acc[6] + rq1.z;  om[7] = acc[7] + rq1.w;
        om[8] = acc[8] + rq2.x;  om[9] = acc[9] + rq2.y;
        om[10] = acc[10] + rq2.z; om[11] = acc[11] + rq2.w;
        om[12] = acc[12] + rq3.x; om[13] = acc[13] + rq3.y;
        om[14] = acc[14] + rq3.z; om[15] = acc[15] + rq3.w;
        if (c + 1 < nc) {
            float4* s = reinterpret_cast<float4*>(sP[(c + 1) & 1]);
            s[tid] = rp0; s[tid + 256] = rp1; s[tid + 512] = rp2; s[tid + 768] = rp3;
        }
        __syncthreads();
        cur = nxt;
    }

    float4* mo = reinterpret_cast<float4*>(Mout + ((size_t)b * 64 + r) * 64 + j0);
    const float* fm = &sM[cur][r * 68 + j0];
    mo[0] = make_float4(fm[0], fm[1], fm[2], fm[3]);
    mo[1] = make_float4(fm[4], fm[5], fm[6], fm[7]);
    mo[2] = make_float4(fm[8], fm[9], fm[10], fm[11]);
    mo[3] = make_float4(fm[12], fm[13], fm[14], fm[15]);
}

// ---------------------------------------------------------------------------
// Attention read + second k/v projection (unchanged).
// ---------------------------------------------------------------------------
__global__ __launch_bounds__(256) void attn_kernel(
    const float* __restrict__ qg, const float* __restrict__ Mbuf,
    const float* __restrict__ Wk, const float* __restrict__ Wv,
    float* __restrict__ ks2, float* __restrict__ vs2)
{
    __shared__ __align__(16) float sM[64 * 65];
    __shared__ __align__(16) float sWkT[64 * 65];
    __shared__ __align__(16) float sWvT[64 * 65];
    __shared__ __align__(16) float sA[64 * 36];
    __shared__ __align__(16) float sB[64 * 36];

    const int b = blockIdx.y;
    const int tile0 = blockIdx.x * 32;
    const int tid = threadIdx.x;
    const int lane = tid & 63;
    const int t0 = (tid >> 6) * 8;
    const size_t qbase = (size_t)b * 2048 + tile0;

    for (int idx = tid; idx < 4096; idx += 256) {
        int rr = idx >> 6, cc = idx & 63;
        sM[rr * 65 + cc] = Mbuf[(size_t)b * 4096 + idx];
        sWkT[cc * 65 + rr] = Wk[idx];
        sWvT[cc * 65 + rr] = Wv[idx];
    }
    for (int it = tid; it < 512; it += 256) {
        int hg = it & 15, t = it >> 4;
        float4 qv = *reinterpret_cast<const float4*>(&qg[(qbase + t) * 64 + hg * 4]);
        sA[(hg * 4 + 0) * 36 + t] = qv.x;
        sA[(hg * 4 + 1) * 36 + t] = qv.y;
        sA[(hg * 4 + 2) * 36 + t] = qv.z;
        sA[(hg * 4 + 3) * 36 + t] = qv.w;
    }
    __syncthreads();

    float acc[8];
#pragma unroll
    for (int u = 0; u < 8; ++u) acc[u] = 0.f;
    for (int h = 0; h < 64; ++h) {
        float w = sM[h * 65 + lane];
        const float4* qp = reinterpret_cast<const float4*>(&sA[h * 36 + t0]);
        float4 q0 = qp[0], q1 = qp[1];
        acc[0] = fmaf(w, q0.x, acc[0]); acc[1] = fmaf(w, q0.y, acc[1]);
        acc[2] = fmaf(w, q0.z, acc[2]); acc[3] = fmaf(w, q0.w, acc[3]);
        acc[4] = fmaf(w, q1.x, acc[4]); acc[5] = fmaf(w, q1.y, acc[5]);
        acc[6] = fmaf(w, q1.z, acc[6]); acc[7] = fmaf(w, q1.w, acc[7]);
    }

#pragma unroll
    for (int u = 0; u < 8; ++u) {
        float sv = acc[u] * 0.125f;
        float mx = sv;
        for (int off = 32; off; off >>= 1) mx = fmaxf(mx, __shfl_xor(mx, off));
        float e = __expf(sv - mx);
        float sm = e;
        for (int off = 32; off; off >>= 1) sm += __shfl_xor(sm, off);
        acc[u] = e / sm;
    }
#pragma unroll
    for (int u = 0; u < 8; ++u) sB[lane * 36 + t0 + u] = acc[u];
    __syncthreads();

#pragma unroll
    for (int u = 0; u < 8; ++u) acc[u] = 0.f;
    for (int k = 0; k < 64; ++k) {
        float m = sM[lane * 65 + k];
        const float4* pp = reinterpret_cast<const float4*>(&sB[k * 36 + t0]);
        float4 p0 = pp[0], p1 = pp[1];
        acc[0] = fmaf(m, p0.x, acc[0]); acc[1] = fmaf(m, p0.y, acc[1]);
        acc[2] = fmaf(m, p0.z, acc[2]); acc[3] = fmaf(m, p0.w, acc[3]);
        acc[4] = fmaf(m, p1.x, acc[4]); acc[5] = fmaf(m, p1.y, acc[5]);
        acc[6] = fmaf(m, p1.z, acc[6]); acc[7] = fmaf(m, p1.w, acc[7]);
    }
#pragma unroll
    for (int u = 0; u < 8; ++u) sA[lane * 36 + t0 + u] = acc[u];
    __syncthreads();

    float ak[8], av[8];
#pragma unroll
    for (int u = 0; u < 8; ++u) { ak[u] = 0.f; av[u] = 0.f; }
    for (int h = 0; h < 64; ++h) {
        float wk = sWkT[h * 65 + lane];
        float wv = sWvT[h * 65 + lane];
        const float4* cp = reinterpret_cast<const float4*>(&sA[h * 36 + t0]);
        float4 c0 = cp[0], c1 = cp[1];
        ak[0] = fmaf(wk, c0.x, ak[0]); av[0] = fmaf(wv, c0.x, av[0]);
        ak[1] = fmaf(wk, c0.y, ak[1]); av[1] = fmaf(wv, c0.y, av[1]);
        ak[2] = fmaf(wk, c0.z, ak[2]); av[2] = fmaf(wv, c0.z, av[2]);
        ak[3] = fmaf(wk, c0.w, ak[3]); av[3] = fmaf(wv, c0.w, av[3]);
        ak[4] = fmaf(wk, c1.x, ak[4]); av[4] = fmaf(wv, c1.x, av[4]);
        ak[5] = fmaf(wk, c1.y, ak[5]); av[5] = fmaf(wv, c1.y, av[5]);
        ak[6] = fmaf(wk, c1.z, ak[6]); av[6] = fmaf(wv, c1.z, av[6]);
        ak[7] = fmaf(wk, c1.w, ak[7]); av[7] = fmaf(wv, c1.w, av[7]);
    }
#pragma unroll
    for (int u = 0; u < 8; ++u) {
        float ssq = ak[u] * ak[u];
        for (int off = 32; off; off >>= 1) ssq += __shfl_xor(ssq, off);
        float n = sqrtf(ssq);
        float sc = 1.f / fmaxf(n, 1e-12f);
        const size_t o = (qbase + t0 + u) * 64 + lane;
        ks2[o] = ak[u] * sc;
        vs2[o] = av[u];
    }
}

// ---------------------------------------------------------------------------
// Output: read = M2 @ q_last; out = read @ Wout^T + bout
// ---------------------------------------------------------------------------
__global__ __launch_bounds__(128) void out_kernel(
    const float* __restrict__ M2, const float* __restrict__ qlast,
    const float* __restrict__ Wout, const float* __restrict__ bout,
    float* __restrict__ out)
{
    const int b = blockIdx.x;
    const int tid = threadIdx.x;
    __shared__ float sq[64], sread[64];
    if (tid < 64) sq[tid] = qlast[b * 64 + tid];
    __syncthreads();
    if (tid < 64) {
        const float* Mr = M2 + ((size_t)b * 64 + tid) * 64;
        float acc = 0.f;
        for (int j = 0; j < 64; ++j) acc = fmaf(Mr[j], sq[j], acc);
        sread[tid] = acc;
    }
    __syncthreads();
    float acc = bout[tid];
    for (int h = 0; h < 64; ++h) acc = fmaf(Wout[tid * 64 + h], sread[h], acc);
    out[b * 128 + tid] = acc;
}

// ---------------------------------------------------------------------------
extern "C" void kernel_launch(void* const* d_in, const int* in_sizes, int n_in,
                              void* d_out, int out_size, void* d_ws, size_t ws_size,
                              hipStream_t stream)
{
    const int* x        = (const int*)d_in[0];
    const float* embed  = (const float*)d_in[1];
    const float* W1     = (const float*)d_in[2];
    const float* b1     = (const float*)d_in[3];
    const float* W2     = (const float*)d_in[4];
    const float* b2     = (const float*)d_in[5];
    const float* ln_g   = (const float*)d_in[6];
    const float* ln_b   = (const float*)d_in[7];
    const float* Wk     = (const float*)d_in[8];
    const float* Wv     = (const float*)d_in[9];
    const float* Wq     = (const float*)d_in[10];
    const float* Wattn  = (const float*)d_in[11];
    const float* Wout   = (const float*)d_in[12];
    const float* bout   = (const float*)d_in[13];

    // workspace layout (floats): ks | vs | q | qlast | M | M2
    float* ws = (float*)d_ws;
    float* ks = ws;
    float* vs = ks + (size_t)NB * SEQL * 64;
    float* qb = vs + (size_t)NB * SEQL * 64;
    float* ql = qb + (size_t)NB * 2048 * 64;
    float* M  = ql + (size_t)NB * 64;
    float* M2 = M + (size_t)NB * 64 * 64;
    if (ws_size < (size_t)(M2 + (size_t)NB * 64 * 64 - ws) * sizeof(float)) return;

    hipLaunchKernelGGL(encoder_kernel, dim3((NB * SEQL) / 64), dim3(256), 0, stream,
                       x, embed, W1, b1, W2, b2, ln_g, ln_b, Wk, Wv, Wq, Wattn,
                       ks, vs, qb, ql);

    // scan 1: L=4096, C=256 -> 16 chunks/batch, 1024 parallel chunk jobs
    const int C1 = 256, nc1 = SEQL / C1;
    hipLaunchKernelGGL(chunk_kernel, dim3(NB * nc1), dim3(256), 0, stream, ks, vs, C1);
    hipLaunchKernelGGL(combine_kernel, dim3(NB), dim3(256), 0, stream,
                       ks, vs, (const float*)nullptr, M, nc1, C1 * 64);

    // attention + second k/v projection (ks2/vs2 reuse ks/vs)
    hipLaunchKernelGGL(attn_kernel, dim3(64, NB), dim3(256), 0, stream,
                       qb, M, Wk, Wv, ks, vs);

    // scan 2: L=2048, C=128 -> 16 chunks/batch, 1024 parallel chunk jobs
    const int C2 = 128, nc2 = 2048 / C2;
    hipLaunchKernelGGL(chunk_kernel, dim3(NB * nc2), dim3(256), 0, stream, ks, vs, C2);
    hipLaunchKernelGGL(combine_kernel, dim3(NB), dim3(256), 0, stream,
                       ks, vs, M, M2, nc2, C2 * 64);

    hipLaunchKernelGGL(out_kernel, dim3(NB), dim3(128), 0, stream,
                       M2, ql, Wout, bout, (float*)d_out);
}

// Round 9
// 608.559 us; speedup vs baseline: 5.7015x; 1.1209x over previous
//
#include <hip/hip_runtime.h>

#define SEQL 4096
#define NB 64

// ---------------------------------------------------------------------------
// DPP quad-reductions (VALU pipe, no DS ops).
// ---------------------------------------------------------------------------
__device__ __forceinline__ float dpp_xor1_add(float x) {
    int v = __builtin_amdgcn_mov_dpp(__float_as_int(x), 0xB1, 0xF, 0xF, true);
    return x + __int_as_float(v);
}
__device__ __forceinline__ float dpp_xor2_add(float x) {
    int v = __builtin_amdgcn_mov_dpp(__float_as_int(x), 0x4E, 0xF, 0xF, true);
    return x + __int_as_float(v);
}

// ---------------------------------------------------------------------------
// Encoder v4: 64 tokens/block, 256 threads, 4x4 tile per thread.
//  - LDS 52.2KB (sZ + one 64-row f-buffer + sW) -> 3 blocks/CU (was 2).
//  - ff1->ff2 fused per 64-channel p-half (f-buffer reused).
//  - Weight staging: coalesced float4 global reads, scalar LDS writes at
//    banks (4c+j)%32 with j=lane spanning 0..63 -> 2-way only (free).
// ---------------------------------------------------------------------------
#define FMA16(A, W, H)                                      \
    A[0]  = fmaf(W.x, H.x, A[0]);  A[1]  = fmaf(W.x, H.y, A[1]);   \
    A[2]  = fmaf(W.x, H.z, A[2]);  A[3]  = fmaf(W.x, H.w, A[3]);   \
    A[4]  = fmaf(W.y, H.x, A[4]);  A[5]  = fmaf(W.y, H.y, A[5]);   \
    A[6]  = fmaf(W.y, H.z, A[6]);  A[7]  = fmaf(W.y, H.w, A[7]);   \
    A[8]  = fmaf(W.z, H.x, A[8]);  A[9]  = fmaf(W.z, H.y, A[9]);   \
    A[10] = fmaf(W.z, H.z, A[10]); A[11] = fmaf(W.z, H.w, A[11]);  \
    A[12] = fmaf(W.w, H.x, A[12]); A[13] = fmaf(W.w, H.y, A[13]);  \
    A[14] = fmaf(W.w, H.z, A[14]); A[15] = fmaf(W.w, H.w, A[15])

__device__ __forceinline__ void proj_tile64(const float* __restrict__ sW,
                                            const float* __restrict__ sA,
                                            int jq, int tq, float* __restrict__ a)
{
#pragma unroll
    for (int u = 0; u < 16; ++u) a[u] = 0.f;
#pragma unroll 2
    for (int i = 0; i < 64; ++i) {
        float4 w  = *reinterpret_cast<const float4*>(&sW[i * 68 + jq]);
        float4 h4 = *reinterpret_cast<const float4*>(&sA[i * 68 + tq]);
        FMA16(a, w, h4);
    }
}

// sW[c*68 + j] = W[j*ldw + col0 + c]  for j,c in [0,64)
__device__ __forceinline__ void stage_w_t(const float* __restrict__ W, int ldw, int col0,
                                          float* __restrict__ sWb, int tid)
{
#pragma unroll
    for (int it = 0; it < 4; ++it) {
        int item = it * 256 + tid;
        int j = item & 63, cq = item >> 6;
        float4 w = *reinterpret_cast<const float4*>(&W[(size_t)j * ldw + col0 + cq * 4]);
        sWb[(cq * 4 + 0) * 68 + j] = w.x;
        sWb[(cq * 4 + 1) * 68 + j] = w.y;
        sWb[(cq * 4 + 2) * 68 + j] = w.z;
        sWb[(cq * 4 + 3) * 68 + j] = w.w;
    }
}

__global__ __launch_bounds__(256) void encoder_kernel(
    const int* __restrict__ x, const float* __restrict__ embed,
    const float* __restrict__ W1, const float* __restrict__ b1,
    const float* __restrict__ W2, const float* __restrict__ b2,
    const float* __restrict__ ln_g, const float* __restrict__ ln_b,
    const float* __restrict__ Wk, const float* __restrict__ Wv,
    const float* __restrict__ Wq, const float* __restrict__ Wattn,
    float* __restrict__ ks, float* __restrict__ vs,
    float* __restrict__ qbuf, float* __restrict__ qlast)
{
    __shared__ __align__(16) float sZ[64 * 68];   // embed h -> hidden, [i][t]
    __shared__ __align__(16) float sF[64 * 68];   // ff1 half out, [p_local][t]
    __shared__ __align__(16) float sW[64 * 68];   // staged weight, [k][j]

    const int tid = threadIdx.x;
    const size_t g0 = (size_t)blockIdx.x * 64;
    const int b = (int)(g0 >> 12);
    const int l0 = (int)(g0 & (SEQL - 1));
    const int jq = (tid & 15) * 4;
    const int tq = (tid >> 4) * 4;

    // ---- embed gather -> sZ[i][t] ----
    for (int idx = tid; idx < 4096; idx += 256) {
        int t = idx >> 6, i = idx & 63;
        sZ[i * 68 + t] = embed[(size_t)x[g0 + t] * 64 + i];
    }

    // ---- FF fused per p-half: f = relu(W1h @ h + b1h); z += W2h @ f ----
    float zacc[16];
#pragma unroll
    for (int u = 0; u < 16; ++u) zacc[u] = 0.f;
    for (int ph = 0; ph < 2; ++ph) {
        if (ph) __syncthreads();                       // prev ff2 done reading sW/sF
        stage_w_t(W1 + (size_t)ph * 64 * 64, 64, 0, sW, tid);
        __syncthreads();                               // sW ready (covers embed on ph=0)
        float a[16];
        proj_tile64(sW, sZ, jq, tq, a);
        float4 bb = *reinterpret_cast<const float4*>(&b1[ph * 64 + jq]);
        float bv[4] = {bb.x, bb.y, bb.z, bb.w};
#pragma unroll
        for (int u = 0; u < 4; ++u) {
            float4 o;
            o.x = fmaxf(a[u * 4 + 0] + bv[u], 0.f);
            o.y = fmaxf(a[u * 4 + 1] + bv[u], 0.f);
            o.z = fmaxf(a[u * 4 + 2] + bv[u], 0.f);
            o.w = fmaxf(a[u * 4 + 3] + bv[u], 0.f);
            *reinterpret_cast<float4*>(&sF[(jq + u) * 68 + tq]) = o;
        }
        __syncthreads();                               // sF complete, sW free
        stage_w_t(W2, 128, ph * 64, sW, tid);
        __syncthreads();                               // W2 half ready
#pragma unroll 2
        for (int p = 0; p < 64; ++p) {
            float4 w  = *reinterpret_cast<const float4*>(&sW[p * 68 + jq]);
            float4 f4 = *reinterpret_cast<const float4*>(&sF[p * 68 + tq]);
            FMA16(zacc, w, f4);
        }
    }

    // ---- residual + LayerNorm ----
    {
        float z[16];
        float4 b2v = *reinterpret_cast<const float4*>(&b2[jq]);
        float bv[4] = {b2v.x, b2v.y, b2v.z, b2v.w};
#pragma unroll
        for (int u = 0; u < 4; ++u) {
            float4 h4 = *reinterpret_cast<const float4*>(&sZ[(jq + u) * 68 + tq]);
            z[u * 4 + 0] = h4.x + bv[u] + zacc[u * 4 + 0];
            z[u * 4 + 1] = h4.y + bv[u] + zacc[u * 4 + 1];
            z[u * 4 + 2] = h4.z + bv[u] + zacc[u * 4 + 2];
            z[u * 4 + 3] = h4.w + bv[u] + zacc[u * 4 + 3];
        }
        float s[4], ss[4];
#pragma unroll
        for (int v = 0; v < 4; ++v) {
            s[v]  = z[v] + z[4 + v] + z[8 + v] + z[12 + v];
            ss[v] = z[v] * z[v] + z[4 + v] * z[4 + v]
                  + z[8 + v] * z[8 + v] + z[12 + v] * z[12 + v];
        }
#pragma unroll
        for (int m = 1; m <= 8; m <<= 1) {
#pragma unroll
            for (int v = 0; v < 4; ++v) {
                s[v]  += __shfl_xor(s[v], m);
                ss[v] += __shfl_xor(ss[v], m);
            }
        }
        float mu[4], inv[4];
#pragma unroll
        for (int v = 0; v < 4; ++v) {
            mu[v] = s[v] * 0.015625f;
            float var = ss[v] * 0.015625f - mu[v] * mu[v];
            inv[v] = rsqrtf(var + 1e-5f);
        }
        float4 g4  = *reinterpret_cast<const float4*>(&ln_g[jq]);
        float4 be4 = *reinterpret_cast<const float4*>(&ln_b[jq]);
        float gv[4] = {g4.x, g4.y, g4.z, g4.w};
        float bev[4] = {be4.x, be4.y, be4.z, be4.w};
#pragma unroll
        for (int u = 0; u < 4; ++u) {
            float4 o;
            o.x = (z[u * 4 + 0] - mu[0]) * inv[0] * gv[u] + bev[u];
            o.y = (z[u * 4 + 1] - mu[1]) * inv[1] * gv[u] + bev[u];
            o.z = (z[u * 4 + 2] - mu[2]) * inv[2] * gv[u] + bev[u];
            o.w = (z[u * 4 + 3] - mu[3]) * inv[3] * gv[u] + bev[u];
            *reinterpret_cast<float4*>(&sZ[(jq + u) * 68 + tq]) = o;  // own cells
        }
    }

    // ---- k projection + l2norm ----
    {
        __syncthreads();                               // LN writes visible, sW free
        stage_w_t(Wk, 64, 0, sW, tid);
        __syncthreads();
        float a[16];
        proj_tile64(sW, sZ, jq, tq, a);
        float ssq[4];
#pragma unroll
        for (int v = 0; v < 4; ++v)
            ssq[v] = a[v] * a[v] + a[4 + v] * a[4 + v]
                   + a[8 + v] * a[8 + v] + a[12 + v] * a[12 + v];
#pragma unroll
        for (int m = 1; m <= 8; m <<= 1) {
#pragma unroll
            for (int v = 0; v < 4; ++v) ssq[v] += __shfl_xor(ssq[v], m);
        }
#pragma unroll
        for (int v = 0; v < 4; ++v) {
            float sc = 1.f / fmaxf(sqrtf(ssq[v]), 1e-12f);
            float4 o = make_float4(a[v] * sc, a[4 + v] * sc, a[8 + v] * sc, a[12 + v] * sc);
            *reinterpret_cast<float4*>(&ks[(g0 + tq + v) * 64 + jq]) = o;
        }
    }

    // ---- v projection ----
    {
        __syncthreads();
        stage_w_t(Wv, 64, 0, sW, tid);
        __syncthreads();
        float a[16];
        proj_tile64(sW, sZ, jq, tq, a);
#pragma unroll
        for (int v = 0; v < 4; ++v) {
            float4 o = make_float4(a[v], a[4 + v], a[8 + v], a[12 + v]);
            *reinterpret_cast<float4*>(&vs[(g0 + tq + v) * 64 + jq]) = o;
        }
    }

    // ---- q projection (first-half blocks only) ----
    if (l0 < 2048) {
        __syncthreads();
        stage_w_t(Wattn, 64, 0, sW, tid);
        __syncthreads();
        float a[16];
        proj_tile64(sW, sZ, jq, tq, a);
#pragma unroll
        for (int v = 0; v < 4; ++v) {
            float4 o = make_float4(a[v], a[4 + v], a[8 + v], a[12 + v]);
            *reinterpret_cast<float4*>(&qbuf[((size_t)b * 2048 + l0 + tq + v) * 64 + jq]) = o;
        }
    }

    // ---- q_last (last block of batch; token 4095 = local t 63) ----
    if (l0 == SEQL - 64) {
        __syncthreads();
        stage_w_t(Wq, 64, 0, sW, tid);
        __syncthreads();
        float a[16];
        proj_tile64(sW, sZ, jq, tq, a);
        if ((tid >> 4) == 15) {
            float4 o = make_float4(a[3], a[7], a[11], a[15]);
            *reinterpret_cast<float4*>(&qlast[(size_t)b * 64 + jq]) = o;
        }
    }
}

// ---------------------------------------------------------------------------
// Chunked delta scan, phase A (unchanged from round 8: LDS-staged k/v tiles).
// ---------------------------------------------------------------------------
#define STEP2(K0, K1, K2, K3, V)                                                \
    do {                                                                        \
        float dp0 = fmaf(p[0], K0.x, fmaf(p[1], K0.y, fmaf(p[2], K0.z, p[3] * K0.w))); \
        float dp1 = fmaf(p[4], K1.x, fmaf(p[5], K1.y, fmaf(p[6], K1.z, p[7] * K1.w))); \
        float dp2 = fmaf(p[8], K2.x, fmaf(p[9], K2.y, fmaf(p[10], K2.z, p[11] * K2.w))); \
        float dp3 = fmaf(p[12], K3.x, fmaf(p[13], K3.y, fmaf(p[14], K3.z, p[15] * K3.w))); \
        float dq0 = fmaf(q[0], K0.x, fmaf(q[1], K0.y, fmaf(q[2], K0.z, q[3] * K0.w))); \
        float dq1 = fmaf(q[4], K1.x, fmaf(q[5], K1.y, fmaf(q[6], K1.z, q[7] * K1.w))); \
        float dq2 = fmaf(q[8], K2.x, fmaf(q[9], K2.y, fmaf(q[10], K2.z, q[11] * K2.w))); \
        float dq3 = fmaf(q[12], K3.x, fmaf(q[13], K3.y, fmaf(q[14], K3.z, q[15] * K3.w))); \
        float ddp = (dp0 + dp1) + (dp2 + dp3);                                  \
        float ddq = (dq0 + dq1) + (dq2 + dq3);                                  \
        ddp = dpp_xor1_add(ddp);  ddq = dpp_xor1_add(ddq);                      \
        ddp = dpp_xor2_add(ddp);  ddq = dpp_xor2_add(ddq);                      \
        float up = -ddp;                                                        \
        float uq = V - ddq;                                                     \
        p[0] = fmaf(up, K0.x, p[0]);   q[0] = fmaf(uq, K0.x, q[0]);             \
        p[1] = fmaf(up, K0.y, p[1]);   q[1] = fmaf(uq, K0.y, q[1]);             \
        p[2] = fmaf(up, K0.z, p[2]);   q[2] = fmaf(uq, K0.z, q[2]);             \
        p[3] = fmaf(up, K0.w, p[3]);   q[3] = fmaf(uq, K0.w, q[3]);             \
        p[4] = fmaf(up, K1.x, p[4]);   q[4] = fmaf(uq, K1.x, q[4]);             \
        p[5] = fmaf(up, K1.y, p[5]);   q[5] = fmaf(uq, K1.y, q[5]);             \
        p[6] = fmaf(up, K1.z, p[6]);   q[6] = fmaf(uq, K1.z, q[6]);             \
        p[7] = fmaf(up, K1.w, p[7]);   q[7] = fmaf(uq, K1.w, q[7]);             \
        p[8] = fmaf(up, K2.x, p[8]);   q[8] = fmaf(uq, K2.x, q[8]);             \
        p[9] = fmaf(up, K2.y, p[9]);   q[9] = fmaf(uq, K2.y, q[9]);             \
        p[10] = fmaf(up, K2.z, p[10]); q[10] = fmaf(uq, K2.z, q[10]);           \
        p[11] = fmaf(up, K2.w, p[11]); q[11] = fmaf(uq, K2.w, q[11]);           \
        p[12] = fmaf(up, K3.x, p[12]); q[12] = fmaf(uq, K3.x, q[12]);           \
        p[13] = fmaf(up, K3.y, p[13]); q[13] = fmaf(uq, K3.y, q[13]);           \
        p[14] = fmaf(up, K3.z, p[14]); q[14] = fmaf(uq, K3.z, q[14]);           \
        p[15] = fmaf(up, K3.w, p[15]); q[15] = fmaf(uq, K3.w, q[15]);           \
    } while (0)

__global__ __launch_bounds__(256) void chunk_kernel(
    float* __restrict__ ksb, float* __restrict__ vsb, int C)
{
    __shared__ __align__(16) float sk[2][32 * 64];
    __shared__ __align__(16) float sv[2][32 * 64];

    const int job = blockIdx.x;
    const int tid = threadIdx.x;
    const int r = tid >> 2;
    const int c0 = (tid & 3) * 16;
    float* kc = ksb + (size_t)job * C * 64;
    float* vc = vsb + (size_t)job * C * 64;

    float p[16], q[16];
#pragma unroll
    for (int j = 0; j < 16; ++j) { p[j] = (c0 + j == r) ? 1.f : 0.f; q[j] = 0.f; }

    const int nt = C >> 5;
    float4 rk0, rk1, rv0, rv1;

    {
        const float4* gk = reinterpret_cast<const float4*>(kc);
        const float4* gv = reinterpret_cast<const float4*>(vc);
        float4 a0 = gk[tid], a1 = gk[256 + tid];
        float4 b0 = gv[tid], b1 = gv[256 + tid];
        float4* dk = reinterpret_cast<float4*>(sk[0]);
        float4* dv = reinterpret_cast<float4*>(sv[0]);
        dk[tid] = a0; dk[256 + tid] = a1;
        dv[tid] = b0; dv[256 + tid] = b1;
    }
    if (nt > 1) {
        const float4* gk = reinterpret_cast<const float4*>(kc + 2048);
        const float4* gv = reinterpret_cast<const float4*>(vc + 2048);
        rk0 = gk[tid]; rk1 = gk[256 + tid];
        rv0 = gv[tid]; rv1 = gv[256 + tid];
    }
    __syncthreads();

    int cur = 0;
    for (int tile = 0; tile < nt; ++tile) {
        if (tile + 1 < nt) {
            float4* dk = reinterpret_cast<float4*>(sk[cur ^ 1]);
            float4* dv = reinterpret_cast<float4*>(sv[cur ^ 1]);
            dk[tid] = rk0; dk[256 + tid] = rk1;
            dv[tid] = rv0; dv[256 + tid] = rv1;
            if (tile + 2 < nt) {
                const float4* gk = reinterpret_cast<const float4*>(kc + (size_t)(tile + 2) * 2048);
                const float4* gv = reinterpret_cast<const float4*>(vc + (size_t)(tile + 2) * 2048);
                rk0 = gk[tid]; rk1 = gk[256 + tid];
                rv0 = gv[tid]; rv1 = gv[256 + tid];
            }
        }

        const float* kl = sk[cur] + c0;
        const float* vl = sv[cur] + r;
        float4 a0, a1, a2, a3, e0, e1, e2, e3;
        float va, ve;
        {
            const float4* kp = reinterpret_cast<const float4*>(kl);
            a0 = kp[0]; a1 = kp[1]; a2 = kp[2]; a3 = kp[3];
            va = vl[0];
        }
#pragma unroll
        for (int t = 0; t < 32; t += 2) {
            {
                const float4* kp = reinterpret_cast<const float4*>(kl + (t + 1) * 64);
                e0 = kp[0]; e1 = kp[1]; e2 = kp[2]; e3 = kp[3];
                ve = vl[(t + 1) * 64];
            }
            STEP2(a0, a1, a2, a3, va);
            if (t + 2 < 32) {
                const float4* kp = reinterpret_cast<const float4*>(kl + (t + 2) * 64);
                a0 = kp[0]; a1 = kp[1]; a2 = kp[2]; a3 = kp[3];
                va = vl[(t + 2) * 64];
            }
            STEP2(e0, e1, e2, e3, ve);
        }
        __syncthreads();
        cur ^= 1;
    }

    float4* po = reinterpret_cast<float4*>(kc + r * 64 + c0);
    po[0] = make_float4(p[0], p[1], p[2], p[3]);
    po[1] = make_float4(p[4], p[5], p[6], p[7]);
    po[2] = make_float4(p[8], p[9], p[10], p[11]);
    po[3] = make_float4(p[12], p[13], p[14], p[15]);
    float4* qo = reinterpret_cast<float4*>(vc + r * 64 + c0);
    qo[0] = make_float4(q[0], q[1], q[2], q[3]);
    qo[1] = make_float4(q[4], q[5], q[6], q[7]);
    qo[2] = make_float4(q[8], q[9], q[10], q[11]);
    qo[3] = make_float4(q[12], q[13], q[14], q[15]);
}

// ---------------------------------------------------------------------------
// Chunked delta scan, phase B (unchanged).
// ---------------------------------------------------------------------------
__global__ __launch_bounds__(256) void combine_kernel(
    const float* __restrict__ Pb, const float* __restrict__ Qb,
    const float* __restrict__ Min, float* __restrict__ Mout,
    int nc, int chunk_stride)
{
    __shared__ __align__(16) float sM[2][64 * 68];
    __shared__ __align__(16) float sP[2][64 * 64];
    const int b = blockIdx.x;
    const int tid = threadIdx.x;
    const int r = tid >> 2;
    const int j0 = (tid & 3) * 16;

    if (Min) {
        const float4* mi = reinterpret_cast<const float4*>(Min + ((size_t)b * 64 + r) * 64 + j0);
        float4* mo = reinterpret_cast<float4*>(&sM[0][r * 68 + j0]);
#pragma unroll
        for (int u = 0; u < 4; ++u) mo[u] = mi[u];
    } else {
#pragma unroll
        for (int u = 0; u < 16; ++u) sM[0][r * 68 + j0 + u] = 0.f;
    }
    {
        const float4* g = reinterpret_cast<const float4*>(Pb + (size_t)b * nc * chunk_stride);
        float4* s = reinterpret_cast<float4*>(sP[0]);
        for (int i = tid; i < 1024; i += 256) s[i] = g[i];
    }
    __syncthreads();

    int cur = 0;
    for (int c = 0; c < nc; ++c) {
        const size_t cbase = (size_t)(b * nc + c) * chunk_stride;
        float4 rp0, rp1, rp2, rp3;
        if (c + 1 < nc) {
            const float4* g = reinterpret_cast<const float4*>(Pb + cbase + chunk_stride);
            rp0 = g[tid]; rp1 = g[tid + 256]; rp2 = g[tid + 512]; rp3 = g[tid + 768];
        }
        float4 rq0, rq1, rq2, rq3;
        {
            const float4* gq = reinterpret_cast<const float4*>(Qb + cbase + r * 64 + j0);
            rq0 = gq[0]; rq1 = gq[1]; rq2 = gq[2]; rq3 = gq[3];
        }
        float acc[16];
#pragma unroll
        for (int u = 0; u < 16; ++u) acc[u] = 0.f;
        const float* Mrow = &sM[cur][r * 68];
        const float* Pl = sP[c & 1];
#pragma unroll
        for (int mg = 0; mg < 16; ++mg) {
            float4 a = *reinterpret_cast<const float4*>(Mrow + mg * 4);
#pragma unroll
            for (int e2 = 0; e2 < 4; ++e2) {
                float am = (e2 == 0) ? a.x : (e2 == 1) ? a.y : (e2 == 2) ? a.z : a.w;
                const float4* pr = reinterpret_cast<const float4*>(Pl + (mg * 4 + e2) * 64 + j0);
                float4 p0 = pr[0], p1 = pr[1], p2 = pr[2], p3 = pr[3];
                acc[0] = fmaf(am, p0.x, acc[0]);  acc[1] = fmaf(am, p0.y, acc[1]);
                acc[2] = fmaf(am, p0.z, acc[2]);  acc[3] = fmaf(am, p0.w, acc[3]);
                acc[4] = fmaf(am, p1.x, acc[4]);  acc[5] = fmaf(am, p1.y, acc[5]);
                acc[6] = fmaf(am, p1.z, acc[6]);  acc[7] = fmaf(am, p1.w, acc[7]);
                acc[8] = fmaf(am, p2.x, acc[8]);  acc[9] = fmaf(am, p2.y, acc[9]);
                acc[10] = fmaf(am, p2.z, acc[10]); acc[11] = fmaf(am, p2.w, acc[11]);
                acc[12] = fmaf(am, p3.x, acc[12]); acc[13] = fmaf(am, p3.y, acc[13]);
                acc[14] = fmaf(am, p3.z, acc[14]); acc[15] = fmaf(am, p3.w, acc[15]);
            }
        }
        const int nxt = cur ^ 1;
        float* om = &sM[nxt][r * 68 + j0];
        om[0] = acc[0] + rq0.x;  om[1] = acc[1] + rq0.y;
        om[2] = acc[2] + rq0.z;  om[3] = acc[3] + rq0.w;
        om[4] = acc[4] + rq1.x;  om[5] = acc[5] + rq1.y;
        om[6] = acc[6] + rq1.z;  om[7] = acc[7] + rq1.w;
        om[8] = acc[8] + rq2.x;  om[9] = acc[9] + rq2.y;
        om[10] = acc[10] + rq2.z; om[11] = acc[11] + rq2.w;
        om[12] = acc[12] + rq3.x; om[13] = acc[13] + rq3.y;
        om[14] = acc[14] + rq3.z; om[15] = acc[15] + rq3.w;
        if (c + 1 < nc) {
            float4* s = reinterpret_cast<float4*>(sP[(c + 1) & 1]);
            s[tid] = rp0; s[tid + 256] = rp1; s[tid + 512] = rp2; s[tid + 768] = rp3;
        }
        __syncthreads();
        cur = nxt;
    }

    float4* mo = reinterpret_cast<float4*>(Mout + ((size_t)b * 64 + r) * 64 + j0);
    const float* fm = &sM[cur][r * 68 + j0];
    mo[0] = make_float4(fm[0], fm[1], fm[2], fm[3]);
    mo[1] = make_float4(fm[4], fm[5], fm[6], fm[7]);
    mo[2] = make_float4(fm[8], fm[9], fm[10], fm[11]);
    mo[3] = make_float4(fm[12], fm[13], fm[14], fm[15]);
}

// ---------------------------------------------------------------------------
// Attention read + second k/v projection (unchanged).
// ---------------------------------------------------------------------------
__global__ __launch_bounds__(256) void attn_kernel(
    const float* __restrict__ qg, const float* __restrict__ Mbuf,
    const float* __restrict__ Wk, const float* __restrict__ Wv,
    float* __restrict__ ks2, float* __restrict__ vs2)
{
    __shared__ __align__(16) float sM[64 * 65];
    __shared__ __align__(16) float sWkT[64 * 65];
    __shared__ __align__(16) float sWvT[64 * 65];
    __shared__ __align__(16) float sA[64 * 36];
    __shared__ __align__(16) float sB[64 * 36];

    const int b = blockIdx.y;
    const int tile0 = blockIdx.x * 32;
    const int tid = threadIdx.x;
    const int lane = tid & 63;
    const int t0 = (tid >> 6) * 8;
    const size_t qbase = (size_t)b * 2048 + tile0;

    for (int idx = tid; idx < 4096; idx += 256) {
        int rr = idx >> 6, cc = idx & 63;
        sM[rr * 65 + cc] = Mbuf[(size_t)b * 4096 + idx];
        sWkT[cc * 65 + rr] = Wk[idx];
        sWvT[cc * 65 + rr] = Wv[idx];
    }
    for (int it = tid; it < 512; it += 256) {
        int hg = it & 15, t = it >> 4;
        float4 qv = *reinterpret_cast<const float4*>(&qg[(qbase + t) * 64 + hg * 4]);
        sA[(hg * 4 + 0) * 36 + t] = qv.x;
        sA[(hg * 4 + 1) * 36 + t] = qv.y;
        sA[(hg * 4 + 2) * 36 + t] = qv.z;
        sA[(hg * 4 + 3) * 36 + t] = qv.w;
    }
    __syncthreads();

    float acc[8];
#pragma unroll
    for (int u = 0; u < 8; ++u) acc[u] = 0.f;
    for (int h = 0; h < 64; ++h) {
        float w = sM[h * 65 + lane];
        const float4* qp = reinterpret_cast<const float4*>(&sA[h * 36 + t0]);
        float4 q0 = qp[0], q1 = qp[1];
        acc[0] = fmaf(w, q0.x, acc[0]); acc[1] = fmaf(w, q0.y, acc[1]);
        acc[2] = fmaf(w, q0.z, acc[2]); acc[3] = fmaf(w, q0.w, acc[3]);
        acc[4] = fmaf(w, q1.x, acc[4]); acc[5] = fmaf(w, q1.y, acc[5]);
        acc[6] = fmaf(w, q1.z, acc[6]); acc[7] = fmaf(w, q1.w, acc[7]);
    }

#pragma unroll
    for (int u = 0; u < 8; ++u) {
        float sv = acc[u] * 0.125f;
        float mx = sv;
        for (int off = 32; off; off >>= 1) mx = fmaxf(mx, __shfl_xor(mx, off));
        float e = __expf(sv - mx);
        float sm = e;
        for (int off = 32; off; off >>= 1) sm += __shfl_xor(sm, off);
        acc[u] = e / sm;
    }
#pragma unroll
    for (int u = 0; u < 8; ++u) sB[lane * 36 + t0 + u] = acc[u];
    __syncthreads();

#pragma unroll
    for (int u = 0; u < 8; ++u) acc[u] = 0.f;
    for (int k = 0; k < 64; ++k) {
        float m = sM[lane * 65 + k];
        const float4* pp = reinterpret_cast<const float4*>(&sB[k * 36 + t0]);
        float4 p0 = pp[0], p1 = pp[1];
        acc[0] = fmaf(m, p0.x, acc[0]); acc[1] = fmaf(m, p0.y, acc[1]);
        acc[2] = fmaf(m, p0.z, acc[2]); acc[3] = fmaf(m, p0.w, acc[3]);
        acc[4] = fmaf(m, p1.x, acc[4]); acc[5] = fmaf(m, p1.y, acc[5]);
        acc[6] = fmaf(m, p1.z, acc[6]); acc[7] = fmaf(m, p1.w, acc[7]);
    }
#pragma unroll
    for (int u = 0; u < 8; ++u) sA[lane * 36 + t0 + u] = acc[u];
    __syncthreads();

    float ak[8], av[8];
#pragma unroll
    for (int u = 0; u < 8; ++u) { ak[u] = 0.f; av[u] = 0.f; }
    for (int h = 0; h < 64; ++h) {
        float wk = sWkT[h * 65 + lane];
        float wv = sWvT[h * 65 + lane];
        const float4* cp = reinterpret_cast<const float4*>(&sA[h * 36 + t0]);
        float4 c0 = cp[0], c1 = cp[1];
        ak[0] = fmaf(wk, c0.x, ak[0]); av[0] = fmaf(wv, c0.x, av[0]);
        ak[1] = fmaf(wk, c0.y, ak[1]); av[1] = fmaf(wv, c0.y, av[1]);
        ak[2] = fmaf(wk, c0.z, ak[2]); av[2] = fmaf(wv, c0.z, av[2]);
        ak[3] = fmaf(wk, c0.w, ak[3]); av[3] = fmaf(wv, c0.w, av[3]);
        ak[4] = fmaf(wk, c1.x, ak[4]); av[4] = fmaf(wv, c1.x, av[4]);
        ak[5] = fmaf(wk, c1.y, ak[5]); av[5] = fmaf(wv, c1.y, av[5]);
        ak[6] = fmaf(wk, c1.z, ak[6]); av[6] = fmaf(wv, c1.z, av[6]);
        ak[7] = fmaf(wk, c1.w, ak[7]); av[7] = fmaf(wv, c1.w, av[7]);
    }
#pragma unroll
    for (int u = 0; u < 8; ++u) {
        float ssq = ak[u] * ak[u];
        for (int off = 32; off; off >>= 1) ssq += __shfl_xor(ssq, off);
        float n = sqrtf(ssq);
        float sc = 1.f / fmaxf(n, 1e-12f);
        const size_t o = (qbase + t0 + u) * 64 + lane;
        ks2[o] = ak[u] * sc;
        vs2[o] = av[u];
    }
}

// ---------------------------------------------------------------------------
// Output: read = M2 @ q_last; out = read @ Wout^T + bout
// ---------------------------------------------------------------------------
__global__ __launch_bounds__(128) void out_kernel(
    const float* __restrict__ M2, const float* __restrict__ qlast,
    const float* __restrict__ Wout, const float* __restrict__ bout,
    float* __restrict__ out)
{
    const int b = blockIdx.x;
    const int tid = threadIdx.x;
    __shared__ float sq[64], sread[64];
    if (tid < 64) sq[tid] = qlast[b * 64 + tid];
    __syncthreads();
    if (tid < 64) {
        const float* Mr = M2 + ((size_t)b * 64 + tid) * 64;
        float acc = 0.f;
        for (int j = 0; j < 64; ++j) acc = fmaf(Mr[j], sq[j], acc);
        sread[tid] = acc;
    }
    __syncthreads();
    float acc = bout[tid];
    for (int h = 0; h < 64; ++h) acc = fmaf(Wout[tid * 64 + h], sread[h], acc);
    out[b * 128 + tid] = acc;
}

// ---------------------------------------------------------------------------
extern "C" void kernel_launch(void* const* d_in, const int* in_sizes, int n_in,
                              void* d_out, int out_size, void* d_ws, size_t ws_size,
                              hipStream_t stream)
{
    const int* x        = (const int*)d_in[0];
    const float* embed  = (const float*)d_in[1];
    const float* W1     = (const float*)d_in[2];
    const float* b1     = (const float*)d_in[3];
    const float* W2     = (const float*)d_in[4];
    const float* b2     = (const float*)d_in[5];
    const float* ln_g   = (const float*)d_in[6];
    const float* ln_b   = (const float*)d_in[7];
    const float* Wk     = (const float*)d_in[8];
    const float* Wv     = (const float*)d_in[9];
    const float* Wq     = (const float*)d_in[10];
    const float* Wattn  = (const float*)d_in[11];
    const float* Wout   = (const float*)d_in[12];
    const float* bout   = (const float*)d_in[13];

    // workspace layout (floats): ks | vs | q | qlast | M | M2
    float* ws = (float*)d_ws;
    float* ks = ws;
    float* vs = ks + (size_t)NB * SEQL * 64;
    float* qb = vs + (size_t)NB * SEQL * 64;
    float* ql = qb + (size_t)NB * 2048 * 64;
    float* M  = ql + (size_t)NB * 64;
    float* M2 = M + (size_t)NB * 64 * 64;
    if (ws_size < (size_t)(M2 + (size_t)NB * 64 * 64 - ws) * sizeof(float)) return;

    hipLaunchKernelGGL(encoder_kernel, dim3((NB * SEQL) / 64), dim3(256), 0, stream,
                       x, embed, W1, b1, W2, b2, ln_g, ln_b, Wk, Wv, Wq, Wattn,
                       ks, vs, qb, ql);

    // scan 1: L=4096, C=256 -> 16 chunks/batch, 1024 parallel chunk jobs
    const int C1 = 256, nc1 = SEQL / C1;
    hipLaunchKernelGGL(chunk_kernel, dim3(NB * nc1), dim3(256), 0, stream, ks, vs, C1);
    hipLaunchKernelGGL(combine_kernel, dim3(NB), dim3(256), 0, stream,
                       ks, vs, (const float*)nullptr, M, nc1, C1 * 64);

    // attention + second k/v projection (ks2/vs2 reuse ks/vs)
    hipLaunchKernelGGL(attn_kernel, dim3(64, NB), dim3(256), 0, stream,
                       qb, M, Wk, Wv, ks, vs);

    // scan 2: L=2048, C=128 -> 16 chunks/batch, 1024 parallel chunk jobs
    const int C2 = 128, nc2 = 2048 / C2;
    hipLaunchKernelGGL(chunk_kernel, dim3(NB * nc2), dim3(256), 0, stream, ks, vs, C2);
    hipLaunchKernelGGL(combine_kernel, dim3(NB), dim3(256), 0, stream,
                       ks, vs, M, M2, nc2, C2 * 64);

    hipLaunchKernelGGL(out_kernel, dim3(NB), dim3(128), 0, stream,
                       M2, ql, Wout, bout, (float*)d_out);
}

// Round 10
// 567.276 us; speedup vs baseline: 6.1164x; 1.0728x over previous
//
#include <hip/hip_runtime.h>

#define SEQL 4096
#define NB 64

// ---------------------------------------------------------------------------
// DPP quad-reductions (VALU pipe, no DS ops).
// ---------------------------------------------------------------------------
__device__ __forceinline__ float dpp_xor1_add(float x) {
    int v = __builtin_amdgcn_mov_dpp(__float_as_int(x), 0xB1, 0xF, 0xF, true);
    return x + __int_as_float(v);
}
__device__ __forceinline__ float dpp_xor2_add(float x) {
    int v = __builtin_amdgcn_mov_dpp(__float_as_int(x), 0x4E, 0xF, 0xF, true);
    return x + __int_as_float(v);
}

// ---------------------------------------------------------------------------
// Shared helpers: 4x4-tile GEMM on 64x68 LDS buffers (encoder v4 pattern).
// ---------------------------------------------------------------------------
#define FMA16(A, W, H)                                      \
    A[0]  = fmaf(W.x, H.x, A[0]);  A[1]  = fmaf(W.x, H.y, A[1]);   \
    A[2]  = fmaf(W.x, H.z, A[2]);  A[3]  = fmaf(W.x, H.w, A[3]);   \
    A[4]  = fmaf(W.y, H.x, A[4]);  A[5]  = fmaf(W.y, H.y, A[5]);   \
    A[6]  = fmaf(W.y, H.z, A[6]);  A[7]  = fmaf(W.y, H.w, A[7]);   \
    A[8]  = fmaf(W.z, H.x, A[8]);  A[9]  = fmaf(W.z, H.y, A[9]);   \
    A[10] = fmaf(W.z, H.z, A[10]); A[11] = fmaf(W.z, H.w, A[11]);  \
    A[12] = fmaf(W.w, H.x, A[12]); A[13] = fmaf(W.w, H.y, A[13]);  \
    A[14] = fmaf(W.w, H.z, A[14]); A[15] = fmaf(W.w, H.w, A[15])

__device__ __forceinline__ void proj_tile64(const float* __restrict__ sW,
                                            const float* __restrict__ sA,
                                            int jq, int tq, float* __restrict__ a)
{
#pragma unroll
    for (int u = 0; u < 16; ++u) a[u] = 0.f;
#pragma unroll 2
    for (int i = 0; i < 64; ++i) {
        float4 w  = *reinterpret_cast<const float4*>(&sW[i * 68 + jq]);
        float4 h4 = *reinterpret_cast<const float4*>(&sA[i * 68 + tq]);
        FMA16(a, w, h4);
    }
}

// sW[c*68 + j] = W[j*ldw + col0 + c]  for j,c in [0,64)  (transposed stage)
__device__ __forceinline__ void stage_w_t(const float* __restrict__ W, int ldw, int col0,
                                          float* __restrict__ sWb, int tid)
{
#pragma unroll
    for (int it = 0; it < 4; ++it) {
        int item = it * 256 + tid;
        int j = item & 63, cq = item >> 6;
        float4 w = *reinterpret_cast<const float4*>(&W[(size_t)j * ldw + col0 + cq * 4]);
        sWb[(cq * 4 + 0) * 68 + j] = w.x;
        sWb[(cq * 4 + 1) * 68 + j] = w.y;
        sWb[(cq * 4 + 2) * 68 + j] = w.z;
        sWb[(cq * 4 + 3) * 68 + j] = w.w;
    }
}

// sWb[r*68 + c] = W[r*64 + c]  (non-transposed stage, float4 rows)
__device__ __forceinline__ void stage_w_n(const float* __restrict__ W,
                                          float* __restrict__ sWb, int tid)
{
#pragma unroll
    for (int it = 0; it < 4; ++it) {
        int item = it * 256 + tid;
        int r = item >> 4, c4 = item & 15;
        float4 w = *reinterpret_cast<const float4*>(&W[(size_t)r * 64 + c4 * 4]);
        *reinterpret_cast<float4*>(&sWb[r * 68 + c4 * 4]) = w;
    }
}

// ---------------------------------------------------------------------------
// Encoder v4 (unchanged from round 9).
// ---------------------------------------------------------------------------
__global__ __launch_bounds__(256) void encoder_kernel(
    const int* __restrict__ x, const float* __restrict__ embed,
    const float* __restrict__ W1, const float* __restrict__ b1,
    const float* __restrict__ W2, const float* __restrict__ b2,
    const float* __restrict__ ln_g, const float* __restrict__ ln_b,
    const float* __restrict__ Wk, const float* __restrict__ Wv,
    const float* __restrict__ Wq, const float* __restrict__ Wattn,
    float* __restrict__ ks, float* __restrict__ vs,
    float* __restrict__ qbuf, float* __restrict__ qlast)
{
    __shared__ __align__(16) float sZ[64 * 68];
    __shared__ __align__(16) float sF[64 * 68];
    __shared__ __align__(16) float sW[64 * 68];

    const int tid = threadIdx.x;
    const size_t g0 = (size_t)blockIdx.x * 64;
    const int b = (int)(g0 >> 12);
    const int l0 = (int)(g0 & (SEQL - 1));
    const int jq = (tid & 15) * 4;
    const int tq = (tid >> 4) * 4;

    for (int idx = tid; idx < 4096; idx += 256) {
        int t = idx >> 6, i = idx & 63;
        sZ[i * 68 + t] = embed[(size_t)x[g0 + t] * 64 + i];
    }

    float zacc[16];
#pragma unroll
    for (int u = 0; u < 16; ++u) zacc[u] = 0.f;
    for (int ph = 0; ph < 2; ++ph) {
        if (ph) __syncthreads();
        stage_w_t(W1 + (size_t)ph * 64 * 64, 64, 0, sW, tid);
        __syncthreads();
        float a[16];
        proj_tile64(sW, sZ, jq, tq, a);
        float4 bb = *reinterpret_cast<const float4*>(&b1[ph * 64 + jq]);
        float bv[4] = {bb.x, bb.y, bb.z, bb.w};
#pragma unroll
        for (int u = 0; u < 4; ++u) {
            float4 o;
            o.x = fmaxf(a[u * 4 + 0] + bv[u], 0.f);
            o.y = fmaxf(a[u * 4 + 1] + bv[u], 0.f);
            o.z = fmaxf(a[u * 4 + 2] + bv[u], 0.f);
            o.w = fmaxf(a[u * 4 + 3] + bv[u], 0.f);
            *reinterpret_cast<float4*>(&sF[(jq + u) * 68 + tq]) = o;
        }
        __syncthreads();
        stage_w_t(W2, 128, ph * 64, sW, tid);
        __syncthreads();
#pragma unroll 2
        for (int p = 0; p < 64; ++p) {
            float4 w  = *reinterpret_cast<const float4*>(&sW[p * 68 + jq]);
            float4 f4 = *reinterpret_cast<const float4*>(&sF[p * 68 + tq]);
            FMA16(zacc, w, f4);
        }
    }

    {
        float z[16];
        float4 b2v = *reinterpret_cast<const float4*>(&b2[jq]);
        float bv[4] = {b2v.x, b2v.y, b2v.z, b2v.w};
#pragma unroll
        for (int u = 0; u < 4; ++u) {
            float4 h4 = *reinterpret_cast<const float4*>(&sZ[(jq + u) * 68 + tq]);
            z[u * 4 + 0] = h4.x + bv[u] + zacc[u * 4 + 0];
            z[u * 4 + 1] = h4.y + bv[u] + zacc[u * 4 + 1];
            z[u * 4 + 2] = h4.z + bv[u] + zacc[u * 4 + 2];
            z[u * 4 + 3] = h4.w + bv[u] + zacc[u * 4 + 3];
        }
        float s[4], ss[4];
#pragma unroll
        for (int v = 0; v < 4; ++v) {
            s[v]  = z[v] + z[4 + v] + z[8 + v] + z[12 + v];
            ss[v] = z[v] * z[v] + z[4 + v] * z[4 + v]
                  + z[8 + v] * z[8 + v] + z[12 + v] * z[12 + v];
        }
#pragma unroll
        for (int m = 1; m <= 8; m <<= 1) {
#pragma unroll
            for (int v = 0; v < 4; ++v) {
                s[v]  += __shfl_xor(s[v], m);
                ss[v] += __shfl_xor(ss[v], m);
            }
        }
        float mu[4], inv[4];
#pragma unroll
        for (int v = 0; v < 4; ++v) {
            mu[v] = s[v] * 0.015625f;
            float var = ss[v] * 0.015625f - mu[v] * mu[v];
            inv[v] = rsqrtf(var + 1e-5f);
        }
        float4 g4  = *reinterpret_cast<const float4*>(&ln_g[jq]);
        float4 be4 = *reinterpret_cast<const float4*>(&ln_b[jq]);
        float gv[4] = {g4.x, g4.y, g4.z, g4.w};
        float bev[4] = {be4.x, be4.y, be4.z, be4.w};
#pragma unroll
        for (int u = 0; u < 4; ++u) {
            float4 o;
            o.x = (z[u * 4 + 0] - mu[0]) * inv[0] * gv[u] + bev[u];
            o.y = (z[u * 4 + 1] - mu[1]) * inv[1] * gv[u] + bev[u];
            o.z = (z[u * 4 + 2] - mu[2]) * inv[2] * gv[u] + bev[u];
            o.w = (z[u * 4 + 3] - mu[3]) * inv[3] * gv[u] + bev[u];
            *reinterpret_cast<float4*>(&sZ[(jq + u) * 68 + tq]) = o;
        }
    }

    {
        __syncthreads();
        stage_w_t(Wk, 64, 0, sW, tid);
        __syncthreads();
        float a[16];
        proj_tile64(sW, sZ, jq, tq, a);
        float ssq[4];
#pragma unroll
        for (int v = 0; v < 4; ++v)
            ssq[v] = a[v] * a[v] + a[4 + v] * a[4 + v]
                   + a[8 + v] * a[8 + v] + a[12 + v] * a[12 + v];
#pragma unroll
        for (int m = 1; m <= 8; m <<= 1) {
#pragma unroll
            for (int v = 0; v < 4; ++v) ssq[v] += __shfl_xor(ssq[v], m);
        }
#pragma unroll
        for (int v = 0; v < 4; ++v) {
            float sc = 1.f / fmaxf(sqrtf(ssq[v]), 1e-12f);
            float4 o = make_float4(a[v] * sc, a[4 + v] * sc, a[8 + v] * sc, a[12 + v] * sc);
            *reinterpret_cast<float4*>(&ks[(g0 + tq + v) * 64 + jq]) = o;
        }
    }

    {
        __syncthreads();
        stage_w_t(Wv, 64, 0, sW, tid);
        __syncthreads();
        float a[16];
        proj_tile64(sW, sZ, jq, tq, a);
#pragma unroll
        for (int v = 0; v < 4; ++v) {
            float4 o = make_float4(a[v], a[4 + v], a[8 + v], a[12 + v]);
            *reinterpret_cast<float4*>(&vs[(g0 + tq + v) * 64 + jq]) = o;
        }
    }

    if (l0 < 2048) {
        __syncthreads();
        stage_w_t(Wattn, 64, 0, sW, tid);
        __syncthreads();
        float a[16];
        proj_tile64(sW, sZ, jq, tq, a);
#pragma unroll
        for (int v = 0; v < 4; ++v) {
            float4 o = make_float4(a[v], a[4 + v], a[8 + v], a[12 + v]);
            *reinterpret_cast<float4*>(&qbuf[((size_t)b * 2048 + l0 + tq + v) * 64 + jq]) = o;
        }
    }

    if (l0 == SEQL - 64) {
        __syncthreads();
        stage_w_t(Wq, 64, 0, sW, tid);
        __syncthreads();
        float a[16];
        proj_tile64(sW, sZ, jq, tq, a);
        if ((tid >> 4) == 15) {
            float4 o = make_float4(a[3], a[7], a[11], a[15]);
            *reinterpret_cast<float4*>(&qlast[(size_t)b * 64 + jq]) = o;
        }
    }
}

// ---------------------------------------------------------------------------
// Chunked delta scan, phase A (unchanged from round 8).
// ---------------------------------------------------------------------------
#define STEP2(K0, K1, K2, K3, V)                                                \
    do {                                                                        \
        float dp0 = fmaf(p[0], K0.x, fmaf(p[1], K0.y, fmaf(p[2], K0.z, p[3] * K0.w))); \
        float dp1 = fmaf(p[4], K1.x, fmaf(p[5], K1.y, fmaf(p[6], K1.z, p[7] * K1.w))); \
        float dp2 = fmaf(p[8], K2.x, fmaf(p[9], K2.y, fmaf(p[10], K2.z, p[11] * K2.w))); \
        float dp3 = fmaf(p[12], K3.x, fmaf(p[13], K3.y, fmaf(p[14], K3.z, p[15] * K3.w))); \
        float dq0 = fmaf(q[0], K0.x, fmaf(q[1], K0.y, fmaf(q[2], K0.z, q[3] * K0.w))); \
        float dq1 = fmaf(q[4], K1.x, fmaf(q[5], K1.y, fmaf(q[6], K1.z, q[7] * K1.w))); \
        float dq2 = fmaf(q[8], K2.x, fmaf(q[9], K2.y, fmaf(q[10], K2.z, q[11] * K2.w))); \
        float dq3 = fmaf(q[12], K3.x, fmaf(q[13], K3.y, fmaf(q[14], K3.z, q[15] * K3.w))); \
        float ddp = (dp0 + dp1) + (dp2 + dp3);                                  \
        float ddq = (dq0 + dq1) + (dq2 + dq3);                                  \
        ddp = dpp_xor1_add(ddp);  ddq = dpp_xor1_add(ddq);                      \
        ddp = dpp_xor2_add(ddp);  ddq = dpp_xor2_add(ddq);                      \
        float up = -ddp;                                                        \
        float uq = V - ddq;                                                     \
        p[0] = fmaf(up, K0.x, p[0]);   q[0] = fmaf(uq, K0.x, q[0]);             \
        p[1] = fmaf(up, K0.y, p[1]);   q[1] = fmaf(uq, K0.y, q[1]);             \
        p[2] = fmaf(up, K0.z, p[2]);   q[2] = fmaf(uq, K0.z, q[2]);             \
        p[3] = fmaf(up, K0.w, p[3]);   q[3] = fmaf(uq, K0.w, q[3]);             \
        p[4] = fmaf(up, K1.x, p[4]);   q[4] = fmaf(uq, K1.x, q[4]);             \
        p[5] = fmaf(up, K1.y, p[5]);   q[5] = fmaf(uq, K1.y, q[5]);             \
        p[6] = fmaf(up, K1.z, p[6]);   q[6] = fmaf(uq, K1.z, q[6]);             \
        p[7] = fmaf(up, K1.w, p[7]);   q[7] = fmaf(uq, K1.w, q[7]);             \
        p[8] = fmaf(up, K2.x, p[8]);   q[8] = fmaf(uq, K2.x, q[8]);             \
        p[9] = fmaf(up, K2.y, p[9]);   q[9] = fmaf(uq, K2.y, q[9]);             \
        p[10] = fmaf(up, K2.z, p[10]); q[10] = fmaf(uq, K2.z, q[10]);           \
        p[11] = fmaf(up, K2.w, p[11]); q[11] = fmaf(uq, K2.w, q[11]);           \
        p[12] = fmaf(up, K3.x, p[12]); q[12] = fmaf(uq, K3.x, q[12]);           \
        p[13] = fmaf(up, K3.y, p[13]); q[13] = fmaf(uq, K3.y, q[13]);           \
        p[14] = fmaf(up, K3.z, p[14]); q[14] = fmaf(uq, K3.z, q[14]);           \
        p[15] = fmaf(up, K3.w, p[15]); q[15] = fmaf(uq, K3.w, q[15]);           \
    } while (0)

__global__ __launch_bounds__(256) void chunk_kernel(
    float* __restrict__ ksb, float* __restrict__ vsb, int C)
{
    __shared__ __align__(16) float sk[2][32 * 64];
    __shared__ __align__(16) float sv[2][32 * 64];

    const int job = blockIdx.x;
    const int tid = threadIdx.x;
    const int r = tid >> 2;
    const int c0 = (tid & 3) * 16;
    float* kc = ksb + (size_t)job * C * 64;
    float* vc = vsb + (size_t)job * C * 64;

    float p[16], q[16];
#pragma unroll
    for (int j = 0; j < 16; ++j) { p[j] = (c0 + j == r) ? 1.f : 0.f; q[j] = 0.f; }

    const int nt = C >> 5;
    float4 rk0, rk1, rv0, rv1;

    {
        const float4* gk = reinterpret_cast<const float4*>(kc);
        const float4* gv = reinterpret_cast<const float4*>(vc);
        float4 a0 = gk[tid], a1 = gk[256 + tid];
        float4 b0 = gv[tid], b1 = gv[256 + tid];
        float4* dk = reinterpret_cast<float4*>(sk[0]);
        float4* dv = reinterpret_cast<float4*>(sv[0]);
        dk[tid] = a0; dk[256 + tid] = a1;
        dv[tid] = b0; dv[256 + tid] = b1;
    }
    if (nt > 1) {
        const float4* gk = reinterpret_cast<const float4*>(kc + 2048);
        const float4* gv = reinterpret_cast<const float4*>(vc + 2048);
        rk0 = gk[tid]; rk1 = gk[256 + tid];
        rv0 = gv[tid]; rv1 = gv[256 + tid];
    }
    __syncthreads();

    int cur = 0;
    for (int tile = 0; tile < nt; ++tile) {
        if (tile + 1 < nt) {
            float4* dk = reinterpret_cast<float4*>(sk[cur ^ 1]);
            float4* dv = reinterpret_cast<float4*>(sv[cur ^ 1]);
            dk[tid] = rk0; dk[256 + tid] = rk1;
            dv[tid] = rv0; dv[256 + tid] = rv1;
            if (tile + 2 < nt) {
                const float4* gk = reinterpret_cast<const float4*>(kc + (size_t)(tile + 2) * 2048);
                const float4* gv = reinterpret_cast<const float4*>(vc + (size_t)(tile + 2) * 2048);
                rk0 = gk[tid]; rk1 = gk[256 + tid];
                rv0 = gv[tid]; rv1 = gv[256 + tid];
            }
        }

        const float* kl = sk[cur] + c0;
        const float* vl = sv[cur] + r;
        float4 a0, a1, a2, a3, e0, e1, e2, e3;
        float va, ve;
        {
            const float4* kp = reinterpret_cast<const float4*>(kl);
            a0 = kp[0]; a1 = kp[1]; a2 = kp[2]; a3 = kp[3];
            va = vl[0];
        }
#pragma unroll
        for (int t = 0; t < 32; t += 2) {
            {
                const float4* kp = reinterpret_cast<const float4*>(kl + (t + 1) * 64);
                e0 = kp[0]; e1 = kp[1]; e2 = kp[2]; e3 = kp[3];
                ve = vl[(t + 1) * 64];
            }
            STEP2(a0, a1, a2, a3, va);
            if (t + 2 < 32) {
                const float4* kp = reinterpret_cast<const float4*>(kl + (t + 2) * 64);
                a0 = kp[0]; a1 = kp[1]; a2 = kp[2]; a3 = kp[3];
                va = vl[(t + 2) * 64];
            }
            STEP2(e0, e1, e2, e3, ve);
        }
        __syncthreads();
        cur ^= 1;
    }

    float4* po = reinterpret_cast<float4*>(kc + r * 64 + c0);
    po[0] = make_float4(p[0], p[1], p[2], p[3]);
    po[1] = make_float4(p[4], p[5], p[6], p[7]);
    po[2] = make_float4(p[8], p[9], p[10], p[11]);
    po[3] = make_float4(p[12], p[13], p[14], p[15]);
    float4* qo = reinterpret_cast<float4*>(vc + r * 64 + c0);
    qo[0] = make_float4(q[0], q[1], q[2], q[3]);
    qo[1] = make_float4(q[4], q[5], q[6], q[7]);
    qo[2] = make_float4(q[8], q[9], q[10], q[11]);
    qo[3] = make_float4(q[12], q[13], q[14], q[15]);
}

// ---------------------------------------------------------------------------
// Chunked delta scan, phase B (unchanged).
// ---------------------------------------------------------------------------
__global__ __launch_bounds__(256) void combine_kernel(
    const float* __restrict__ Pb, const float* __restrict__ Qb,
    const float* __restrict__ Min, float* __restrict__ Mout,
    int nc, int chunk_stride)
{
    __shared__ __align__(16) float sM[2][64 * 68];
    __shared__ __align__(16) float sP[2][64 * 64];
    const int b = blockIdx.x;
    const int tid = threadIdx.x;
    const int r = tid >> 2;
    const int j0 = (tid & 3) * 16;

    if (Min) {
        const float4* mi = reinterpret_cast<const float4*>(Min + ((size_t)b * 64 + r) * 64 + j0);
        float4* mo = reinterpret_cast<float4*>(&sM[0][r * 68 + j0]);
#pragma unroll
        for (int u = 0; u < 4; ++u) mo[u] = mi[u];
    } else {
#pragma unroll
        for (int u = 0; u < 16; ++u) sM[0][r * 68 + j0 + u] = 0.f;
    }
    {
        const float4* g = reinterpret_cast<const float4*>(Pb + (size_t)b * nc * chunk_stride);
        float4* s = reinterpret_cast<float4*>(sP[0]);
        for (int i = tid; i < 1024; i += 256) s[i] = g[i];
    }
    __syncthreads();

    int cur = 0;
    for (int c = 0; c < nc; ++c) {
        const size_t cbase = (size_t)(b * nc + c) * chunk_stride;
        float4 rp0, rp1, rp2, rp3;
        if (c + 1 < nc) {
            const float4* g = reinterpret_cast<const float4*>(Pb + cbase + chunk_stride);
            rp0 = g[tid]; rp1 = g[tid + 256]; rp2 = g[tid + 512]; rp3 = g[tid + 768];
        }
        float4 rq0, rq1, rq2, rq3;
        {
            const float4* gq = reinterpret_cast<const float4*>(Qb + cbase + r * 64 + j0);
            rq0 = gq[0]; rq1 = gq[1]; rq2 = gq[2]; rq3 = gq[3];
        }
        float acc[16];
#pragma unroll
        for (int u = 0; u < 16; ++u) acc[u] = 0.f;
        const float* Mrow = &sM[cur][r * 68];
        const float* Pl = sP[c & 1];
#pragma unroll
        for (int mg = 0; mg < 16; ++mg) {
            float4 a = *reinterpret_cast<const float4*>(Mrow + mg * 4);
#pragma unroll
            for (int e2 = 0; e2 < 4; ++e2) {
                float am = (e2 == 0) ? a.x : (e2 == 1) ? a.y : (e2 == 2) ? a.z : a.w;
                const float4* pr = reinterpret_cast<const float4*>(Pl + (mg * 4 + e2) * 64 + j0);
                float4 p0 = pr[0], p1 = pr[1], p2 = pr[2], p3 = pr[3];
                acc[0] = fmaf(am, p0.x, acc[0]);  acc[1] = fmaf(am, p0.y, acc[1]);
                acc[2] = fmaf(am, p0.z, acc[2]);  acc[3] = fmaf(am, p0.w, acc[3]);
                acc[4] = fmaf(am, p1.x, acc[4]);  acc[5] = fmaf(am, p1.y, acc[5]);
                acc[6] = fmaf(am, p1.z, acc[6]);  acc[7] = fmaf(am, p1.w, acc[7]);
                acc[8] = fmaf(am, p2.x, acc[8]);  acc[9] = fmaf(am, p2.y, acc[9]);
                acc[10] = fmaf(am, p2.z, acc[10]); acc[11] = fmaf(am, p2.w, acc[11]);
                acc[12] = fmaf(am, p3.x, acc[12]); acc[13] = fmaf(am, p3.y, acc[13]);
                acc[14] = fmaf(am, p3.z, acc[14]); acc[15] = fmaf(am, p3.w, acc[15]);
            }
        }
        const int nxt = cur ^ 1;
        float* om = &sM[nxt][r * 68 + j0];
        om[0] = acc[0] + rq0.x;  om[1] = acc[1] + rq0.y;
        om[2] = acc[2] + rq0.z;  om[3] = acc[3] + rq0.w;
        om[4] = acc[4] + rq1.x;  om[5] = acc[5] + rq1.y;
        om[6] = acc[6] + rq1.z;  om[7] = acc[7] + rq1.w;
        om[8] = acc[8] + rq2.x;  om[9] = acc[9] + rq2.y;
        om[10] = acc[10] + rq2.z; om[11] = acc[11] + rq2.w;
        om[12] = acc[12] + rq3.x; om[13] = acc[13] + rq3.y;
        om[14] = acc[14] + rq3.z; om[15] = acc[15] + rq3.w;
        if (c + 1 < nc) {
            float4* s = reinterpret_cast<float4*>(sP[(c + 1) & 1]);
            s[tid] = rp0; s[tid + 256] = rp1; s[tid + 512] = rp2; s[tid + 768] = rp3;
        }
        __syncthreads();
        cur = nxt;
    }

    float4* mo = reinterpret_cast<float4*>(Mout + ((size_t)b * 64 + r) * 64 + j0);
    const float* fm = &sM[cur][r * 68 + j0];
    mo[0] = make_float4(fm[0], fm[1], fm[2], fm[3]);
    mo[1] = make_float4(fm[4], fm[5], fm[6], fm[7]);
    mo[2] = make_float4(fm[8], fm[9], fm[10], fm[11]);
    mo[3] = make_float4(fm[12], fm[13], fm[14], fm[15]);
}

// ---------------------------------------------------------------------------
// Attention v3: 64 tokens/block, 4x4 tile/thread (encoder v4 pattern).
// 4 buffers [64][68]: sW1 = M[h][k] then Wk^T; sW2 = M^T[k][h] then Wv^T;
// sA = qT[h][t] then ctxT[h][t]; sB = pT[k][t].
// Phases: scores -> softmax(k over 16-lane group) -> ctx -> fused k2/v2 ->
// l2norm -> coalesced stores. 5 barriers.
// ---------------------------------------------------------------------------
__global__ __launch_bounds__(256) void attn_kernel(
    const float* __restrict__ qg, const float* __restrict__ Mbuf,
    const float* __restrict__ Wk, const float* __restrict__ Wv,
    float* __restrict__ ks2, float* __restrict__ vs2)
{
    __shared__ __align__(16) float sW1[64 * 68];
    __shared__ __align__(16) float sW2[64 * 68];
    __shared__ __align__(16) float sA[64 * 68];
    __shared__ __align__(16) float sB[64 * 68];

    const int b = blockIdx.y;
    const int tile0 = blockIdx.x * 64;
    const int tid = threadIdx.x;
    const int jq = (tid & 15) * 4;
    const int tq = (tid >> 4) * 4;
    const size_t qbase = (size_t)b * 2048 + tile0;
    const float* Mb = Mbuf + (size_t)b * 4096;

    stage_w_n(Mb, sW1, tid);                     // sW1[h][k] = M[h][k]
    stage_w_t(Mb, 64, 0, sW2, tid);              // sW2[k][h] = M[h][k]
    stage_w_t(qg + qbase * 64, 64, 0, sA, tid);  // sA[h][t]  = q[t][h]
    __syncthreads();

    // phase 1: scores[t][k] = sum_h q[t][h] M[h][k];  a[u*4+v] = s[tq+v][jq+u]
    float a[16];
    proj_tile64(sW1, sA, jq, tq, a);
#pragma unroll
    for (int u = 0; u < 16; ++u) a[u] *= 0.125f;

    // softmax over k (u in thread x 16-lane group)
    {
        float mx[4], sm[4];
#pragma unroll
        for (int v = 0; v < 4; ++v)
            mx[v] = fmaxf(fmaxf(a[v], a[4 + v]), fmaxf(a[8 + v], a[12 + v]));
#pragma unroll
        for (int m = 1; m <= 8; m <<= 1) {
#pragma unroll
            for (int v = 0; v < 4; ++v) mx[v] = fmaxf(mx[v], __shfl_xor(mx[v], m));
        }
#pragma unroll
        for (int v = 0; v < 4; ++v) {
            a[v]      = __expf(a[v]      - mx[v]);
            a[4 + v]  = __expf(a[4 + v]  - mx[v]);
            a[8 + v]  = __expf(a[8 + v]  - mx[v]);
            a[12 + v] = __expf(a[12 + v] - mx[v]);
            sm[v] = a[v] + a[4 + v] + a[8 + v] + a[12 + v];
        }
#pragma unroll
        for (int m = 1; m <= 8; m <<= 1) {
#pragma unroll
            for (int v = 0; v < 4; ++v) sm[v] += __shfl_xor(sm[v], m);
        }
        float rinv[4];
#pragma unroll
        for (int v = 0; v < 4; ++v) rinv[v] = 1.f / sm[v];
#pragma unroll
        for (int v = 0; v < 4; ++v) {
            a[v] *= rinv[v]; a[4 + v] *= rinv[v];
            a[8 + v] *= rinv[v]; a[12 + v] *= rinv[v];
        }
    }
    // write pT[k][t]
#pragma unroll
    for (int u = 0; u < 4; ++u)
        *reinterpret_cast<float4*>(&sB[(jq + u) * 68 + tq]) =
            make_float4(a[u * 4 + 0], a[u * 4 + 1], a[u * 4 + 2], a[u * 4 + 3]);
    __syncthreads();

    // phase 2: ctx[t][h] = sum_k p[t][k] M[h][k]
    float c[16];
    proj_tile64(sW2, sB, jq, tq, c);
#pragma unroll
    for (int u = 0; u < 4; ++u)
        *reinterpret_cast<float4*>(&sA[(jq + u) * 68 + tq]) =
            make_float4(c[u * 4 + 0], c[u * 4 + 1], c[u * 4 + 2], c[u * 4 + 3]);
    __syncthreads();

    // re-stage: Wk^T -> sW1, Wv^T -> sW2 (M no longer needed)
    stage_w_t(Wk, 64, 0, sW1, tid);
    stage_w_t(Wv, 64, 0, sW2, tid);
    __syncthreads();

    // phase 3 fused: k2/v2 projections
    float ak[16], av[16];
#pragma unroll
    for (int u = 0; u < 16; ++u) { ak[u] = 0.f; av[u] = 0.f; }
#pragma unroll 2
    for (int i = 0; i < 64; ++i) {
        float4 wk = *reinterpret_cast<const float4*>(&sW1[i * 68 + jq]);
        float4 wv = *reinterpret_cast<const float4*>(&sW2[i * 68 + jq]);
        float4 c4 = *reinterpret_cast<const float4*>(&sA[i * 68 + tq]);
        FMA16(ak, wk, c4);
        FMA16(av, wv, c4);
    }

    // l2norm over j (16-lane group) + coalesced stores
    {
        float ssq[4];
#pragma unroll
        for (int v = 0; v < 4; ++v)
            ssq[v] = ak[v] * ak[v] + ak[4 + v] * ak[4 + v]
                   + ak[8 + v] * ak[8 + v] + ak[12 + v] * ak[12 + v];
#pragma unroll
        for (int m = 1; m <= 8; m <<= 1) {
#pragma unroll
            for (int v = 0; v < 4; ++v) ssq[v] += __shfl_xor(ssq[v], m);
        }
#pragma unroll
        for (int v = 0; v < 4; ++v) {
            float sc = 1.f / fmaxf(sqrtf(ssq[v]), 1e-12f);
            const size_t o = (qbase + tq + v) * 64 + jq;
            *reinterpret_cast<float4*>(&ks2[o]) =
                make_float4(ak[v] * sc, ak[4 + v] * sc, ak[8 + v] * sc, ak[12 + v] * sc);
            *reinterpret_cast<float4*>(&vs2[o]) =
                make_float4(av[v], av[4 + v], av[8 + v], av[12 + v]);
        }
    }
}

// ---------------------------------------------------------------------------
// Output: read = M2 @ q_last; out = read @ Wout^T + bout
// ---------------------------------------------------------------------------
__global__ __launch_bounds__(128) void out_kernel(
    const float* __restrict__ M2, const float* __restrict__ qlast,
    const float* __restrict__ Wout, const float* __restrict__ bout,
    float* __restrict__ out)
{
    const int b = blockIdx.x;
    const int tid = threadIdx.x;
    __shared__ float sq[64], sread[64];
    if (tid < 64) sq[tid] = qlast[b * 64 + tid];
    __syncthreads();
    if (tid < 64) {
        const float* Mr = M2 + ((size_t)b * 64 + tid) * 64;
        float acc = 0.f;
        for (int j = 0; j < 64; ++j) acc = fmaf(Mr[j], sq[j], acc);
        sread[tid] = acc;
    }
    __syncthreads();
    float acc = bout[tid];
    for (int h = 0; h < 64; ++h) acc = fmaf(Wout[tid * 64 + h], sread[h], acc);
    out[b * 128 + tid] = acc;
}

// ---------------------------------------------------------------------------
extern "C" void kernel_launch(void* const* d_in, const int* in_sizes, int n_in,
                              void* d_out, int out_size, void* d_ws, size_t ws_size,
                              hipStream_t stream)
{
    const int* x        = (const int*)d_in[0];
    const float* embed  = (const float*)d_in[1];
    const float* W1     = (const float*)d_in[2];
    const float* b1     = (const float*)d_in[3];
    const float* W2     = (const float*)d_in[4];
    const float* b2     = (const float*)d_in[5];
    const float* ln_g   = (const float*)d_in[6];
    const float* ln_b   = (const float*)d_in[7];
    const float* Wk     = (const float*)d_in[8];
    const float* Wv     = (const float*)d_in[9];
    const float* Wq     = (const float*)d_in[10];
    const float* Wattn  = (const float*)d_in[11];
    const float* Wout   = (const float*)d_in[12];
    const float* bout   = (const float*)d_in[13];

    // workspace layout (floats): ks | vs | q | qlast | M | M2
    float* ws = (float*)d_ws;
    float* ks = ws;
    float* vs = ks + (size_t)NB * SEQL * 64;
    float* qb = vs + (size_t)NB * SEQL * 64;
    float* ql = qb + (size_t)NB * 2048 * 64;
    float* M  = ql + (size_t)NB * 64;
    float* M2 = M + (size_t)NB * 64 * 64;
    if (ws_size < (size_t)(M2 + (size_t)NB * 64 * 64 - ws) * sizeof(float)) return;

    hipLaunchKernelGGL(encoder_kernel, dim3((NB * SEQL) / 64), dim3(256), 0, stream,
                       x, embed, W1, b1, W2, b2, ln_g, ln_b, Wk, Wv, Wq, Wattn,
                       ks, vs, qb, ql);

    // scan 1: L=4096, C=256 -> 16 chunks/batch, 1024 parallel chunk jobs
    const int C1 = 256, nc1 = SEQL / C1;
    hipLaunchKernelGGL(chunk_kernel, dim3(NB * nc1), dim3(256), 0, stream, ks, vs, C1);
    hipLaunchKernelGGL(combine_kernel, dim3(NB), dim3(256), 0, stream,
                       ks, vs, (const float*)nullptr, M, nc1, C1 * 64);

    // attention + second k/v projection (ks2/vs2 reuse ks/vs)
    hipLaunchKernelGGL(attn_kernel, dim3(32, NB), dim3(256), 0, stream,
                       qb, M, Wk, Wv, ks, vs);

    // scan 2: L=2048, C=128 -> 16 chunks/batch, 1024 parallel chunk jobs
    const int C2 = 128, nc2 = 2048 / C2;
    hipLaunchKernelGGL(chunk_kernel, dim3(NB * nc2), dim3(256), 0, stream, ks, vs, C2);
    hipLaunchKernelGGL(combine_kernel, dim3(NB), dim3(256), 0, stream,
                       ks, vs, M, M2, nc2, C2 * 64);

    hipLaunchKernelGGL(out_kernel, dim3(NB), dim3(128), 0, stream,
                       M2, ql, Wout, bout, (float*)d_out);
}

// Round 11
// 494.612 us; speedup vs baseline: 7.0150x; 1.1469x over previous
//
#include <hip/hip_runtime.h>

#define SEQL 4096
#define NB 64

// ---------------------------------------------------------------------------
// DPP quad-reductions (VALU pipe, no DS ops).
// ---------------------------------------------------------------------------
__device__ __forceinline__ float dpp_xor1_add(float x) {
    int v = __builtin_amdgcn_mov_dpp(__float_as_int(x), 0xB1, 0xF, 0xF, true);
    return x + __int_as_float(v);
}
__device__ __forceinline__ float dpp_xor2_add(float x) {
    int v = __builtin_amdgcn_mov_dpp(__float_as_int(x), 0x4E, 0xF, 0xF, true);
    return x + __int_as_float(v);
}

// ---------------------------------------------------------------------------
// Shared helpers: 4x4-tile GEMM on 64x68 LDS buffers.
// ---------------------------------------------------------------------------
#define FMA16(A, W, H)                                      \
    A[0]  = fmaf(W.x, H.x, A[0]);  A[1]  = fmaf(W.x, H.y, A[1]);   \
    A[2]  = fmaf(W.x, H.z, A[2]);  A[3]  = fmaf(W.x, H.w, A[3]);   \
    A[4]  = fmaf(W.y, H.x, A[4]);  A[5]  = fmaf(W.y, H.y, A[5]);   \
    A[6]  = fmaf(W.y, H.z, A[6]);  A[7]  = fmaf(W.y, H.w, A[7]);   \
    A[8]  = fmaf(W.z, H.x, A[8]);  A[9]  = fmaf(W.z, H.y, A[9]);   \
    A[10] = fmaf(W.z, H.z, A[10]); A[11] = fmaf(W.z, H.w, A[11]);  \
    A[12] = fmaf(W.w, H.x, A[12]); A[13] = fmaf(W.w, H.y, A[13]);  \
    A[14] = fmaf(W.w, H.z, A[14]); A[15] = fmaf(W.w, H.w, A[15])

__device__ __forceinline__ void proj_tile64(const float* __restrict__ sW,
                                            const float* __restrict__ sA,
                                            int jq, int tq, float* __restrict__ a)
{
#pragma unroll
    for (int u = 0; u < 16; ++u) a[u] = 0.f;
#pragma unroll 4
    for (int i = 0; i < 64; ++i) {
        float4 w  = *reinterpret_cast<const float4*>(&sW[i * 68 + jq]);
        float4 h4 = *reinterpret_cast<const float4*>(&sA[i * 68 + tq]);
        FMA16(a, w, h4);
    }
}

// transposed weight stage, split into load (regs) and write (LDS) halves.
// thread: row j = tid&63, col groups (it*4 + tid>>6)*4.
__device__ __forceinline__ void load_w_t(const float* __restrict__ W, int ldw, int col0,
                                         int tid, float4* __restrict__ r)
{
    const int j = tid & 63;
    const int cq0 = tid >> 6;
#pragma unroll
    for (int it = 0; it < 4; ++it)
        r[it] = *reinterpret_cast<const float4*>(&W[(size_t)j * ldw + col0 + (it * 4 + cq0) * 4]);
}
__device__ __forceinline__ void write_w_t(const float4* __restrict__ r,
                                          float* __restrict__ sWb, int tid)
{
    const int j = tid & 63;
    const int cq0 = tid >> 6;
#pragma unroll
    for (int it = 0; it < 4; ++it) {
        const int c = (it * 4 + cq0) * 4;
        sWb[(c + 0) * 68 + j] = r[it].x;
        sWb[(c + 1) * 68 + j] = r[it].y;
        sWb[(c + 2) * 68 + j] = r[it].z;
        sWb[(c + 3) * 68 + j] = r[it].w;
    }
}

// one-shot stage helpers (used by attn)
__device__ __forceinline__ void stage_w_t(const float* __restrict__ W, int ldw, int col0,
                                          float* __restrict__ sWb, int tid)
{
    float4 r[4];
    load_w_t(W, ldw, col0, tid, r);
    write_w_t(r, sWb, tid);
}
__device__ __forceinline__ void stage_w_n(const float* __restrict__ W,
                                          float* __restrict__ sWb, int tid)
{
#pragma unroll
    for (int it = 0; it < 4; ++it) {
        int item = it * 256 + tid;
        int r = item >> 4, c4 = item & 15;
        float4 w = *reinterpret_cast<const float4*>(&W[(size_t)r * 64 + c4 * 4]);
        *reinterpret_cast<float4*>(&sWb[r * 68 + c4 * 4]) = w;
    }
}

// ---------------------------------------------------------------------------
// Encoder v5: 64 tokens/block, 4x4 tile/thread, T14 async-stage split —
// next weight's global loads issue during the current GEMM (latency hidden
// under compute); only the ds_write sits between barriers. k/v staged as a
// pair into sW/sF so their projections run back-to-back. 9-11 barriers.
// ---------------------------------------------------------------------------
__global__ __launch_bounds__(256) void encoder_kernel(
    const int* __restrict__ x, const float* __restrict__ embed,
    const float* __restrict__ W1, const float* __restrict__ b1,
    const float* __restrict__ W2, const float* __restrict__ b2,
    const float* __restrict__ ln_g, const float* __restrict__ ln_b,
    const float* __restrict__ Wk, const float* __restrict__ Wv,
    const float* __restrict__ Wq, const float* __restrict__ Wattn,
    float* __restrict__ ks, float* __restrict__ vs,
    float* __restrict__ qbuf, float* __restrict__ qlast)
{
    __shared__ __align__(16) float sZ[64 * 68];
    __shared__ __align__(16) float sF[64 * 68];
    __shared__ __align__(16) float sW[64 * 68];

    const int tid = threadIdx.x;
    const size_t g0 = (size_t)blockIdx.x * 64;
    const int b = (int)(g0 >> 12);
    const int l0 = (int)(g0 & (SEQL - 1));
    const int jq = (tid & 15) * 4;
    const int tq = (tid >> 4) * 4;
    const bool doq = (l0 < 2048);
    const bool dolast = (l0 == SEQL - 64);

    float4 pf[4], pf2[4];

    // P0: prefetch W1-h0; embed gather; park W1-h0; prefetch W2-h0
    load_w_t(W1, 64, 0, tid, pf);
    for (int idx = tid; idx < 4096; idx += 256) {
        int t = idx >> 6, i = idx & 63;
        sZ[i * 68 + t] = embed[(size_t)x[g0 + t] * 64 + i];
    }
    write_w_t(pf, sW, tid);
    load_w_t(W2, 128, 0, tid, pf2);
    __syncthreads();                                   // (1) sW=W1a, sZ ready

    float zacc[16];
#pragma unroll
    for (int u = 0; u < 16; ++u) zacc[u] = 0.f;

    // ff1-a
    {
        float a[16];
        proj_tile64(sW, sZ, jq, tq, a);
        float4 bb = *reinterpret_cast<const float4*>(&b1[jq]);
        float bv[4] = {bb.x, bb.y, bb.z, bb.w};
#pragma unroll
        for (int u = 0; u < 4; ++u) {
            float4 o;
            o.x = fmaxf(a[u * 4 + 0] + bv[u], 0.f);
            o.y = fmaxf(a[u * 4 + 1] + bv[u], 0.f);
            o.z = fmaxf(a[u * 4 + 2] + bv[u], 0.f);
            o.w = fmaxf(a[u * 4 + 3] + bv[u], 0.f);
            *reinterpret_cast<float4*>(&sF[(jq + u) * 68 + tq]) = o;
        }
    }
    __syncthreads();                                   // (2) sF written, sW free
    write_w_t(pf2, sW, tid);                           // sW = W2a
    load_w_t(W1 + 4096, 64, 0, tid, pf);               // prefetch W1-h1
    __syncthreads();                                   // (3)
    // ff2-a
#pragma unroll 4
    for (int p = 0; p < 64; ++p) {
        float4 w  = *reinterpret_cast<const float4*>(&sW[p * 68 + jq]);
        float4 f4 = *reinterpret_cast<const float4*>(&sF[p * 68 + tq]);
        FMA16(zacc, w, f4);
    }
    __syncthreads();                                   // (4) sW/sF free
    write_w_t(pf, sW, tid);                            // sW = W1b
    load_w_t(W2, 128, 64, tid, pf2);                   // prefetch W2-h1
    __syncthreads();                                   // (5)
    // ff1-b
    {
        float a[16];
        proj_tile64(sW, sZ, jq, tq, a);
        float4 bb = *reinterpret_cast<const float4*>(&b1[64 + jq]);
        float bv[4] = {bb.x, bb.y, bb.z, bb.w};
#pragma unroll
        for (int u = 0; u < 4; ++u) {
            float4 o;
            o.x = fmaxf(a[u * 4 + 0] + bv[u], 0.f);
            o.y = fmaxf(a[u * 4 + 1] + bv[u], 0.f);
            o.z = fmaxf(a[u * 4 + 2] + bv[u], 0.f);
            o.w = fmaxf(a[u * 4 + 3] + bv[u], 0.f);
            *reinterpret_cast<float4*>(&sF[(jq + u) * 68 + tq]) = o;
        }
    }
    __syncthreads();                                   // (6)
    write_w_t(pf2, sW, tid);                           // sW = W2b
    load_w_t(Wk, 64, 0, tid, pf);                      // prefetch Wk, Wv
    load_w_t(Wv, 64, 0, tid, pf2);
    __syncthreads();                                   // (7)
    // ff2-b
#pragma unroll 4
    for (int p = 0; p < 64; ++p) {
        float4 w  = *reinterpret_cast<const float4*>(&sW[p * 68 + jq]);
        float4 f4 = *reinterpret_cast<const float4*>(&sF[p * 68 + tq]);
        FMA16(zacc, w, f4);
    }

    // residual + LayerNorm (own cells of sZ; no barrier needed vs ff2-b)
    {
        float z[16];
        float4 b2v = *reinterpret_cast<const float4*>(&b2[jq]);
        float bv[4] = {b2v.x, b2v.y, b2v.z, b2v.w};
#pragma unroll
        for (int u = 0; u < 4; ++u) {
            float4 h4 = *reinterpret_cast<const float4*>(&sZ[(jq + u) * 68 + tq]);
            z[u * 4 + 0] = h4.x + bv[u] + zacc[u * 4 + 0];
            z[u * 4 + 1] = h4.y + bv[u] + zacc[u * 4 + 1];
            z[u * 4 + 2] = h4.z + bv[u] + zacc[u * 4 + 2];
            z[u * 4 + 3] = h4.w + bv[u] + zacc[u * 4 + 3];
        }
        float s[4], ss[4];
#pragma unroll
        for (int v = 0; v < 4; ++v) {
            s[v]  = z[v] + z[4 + v] + z[8 + v] + z[12 + v];
            ss[v] = z[v] * z[v] + z[4 + v] * z[4 + v]
                  + z[8 + v] * z[8 + v] + z[12 + v] * z[12 + v];
        }
#pragma unroll
        for (int m = 1; m <= 8; m <<= 1) {
#pragma unroll
            for (int v = 0; v < 4; ++v) {
                s[v]  += __shfl_xor(s[v], m);
                ss[v] += __shfl_xor(ss[v], m);
            }
        }
        float mu[4], inv[4];
#pragma unroll
        for (int v = 0; v < 4; ++v) {
            mu[v] = s[v] * 0.015625f;
            float var = ss[v] * 0.015625f - mu[v] * mu[v];
            inv[v] = rsqrtf(var + 1e-5f);
        }
        float4 g4  = *reinterpret_cast<const float4*>(&ln_g[jq]);
        float4 be4 = *reinterpret_cast<const float4*>(&ln_b[jq]);
        float gv[4] = {g4.x, g4.y, g4.z, g4.w};
        float bev[4] = {be4.x, be4.y, be4.z, be4.w};
#pragma unroll
        for (int u = 0; u < 4; ++u) {
            float4 o;
            o.x = (z[u * 4 + 0] - mu[0]) * inv[0] * gv[u] + bev[u];
            o.y = (z[u * 4 + 1] - mu[1]) * inv[1] * gv[u] + bev[u];
            o.z = (z[u * 4 + 2] - mu[2]) * inv[2] * gv[u] + bev[u];
            o.w = (z[u * 4 + 3] - mu[3]) * inv[3] * gv[u] + bev[u];
            *reinterpret_cast<float4*>(&sZ[(jq + u) * 68 + tq]) = o;
        }
    }
    __syncthreads();                                   // (8) sZ=hidden, sW/sF free
    write_w_t(pf, sW, tid);                            // sW = Wk
    write_w_t(pf2, sF, tid);                           // sF = Wv
    if (doq)        load_w_t(Wattn, 64, 0, tid, pf);   // prefetch q weight
    else if (dolast) load_w_t(Wq, 64, 0, tid, pf);
    __syncthreads();                                   // (9)

    // k projection + l2norm
    {
        float a[16];
        proj_tile64(sW, sZ, jq, tq, a);
        float ssq[4];
#pragma unroll
        for (int v = 0; v < 4; ++v)
            ssq[v] = a[v] * a[v] + a[4 + v] * a[4 + v]
                   + a[8 + v] * a[8 + v] + a[12 + v] * a[12 + v];
#pragma unroll
        for (int m = 1; m <= 8; m <<= 1) {
#pragma unroll
            for (int v = 0; v < 4; ++v) ssq[v] += __shfl_xor(ssq[v], m);
        }
#pragma unroll
        for (int v = 0; v < 4; ++v) {
            float sc = 1.f / fmaxf(sqrtf(ssq[v]), 1e-12f);
            float4 o = make_float4(a[v] * sc, a[4 + v] * sc, a[8 + v] * sc, a[12 + v] * sc);
            *reinterpret_cast<float4*>(&ks[(g0 + tq + v) * 64 + jq]) = o;
        }
    }
    // v projection (sF) — no barrier needed, both phases only read
    {
        float a[16];
        proj_tile64(sF, sZ, jq, tq, a);
#pragma unroll
        for (int v = 0; v < 4; ++v) {
            float4 o = make_float4(a[v], a[4 + v], a[8 + v], a[12 + v]);
            *reinterpret_cast<float4*>(&vs[(g0 + tq + v) * 64 + jq]) = o;
        }
    }

    if (doq || dolast) {
        __syncthreads();                               // (10) sW free
        write_w_t(pf, sW, tid);
        __syncthreads();                               // (11)
        float a[16];
        proj_tile64(sW, sZ, jq, tq, a);
        if (doq) {
#pragma unroll
            for (int v = 0; v < 4; ++v) {
                float4 o = make_float4(a[v], a[4 + v], a[8 + v], a[12 + v]);
                *reinterpret_cast<float4*>(&qbuf[((size_t)b * 2048 + l0 + tq + v) * 64 + jq]) = o;
            }
        } else if ((tid >> 4) == 15) {
            float4 o = make_float4(a[3], a[7], a[11], a[15]);
            *reinterpret_cast<float4*>(&qlast[(size_t)b * 64 + jq]) = o;
        }
    }
}

// ---------------------------------------------------------------------------
// Chunked delta scan, phase A (unchanged from round 8).
// ---------------------------------------------------------------------------
#define STEP2(K0, K1, K2, K3, V)                                                \
    do {                                                                        \
        float dp0 = fmaf(p[0], K0.x, fmaf(p[1], K0.y, fmaf(p[2], K0.z, p[3] * K0.w))); \
        float dp1 = fmaf(p[4], K1.x, fmaf(p[5], K1.y, fmaf(p[6], K1.z, p[7] * K1.w))); \
        float dp2 = fmaf(p[8], K2.x, fmaf(p[9], K2.y, fmaf(p[10], K2.z, p[11] * K2.w))); \
        float dp3 = fmaf(p[12], K3.x, fmaf(p[13], K3.y, fmaf(p[14], K3.z, p[15] * K3.w))); \
        float dq0 = fmaf(q[0], K0.x, fmaf(q[1], K0.y, fmaf(q[2], K0.z, q[3] * K0.w))); \
        float dq1 = fmaf(q[4], K1.x, fmaf(q[5], K1.y, fmaf(q[6], K1.z, q[7] * K1.w))); \
        float dq2 = fmaf(q[8], K2.x, fmaf(q[9], K2.y, fmaf(q[10], K2.z, q[11] * K2.w))); \
        float dq3 = fmaf(q[12], K3.x, fmaf(q[13], K3.y, fmaf(q[14], K3.z, q[15] * K3.w))); \
        float ddp = (dp0 + dp1) + (dp2 + dp3);                                  \
        float ddq = (dq0 + dq1) + (dq2 + dq3);                                  \
        ddp = dpp_xor1_add(ddp);  ddq = dpp_xor1_add(ddq);                      \
        ddp = dpp_xor2_add(ddp);  ddq = dpp_xor2_add(ddq);                      \
        float up = -ddp;                                                        \
        float uq = V - ddq;                                                     \
        p[0] = fmaf(up, K0.x, p[0]);   q[0] = fmaf(uq, K0.x, q[0]);             \
        p[1] = fmaf(up, K0.y, p[1]);   q[1] = fmaf(uq, K0.y, q[1]);             \
        p[2] = fmaf(up, K0.z, p[2]);   q[2] = fmaf(uq, K0.z, q[2]);             \
        p[3] = fmaf(up, K0.w, p[3]);   q[3] = fmaf(uq, K0.w, q[3]);             \
        p[4] = fmaf(up, K1.x, p[4]);   q[4] = fmaf(uq, K1.x, q[4]);             \
        p[5] = fmaf(up, K1.y, p[5]);   q[5] = fmaf(uq, K1.y, q[5]);             \
        p[6] = fmaf(up, K1.z, p[6]);   q[6] = fmaf(uq, K1.z, q[6]);             \
        p[7] = fmaf(up, K1.w, p[7]);   q[7] = fmaf(uq, K1.w, q[7]);             \
        p[8] = fmaf(up, K2.x, p[8]);   q[8] = fmaf(uq, K2.x, q[8]);             \
        p[9] = fmaf(up, K2.y, p[9]);   q[9] = fmaf(uq, K2.y, q[9]);             \
        p[10] = fmaf(up, K2.z, p[10]); q[10] = fmaf(uq, K2.z, q[10]);           \
        p[11] = fmaf(up, K2.w, p[11]); q[11] = fmaf(uq, K2.w, q[11]);           \
        p[12] = fmaf(up, K3.x, p[12]); q[12] = fmaf(uq, K3.x, q[12]);           \
        p[13] = fmaf(up, K3.y, p[13]); q[13] = fmaf(uq, K3.y, q[13]);           \
        p[14] = fmaf(up, K3.z, p[14]); q[14] = fmaf(uq, K3.z, q[14]);           \
        p[15] = fmaf(up, K3.w, p[15]); q[15] = fmaf(uq, K3.w, q[15]);           \
    } while (0)

__global__ __launch_bounds__(256) void chunk_kernel(
    float* __restrict__ ksb, float* __restrict__ vsb, int C)
{
    __shared__ __align__(16) float sk[2][32 * 64];
    __shared__ __align__(16) float sv[2][32 * 64];

    const int job = blockIdx.x;
    const int tid = threadIdx.x;
    const int r = tid >> 2;
    const int c0 = (tid & 3) * 16;
    float* kc = ksb + (size_t)job * C * 64;
    float* vc = vsb + (size_t)job * C * 64;

    float p[16], q[16];
#pragma unroll
    for (int j = 0; j < 16; ++j) { p[j] = (c0 + j == r) ? 1.f : 0.f; q[j] = 0.f; }

    const int nt = C >> 5;
    float4 rk0, rk1, rv0, rv1;

    {
        const float4* gk = reinterpret_cast<const float4*>(kc);
        const float4* gv = reinterpret_cast<const float4*>(vc);
        float4 a0 = gk[tid], a1 = gk[256 + tid];
        float4 b0 = gv[tid], b1 = gv[256 + tid];
        float4* dk = reinterpret_cast<float4*>(sk[0]);
        float4* dv = reinterpret_cast<float4*>(sv[0]);
        dk[tid] = a0; dk[256 + tid] = a1;
        dv[tid] = b0; dv[256 + tid] = b1;
    }
    if (nt > 1) {
        const float4* gk = reinterpret_cast<const float4*>(kc + 2048);
        const float4* gv = reinterpret_cast<const float4*>(vc + 2048);
        rk0 = gk[tid]; rk1 = gk[256 + tid];
        rv0 = gv[tid]; rv1 = gv[256 + tid];
    }
    __syncthreads();

    int cur = 0;
    for (int tile = 0; tile < nt; ++tile) {
        if (tile + 1 < nt) {
            float4* dk = reinterpret_cast<float4*>(sk[cur ^ 1]);
            float4* dv = reinterpret_cast<float4*>(sv[cur ^ 1]);
            dk[tid] = rk0; dk[256 + tid] = rk1;
            dv[tid] = rv0; dv[256 + tid] = rv1;
            if (tile + 2 < nt) {
                const float4* gk = reinterpret_cast<const float4*>(kc + (size_t)(tile + 2) * 2048);
                const float4* gv = reinterpret_cast<const float4*>(vc + (size_t)(tile + 2) * 2048);
                rk0 = gk[tid]; rk1 = gk[256 + tid];
                rv0 = gv[tid]; rv1 = gv[256 + tid];
            }
        }

        const float* kl = sk[cur] + c0;
        const float* vl = sv[cur] + r;
        float4 a0, a1, a2, a3, e0, e1, e2, e3;
        float va, ve;
        {
            const float4* kp = reinterpret_cast<const float4*>(kl);
            a0 = kp[0]; a1 = kp[1]; a2 = kp[2]; a3 = kp[3];
            va = vl[0];
        }
#pragma unroll
        for (int t = 0; t < 32; t += 2) {
            {
                const float4* kp = reinterpret_cast<const float4*>(kl + (t + 1) * 64);
                e0 = kp[0]; e1 = kp[1]; e2 = kp[2]; e3 = kp[3];
                ve = vl[(t + 1) * 64];
            }
            STEP2(a0, a1, a2, a3, va);
            if (t + 2 < 32) {
                const float4* kp = reinterpret_cast<const float4*>(kl + (t + 2) * 64);
                a0 = kp[0]; a1 = kp[1]; a2 = kp[2]; a3 = kp[3];
                va = vl[(t + 2) * 64];
            }
            STEP2(e0, e1, e2, e3, ve);
        }
        __syncthreads();
        cur ^= 1;
    }

    float4* po = reinterpret_cast<float4*>(kc + r * 64 + c0);
    po[0] = make_float4(p[0], p[1], p[2], p[3]);
    po[1] = make_float4(p[4], p[5], p[6], p[7]);
    po[2] = make_float4(p[8], p[9], p[10], p[11]);
    po[3] = make_float4(p[12], p[13], p[14], p[15]);
    float4* qo = reinterpret_cast<float4*>(vc + r * 64 + c0);
    qo[0] = make_float4(q[0], q[1], q[2], q[3]);
    qo[1] = make_float4(q[4], q[5], q[6], q[7]);
    qo[2] = make_float4(q[8], q[9], q[10], q[11]);
    qo[3] = make_float4(q[12], q[13], q[14], q[15]);
}

// ---------------------------------------------------------------------------
// Chunked delta scan, phase B v2: M <- M*P + Q row-split across 4 blocks
// (rows are independent: row i needs M[i,:], all of P, Q[i,:]).
// grid = NB*4; block owns 16 rows; P double-buffered with reg prefetch.
// ---------------------------------------------------------------------------
__global__ __launch_bounds__(256) void combine_kernel(
    const float* __restrict__ Pb, const float* __restrict__ Qb,
    const float* __restrict__ Min, float* __restrict__ Mout,
    int nc, int chunk_stride)
{
    __shared__ __align__(16) float sP[2][64 * 64];
    __shared__ __align__(16) float sM[2][16 * 68];
    const int bb = blockIdx.x;
    const int b = bb >> 2;
    const int r0 = (bb & 3) << 4;
    const int tid = threadIdx.x;
    const int rl = tid >> 4;         // local row 0..15
    const int j4 = (tid & 15) * 4;   // col group
    const int gr = r0 + rl;          // global row

    if (Min) {
        *reinterpret_cast<float4*>(&sM[0][rl * 68 + j4]) =
            *reinterpret_cast<const float4*>(Min + ((size_t)b * 64 + gr) * 64 + j4);
    } else {
        *reinterpret_cast<float4*>(&sM[0][rl * 68 + j4]) = make_float4(0.f, 0.f, 0.f, 0.f);
    }
    {
        const float4* g = reinterpret_cast<const float4*>(Pb + (size_t)b * nc * chunk_stride);
        float4* s = reinterpret_cast<float4*>(sP[0]);
        for (int i = tid; i < 1024; i += 256) s[i] = g[i];
    }
    __syncthreads();

    int cur = 0;
    for (int c = 0; c < nc; ++c) {
        const size_t cbase = (size_t)(b * nc + c) * chunk_stride;
        float4 rp0, rp1, rp2, rp3;
        if (c + 1 < nc) {
            const float4* g = reinterpret_cast<const float4*>(Pb + cbase + chunk_stride);
            rp0 = g[tid]; rp1 = g[tid + 256]; rp2 = g[tid + 512]; rp3 = g[tid + 768];
        }
        float4 rq = *reinterpret_cast<const float4*>(Qb + cbase + (size_t)gr * 64 + j4);

        float ax = 0.f, ay = 0.f, az = 0.f, aw = 0.f;
        const float* Mrow = &sM[cur][rl * 68];
        const float* Pl = sP[c & 1];
#pragma unroll 4
        for (int mg = 0; mg < 16; ++mg) {
            float4 a4 = *reinterpret_cast<const float4*>(Mrow + mg * 4);
            float4 p0 = *reinterpret_cast<const float4*>(Pl + (mg * 4 + 0) * 64 + j4);
            float4 p1 = *reinterpret_cast<const float4*>(Pl + (mg * 4 + 1) * 64 + j4);
            float4 p2 = *reinterpret_cast<const float4*>(Pl + (mg * 4 + 2) * 64 + j4);
            float4 p3 = *reinterpret_cast<const float4*>(Pl + (mg * 4 + 3) * 64 + j4);
            ax = fmaf(a4.x, p0.x, ax); ay = fmaf(a4.x, p0.y, ay);
            az = fmaf(a4.x, p0.z, az); aw = fmaf(a4.x, p0.w, aw);
            ax = fmaf(a4.y, p1.x, ax); ay = fmaf(a4.y, p1.y, ay);
            az = fmaf(a4.y, p1.z, az); aw = fmaf(a4.y, p1.w, aw);
            ax = fmaf(a4.z, p2.x, ax); ay = fmaf(a4.z, p2.y, ay);
            az = fmaf(a4.z, p2.z, az); aw = fmaf(a4.z, p2.w, aw);
            ax = fmaf(a4.w, p3.x, ax); ay = fmaf(a4.w, p3.y, ay);
            az = fmaf(a4.w, p3.z, az); aw = fmaf(a4.w, p3.w, aw);
        }
        const int nxt = cur ^ 1;
        *reinterpret_cast<float4*>(&sM[nxt][rl * 68 + j4]) =
            make_float4(ax + rq.x, ay + rq.y, az + rq.z, aw + rq.w);
        if (c + 1 < nc) {
            float4* s = reinterpret_cast<float4*>(sP[(c + 1) & 1]);
            s[tid] = rp0; s[tid + 256] = rp1; s[tid + 512] = rp2; s[tid + 768] = rp3;
        }
        __syncthreads();
        cur = nxt;
    }
    *reinterpret_cast<float4*>(Mout + ((size_t)b * 64 + gr) * 64 + j4) =
        *reinterpret_cast<const float4*>(&sM[cur][rl * 68 + j4]);
}

// ---------------------------------------------------------------------------
// Attention v3 (unchanged from round 10).
// ---------------------------------------------------------------------------
__global__ __launch_bounds__(256) void attn_kernel(
    const float* __restrict__ qg, const float* __restrict__ Mbuf,
    const float* __restrict__ Wk, const float* __restrict__ Wv,
    float* __restrict__ ks2, float* __restrict__ vs2)
{
    __shared__ __align__(16) float sW1[64 * 68];
    __shared__ __align__(16) float sW2[64 * 68];
    __shared__ __align__(16) float sA[64 * 68];
    __shared__ __align__(16) float sB[64 * 68];

    const int b = blockIdx.y;
    const int tile0 = blockIdx.x * 64;
    const int tid = threadIdx.x;
    const int jq = (tid & 15) * 4;
    const int tq = (tid >> 4) * 4;
    const size_t qbase = (size_t)b * 2048 + tile0;
    const float* Mb = Mbuf + (size_t)b * 4096;

    stage_w_n(Mb, sW1, tid);
    stage_w_t(Mb, 64, 0, sW2, tid);
    stage_w_t(qg + qbase * 64, 64, 0, sA, tid);
    __syncthreads();

    float a[16];
    proj_tile64(sW1, sA, jq, tq, a);
#pragma unroll
    for (int u = 0; u < 16; ++u) a[u] *= 0.125f;

    {
        float mx[4], sm[4];
#pragma unroll
        for (int v = 0; v < 4; ++v)
            mx[v] = fmaxf(fmaxf(a[v], a[4 + v]), fmaxf(a[8 + v], a[12 + v]));
#pragma unroll
        for (int m = 1; m <= 8; m <<= 1) {
#pragma unroll
            for (int v = 0; v < 4; ++v) mx[v] = fmaxf(mx[v], __shfl_xor(mx[v], m));
        }
#pragma unroll
        for (int v = 0; v < 4; ++v) {
            a[v]      = __expf(a[v]      - mx[v]);
            a[4 + v]  = __expf(a[4 + v]  - mx[v]);
            a[8 + v]  = __expf(a[8 + v]  - mx[v]);
            a[12 + v] = __expf(a[12 + v] - mx[v]);
            sm[v] = a[v] + a[4 + v] + a[8 + v] + a[12 + v];
        }
#pragma unroll
        for (int m = 1; m <= 8; m <<= 1) {
#pragma unroll
            for (int v = 0; v < 4; ++v) sm[v] += __shfl_xor(sm[v], m);
        }
        float rinv[4];
#pragma unroll
        for (int v = 0; v < 4; ++v) rinv[v] = 1.f / sm[v];
#pragma unroll
        for (int v = 0; v < 4; ++v) {
            a[v] *= rinv[v]; a[4 + v] *= rinv[v];
            a[8 + v] *= rinv[v]; a[12 + v] *= rinv[v];
        }
    }
#pragma unroll
    for (int u = 0; u < 4; ++u)
        *reinterpret_cast<float4*>(&sB[(jq + u) * 68 + tq]) =
            make_float4(a[u * 4 + 0], a[u * 4 + 1], a[u * 4 + 2], a[u * 4 + 3]);
    __syncthreads();

    float c[16];
    proj_tile64(sW2, sB, jq, tq, c);
#pragma unroll
    for (int u = 0; u < 4; ++u)
        *reinterpret_cast<float4*>(&sA[(jq + u) * 68 + tq]) =
            make_float4(c[u * 4 + 0], c[u * 4 + 1], c[u * 4 + 2], c[u * 4 + 3]);
    __syncthreads();

    stage_w_t(Wk, 64, 0, sW1, tid);
    stage_w_t(Wv, 64, 0, sW2, tid);
    __syncthreads();

    float ak[16], av[16];
#pragma unroll
    for (int u = 0; u < 16; ++u) { ak[u] = 0.f; av[u] = 0.f; }
#pragma unroll 2
    for (int i = 0; i < 64; ++i) {
        float4 wk = *reinterpret_cast<const float4*>(&sW1[i * 68 + jq]);
        float4 wv = *reinterpret_cast<const float4*>(&sW2[i * 68 + jq]);
        float4 c4 = *reinterpret_cast<const float4*>(&sA[i * 68 + tq]);
        FMA16(ak, wk, c4);
        FMA16(av, wv, c4);
    }

    {
        float ssq[4];
#pragma unroll
        for (int v = 0; v < 4; ++v)
            ssq[v] = ak[v] * ak[v] + ak[4 + v] * ak[4 + v]
                   + ak[8 + v] * ak[8 + v] + ak[12 + v] * ak[12 + v];
#pragma unroll
        for (int m = 1; m <= 8; m <<= 1) {
#pragma unroll
            for (int v = 0; v < 4; ++v) ssq[v] += __shfl_xor(ssq[v], m);
        }
#pragma unroll
        for (int v = 0; v < 4; ++v) {
            float sc = 1.f / fmaxf(sqrtf(ssq[v]), 1e-12f);
            const size_t o = (qbase + tq + v) * 64 + jq;
            *reinterpret_cast<float4*>(&ks2[o]) =
                make_float4(ak[v] * sc, ak[4 + v] * sc, ak[8 + v] * sc, ak[12 + v] * sc);
            *reinterpret_cast<float4*>(&vs2[o]) =
                make_float4(av[v], av[4 + v], av[8 + v], av[12 + v]);
        }
    }
}

// ---------------------------------------------------------------------------
// Output: read = M2 @ q_last; out = read @ Wout^T + bout
// ---------------------------------------------------------------------------
__global__ __launch_bounds__(128) void out_kernel(
    const float* __restrict__ M2, const float* __restrict__ qlast,
    const float* __restrict__ Wout, const float* __restrict__ bout,
    float* __restrict__ out)
{
    const int b = blockIdx.x;
    const int tid = threadIdx.x;
    __shared__ float sq[64], sread[64];
    if (tid < 64) sq[tid] = qlast[b * 64 + tid];
    __syncthreads();
    if (tid < 64) {
        const float* Mr = M2 + ((size_t)b * 64 + tid) * 64;
        float acc = 0.f;
        for (int j = 0; j < 64; ++j) acc = fmaf(Mr[j], sq[j], acc);
        sread[tid] = acc;
    }
    __syncthreads();
    float acc = bout[tid];
    for (int h = 0; h < 64; ++h) acc = fmaf(Wout[tid * 64 + h], sread[h], acc);
    out[b * 128 + tid] = acc;
}

// ---------------------------------------------------------------------------
extern "C" void kernel_launch(void* const* d_in, const int* in_sizes, int n_in,
                              void* d_out, int out_size, void* d_ws, size_t ws_size,
                              hipStream_t stream)
{
    const int* x        = (const int*)d_in[0];
    const float* embed  = (const float*)d_in[1];
    const float* W1     = (const float*)d_in[2];
    const float* b1     = (const float*)d_in[3];
    const float* W2     = (const float*)d_in[4];
    const float* b2     = (const float*)d_in[5];
    const float* ln_g   = (const float*)d_in[6];
    const float* ln_b   = (const float*)d_in[7];
    const float* Wk     = (const float*)d_in[8];
    const float* Wv     = (const float*)d_in[9];
    const float* Wq     = (const float*)d_in[10];
    const float* Wattn  = (const float*)d_in[11];
    const float* Wout   = (const float*)d_in[12];
    const float* bout   = (const float*)d_in[13];

    // workspace layout (floats): ks | vs | q | qlast | M | M2
    float* ws = (float*)d_ws;
    float* ks = ws;
    float* vs = ks + (size_t)NB * SEQL * 64;
    float* qb = vs + (size_t)NB * SEQL * 64;
    float* ql = qb + (size_t)NB * 2048 * 64;
    float* M  = ql + (size_t)NB * 64;
    float* M2 = M + (size_t)NB * 64 * 64;
    if (ws_size < (size_t)(M2 + (size_t)NB * 64 * 64 - ws) * sizeof(float)) return;

    hipLaunchKernelGGL(encoder_kernel, dim3((NB * SEQL) / 64), dim3(256), 0, stream,
                       x, embed, W1, b1, W2, b2, ln_g, ln_b, Wk, Wv, Wq, Wattn,
                       ks, vs, qb, ql);

    // scan 1: L=4096, C=256 -> 16 chunks/batch, 1024 parallel chunk jobs
    const int C1 = 256, nc1 = SEQL / C1;
    hipLaunchKernelGGL(chunk_kernel, dim3(NB * nc1), dim3(256), 0, stream, ks, vs, C1);
    hipLaunchKernelGGL(combine_kernel, dim3(NB * 4), dim3(256), 0, stream,
                       ks, vs, (const float*)nullptr, M, nc1, C1 * 64);

    // attention + second k/v projection (ks2/vs2 reuse ks/vs)
    hipLaunchKernelGGL(attn_kernel, dim3(32, NB), dim3(256), 0, stream,
                       qb, M, Wk, Wv, ks, vs);

    // scan 2: L=2048, C=128 -> 16 chunks/batch, 1024 parallel chunk jobs
    const int C2 = 128, nc2 = 2048 / C2;
    hipLaunchKernelGGL(chunk_kernel, dim3(NB * nc2), dim3(256), 0, stream, ks, vs, C2);
    hipLaunchKernelGGL(combine_kernel, dim3(NB * 4), dim3(256), 0, stream,
                       ks, vs, M, M2, nc2, C2 * 64);

    hipLaunchKernelGGL(out_kernel, dim3(NB), dim3(128), 0, stream,
                       M2, ql, Wout, bout, (float*)d_out);
}